// Round 7
// baseline (1060.414 us; speedup 1.0000x reference)
//
#include <hip/hip_runtime.h>

// ============================================================================
// New_LinkNet GNN forward — MFMA bf16 GEMMs + fused gate updates.
// Round-7 changes vs round 6 (1000us; gemm_mfma<0> 85us latency-bound:
// 2 load-wait stages per K=128, Q written fp32):
//  - gemm_mfma: full-K=128 single LDS stage (As/Bs 128x128 bf16, 64KB),
//    16 outstanding 16B loads -> ONE wait+barrier per chunk (MODE0: 1 chunk,
//    MODE1 K=256: 2 chunks).
//  - Q stored bf16 (epilogue f2bf + attn uint2 load): -25.6MB write/read.
//  - P aliases dead skipb+kvb region; peak ws ~214MB.
// ============================================================================

#define LN_EPS 1e-5f
#define PBLK 512

typedef __attribute__((ext_vector_type(8))) short bf16x8;
typedef __attribute__((ext_vector_type(4))) float f32x4;

static __device__ __forceinline__ float wsum(float v) {
#pragma unroll
  for (int d = 32; d > 0; d >>= 1) v += __shfl_xor(v, d);
  return v;
}
static __device__ __forceinline__ float sigm(float x) { return 1.0f / (1.0f + __expf(-x)); }
static __device__ __forceinline__ unsigned short f2bf(float f) {
  unsigned int u = __float_as_uint(f);
  u += 0x7FFFu + ((u >> 16) & 1u);
  return (unsigned short)(u >> 16);
}
static __device__ __forceinline__ float bf2f(unsigned short b) {
  return __uint_as_float(((unsigned int)b) << 16);
}

// ---------------- util ----------------
__global__ __launch_bounds__(256) void k_zero2(int* __restrict__ a, int* __restrict__ b, int n) {
  int i = blockIdx.x * 256 + threadIdx.x;
  if (i < n) { a[i] = 0; b[i] = 0; }
}

__global__ __launch_bounds__(256) void k_sentinel(float* __restrict__ out, int n) {
  int i = blockIdx.x * 256 + threadIdx.x;
  if (i < n) out[i] = 1.0e6f;
}

// ---------------- CSR build (by dst) ----------------
__global__ __launch_bounds__(256) void k_hist(const int* __restrict__ ei, int* __restrict__ cnt, int E) {
  int e = blockIdx.x * 256 + threadIdx.x;
  if (e >= 2 * E) return;
  int d = (e < E) ? ei[E + e] : ei[e - E];
  atomicAdd(&cnt[d], 1);
}

__global__ __launch_bounds__(256) void k_scan1(const int* __restrict__ cnt, int* __restrict__ off,
                                               int* __restrict__ bsum, int n) {
  const int t = threadIdx.x;
  const int lane = t & 63, w = t >> 6;
  const int i0 = blockIdx.x * 1024 + t * 4;
  int v0 = (i0 + 0 < n) ? cnt[i0 + 0] : 0;
  int v1 = (i0 + 1 < n) ? cnt[i0 + 1] : 0;
  int v2 = (i0 + 2 < n) ? cnt[i0 + 2] : 0;
  int v3 = (i0 + 3 < n) ? cnt[i0 + 3] : 0;
  int s = v0 + v1 + v2 + v3;
  int sc = s;
#pragma unroll
  for (int d = 1; d < 64; d <<= 1) {
    int tv = __shfl_up(sc, d);
    if (lane >= d) sc += tv;
  }
  __shared__ int wsums[4];
  if (lane == 63) wsums[w] = sc;
  __syncthreads();
  int wbase = 0;
#pragma unroll
  for (int k = 0; k < 4; ++k)
    if (k < w) wbase += wsums[k];
  int run = wbase + sc - s;
  if (i0 + 0 < n) off[i0 + 0] = run; run += v0;
  if (i0 + 1 < n) off[i0 + 1] = run; run += v1;
  if (i0 + 2 < n) off[i0 + 2] = run; run += v2;
  if (i0 + 3 < n) off[i0 + 3] = run;
  if (t == 255) bsum[blockIdx.x] = wbase + sc;
}

__global__ __launch_bounds__(64) void k_scan2(const int* __restrict__ bsum, int* __restrict__ boff,
                                              int* __restrict__ off, int n, int nblk) {
  const int lane = threadIdx.x;
  int carry = 0;
  for (int base = 0; base < nblk; base += 64) {
    int i = base + lane;
    int v = (i < nblk) ? bsum[i] : 0;
    int sc = v;
#pragma unroll
    for (int d = 1; d < 64; d <<= 1) {
      int tv = __shfl_up(sc, d);
      if (lane >= d) sc += tv;
    }
    if (i < nblk) boff[i] = carry + sc - v;
    carry += __shfl(sc, 63);
  }
  if (lane == 0) off[n] = carry;
}

__global__ __launch_bounds__(256) void k_scan3(int* __restrict__ off, const int* __restrict__ boff, int n) {
  int i = blockIdx.x * 256 + threadIdx.x;
  if (i < n) off[i] += boff[i >> 10];
}

__global__ __launch_bounds__(256) void k_scatter(const int* __restrict__ ei, const int* __restrict__ off,
                                                 int* __restrict__ cur, int* __restrict__ elist, int E) {
  int e = blockIdx.x * 256 + threadIdx.x;
  if (e >= 2 * E) return;
  int d = (e < E) ? ei[E + e] : ei[e - E];
  int pos = atomicAdd(&cur[d], 1);
  elist[off[d] + pos] = e;
}

// ---------------- pack all transposed bf16 weights ----------------
__global__ __launch_bounds__(256) void k_packW(
    const float* __restrict__ Wq, const float* __restrict__ Wk, const float* __restrict__ Wv,
    const float* __restrict__ Ws, const float* __restrict__ bq, const float* __restrict__ bk,
    const float* __restrict__ bv, const float* __restrict__ bs,
    const float* __restrict__ Wpn, const float* __restrict__ Wpe,
    const float* __restrict__ bpn, const float* __restrict__ bpe,
    const float* __restrict__ Wg, const float* __restrict__ Wc1,
    unsigned short* __restrict__ W1t, float* __restrict__ bias1,
    unsigned short* __restrict__ B2t, float* __restrict__ bias2,
    unsigned short* __restrict__ Wg1t, unsigned short* __restrict__ Wc1t) {
  const int S1 = 3 * 1024 * 128, S2 = 3 * 1024, S3 = 3 * 256 * 256, S4 = 3 * 256;
  const int S5 = 3 * 64 * 64, S6 = 2 * 64 * 64;
  int idx = blockIdx.x * 256 + threadIdx.x;
  if (idx < S1) {
    int i = idx / 131072, r = idx % 131072;
    int col = r >> 7, k = r & 127;
    int m = col >> 8, cc = col & 255;
    const float* W = (m == 0) ? Wq : (m == 1) ? Wk : (m == 2) ? Wv : Ws;
    W1t[idx] = f2bf(W[i * 32768 + k * 256 + cc]);
  } else if (idx < S1 + S2) {
    int j = idx - S1;
    int i = j >> 10, col = j & 1023;
    int m = col >> 8, cc = col & 255;
    const float* bsrc = (m == 0) ? bq : (m == 1) ? bk : (m == 2) ? bv : bs;
    bias1[j] = bsrc[i * 256 + cc];
  } else if (idx < S1 + S2 + S3) {
    int j = idx - S1 - S2;
    int i = j / 65536, r = j % 65536;
    int col = r >> 8, k = r & 255;
    float v;
    if (col < 64) v = Wpn[i * 16384 + k * 64 + col];
    else if (col < 128) v = Wpe[i * 16384 + k * 64 + (col - 64)];
    else {
      const float* Wsrc = (col < 192) ? Wpn : Wpe;
      int cc = col & 63;
      float acc = 0.f;
      for (int jj = 0; jj < 64; ++jj)
        acc = fmaf(Wsrc[i * 16384 + k * 64 + jj], Wg[i * 8192 + (64 + jj) * 64 + cc], acc);
      v = acc;
    }
    B2t[j] = f2bf(v);
  } else if (idx < S1 + S2 + S3 + S4) {
    int j = idx - S1 - S2 - S3;
    int i = j >> 8, col = j & 255;
    float v;
    if (col < 64) v = bpn[i * 64 + col];
    else if (col < 128) v = bpe[i * 64 + col - 64];
    else {
      const float* bsrc = (col < 192) ? bpn : bpe;
      int cc = col & 63;
      float acc = 0.f;
      for (int jj = 0; jj < 64; ++jj)
        acc = fmaf(bsrc[i * 64 + jj], Wg[i * 8192 + (64 + jj) * 64 + cc], acc);
      v = acc;
    }
    bias2[j] = v;
  } else if (idx < S1 + S2 + S3 + S4 + S5) {
    int j = idx - S1 - S2 - S3 - S4;
    int i = j / 4096, r = j % 4096;
    int col = r >> 6, k = r & 63;
    Wg1t[j] = f2bf(Wg[i * 8192 + k * 64 + col]);
  } else if (idx < S1 + S2 + S3 + S4 + S5 + S6) {
    int j = idx - S1 - S2 - S3 - S4 - S5;
    int h = j / 4096, r = j % 4096;
    int col = r >> 6, k = r & 63;
    Wc1t[j] = f2bf(Wc1[(h * 64 + k) * 64 + col]);
  }
}

// ---------------- embeddings ----------------
__global__ __launch_bounds__(256) void k_node_embed(
    const float* __restrict__ x, const int* __restrict__ zk, const float* __restrict__ zt,
    const float* __restrict__ Wn, const float* __restrict__ bn, float* __restrict__ nf, int N) {
  int n = blockIdx.x * 4 + (threadIdx.x >> 6);
  int lane = threadIdx.x & 63;
  if (n >= N) return;
  const float* xr = x + (size_t)n * 6;
  float acc = bn[lane];
#pragma unroll
  for (int d = 0; d < 6; ++d) acc = fmaf(xr[d], Wn[d * 64 + lane], acc);
  int zi = __float2int_rn(xr[2]);
  int idx = 0;
#pragma unroll
  for (int t = 5; t >= 0; --t)
    if (zi == zk[t]) idx = t;
  nf[(size_t)n * 64 + lane] = fmaxf(acc, 0.0f) + zt[idx * 64 + lane];
}

__global__ __launch_bounds__(256) void k_edge_embed(
    const float* __restrict__ x, const float* __restrict__ ea, const int* __restrict__ ei,
    const float* __restrict__ We, const float* __restrict__ be, float* __restrict__ ef, int E) {
  int e = blockIdx.x * 4 + (threadIdx.x >> 6);
  int lane = threadIdx.x & 63;
  if (e >= 2 * E) return;
  int e0 = (e < E) ? e : e - E;
  int s = ei[e];
  int d = (e < E) ? ei[E + e] : ei[e - E];
  const float* ar = ea + (size_t)e0 * 4;
  const float* xs = x + (size_t)s * 6;
  const float* xd = x + (size_t)d * 6;
  float in[7];
  in[0] = ar[0]; in[1] = ar[1]; in[2] = ar[2]; in[3] = ar[3];
  in[4] = xs[0] - xd[0]; in[5] = xs[1] - xd[1]; in[6] = xs[2] - xd[2];
  float acc = be[lane];
#pragma unroll
  for (int dd = 0; dd < 7; ++dd) acc = fmaf(in[dd], We[dd * 64 + lane], acc);
  ef[(size_t)e * 64 + lane] = fmaxf(acc, 0.0f);
}

// ---------------- CBAM (vectorized) ----------------
__global__ __launch_bounds__(256) void k_pool_partial(const float* __restrict__ buf, int n,
                                                      float* __restrict__ pm, float* __restrict__ ps) {
  const int w = threadIdx.x >> 6, l = threadIdx.x & 63;
  const int rsub = l >> 4, c4 = (l & 15) << 2;
  float4 mx = make_float4(-INFINITY, -INFINITY, -INFINITY, -INFINITY);
  float4 sm = make_float4(0.f, 0.f, 0.f, 0.f);
  for (int r = blockIdx.x * 16 + w * 4 + rsub; r < n; r += gridDim.x * 16) {
    float4 v = *(const float4*)(buf + (size_t)r * 64 + c4);
    mx.x = fmaxf(mx.x, v.x); mx.y = fmaxf(mx.y, v.y);
    mx.z = fmaxf(mx.z, v.z); mx.w = fmaxf(mx.w, v.w);
    sm.x += v.x; sm.y += v.y; sm.z += v.z; sm.w += v.w;
  }
#pragma unroll
  for (int d = 16; d < 64; d <<= 1) {
    mx.x = fmaxf(mx.x, __shfl_xor(mx.x, d)); mx.y = fmaxf(mx.y, __shfl_xor(mx.y, d));
    mx.z = fmaxf(mx.z, __shfl_xor(mx.z, d)); mx.w = fmaxf(mx.w, __shfl_xor(mx.w, d));
    sm.x += __shfl_xor(sm.x, d); sm.y += __shfl_xor(sm.y, d);
    sm.z += __shfl_xor(sm.z, d); sm.w += __shfl_xor(sm.w, d);
  }
  __shared__ float smx[4][64], ssm[4][64];
  if (l < 16) {
    *(float4*)&smx[w][c4] = mx;
    *(float4*)&ssm[w][c4] = sm;
  }
  __syncthreads();
  if (threadIdx.x < 64) {
    int t = threadIdx.x;
    float m2 = fmaxf(fmaxf(smx[0][t], smx[1][t]), fmaxf(smx[2][t], smx[3][t]));
    float s2 = ssm[0][t] + ssm[1][t] + ssm[2][t] + ssm[3][t];
    pm[blockIdx.x * 64 + t] = m2;
    ps[blockIdx.x * 64 + t] = s2;
  }
}

__global__ __launch_bounds__(256) void k_pool_final(
    const float* __restrict__ pm, const float* __restrict__ ps, int n, int nblk,
    const float* __restrict__ w1, const float* __restrict__ b1,
    const float* __restrict__ w2, const float* __restrict__ b2, float* __restrict__ cw) {
  __shared__ float redm[4][64], reds[4][64];
  __shared__ float cat[128];
  __shared__ float hid[4];
  int t = threadIdx.x;
  int g = t >> 6, col = t & 63;
  float mx = -INFINITY, sm = 0.0f;
  for (int p = g; p < nblk; p += 4) {
    mx = fmaxf(mx, pm[p * 64 + col]);
    sm += ps[p * 64 + col];
  }
  redm[g][col] = mx;
  reds[g][col] = sm;
  __syncthreads();
  if (t < 64) {
    float m2 = fmaxf(fmaxf(redm[0][t], redm[1][t]), fmaxf(redm[2][t], redm[3][t]));
    float s2 = reds[0][t] + reds[1][t] + reds[2][t] + reds[3][t];
    cat[t] = m2;
    cat[64 + t] = s2 / (float)n;
  }
  __syncthreads();
  if (t < 4) {
    float a = b1[t];
    for (int k = 0; k < 128; ++k) a = fmaf(cat[k], w1[k * 4 + t], a);
    hid[t] = fmaxf(a, 0.0f);
  }
  __syncthreads();
  if (t < 64) {
    float a = b2[t];
#pragma unroll
    for (int h = 0; h < 4; ++h) a = fmaf(hid[h], w2[h * 64 + t], a);
    cw[t] = sigm(a);
  }
}

__global__ __launch_bounds__(256) void k_chan_sp(float* __restrict__ buf, int n,
                                                 const float* __restrict__ cw,
                                                 float* __restrict__ spmax, float* __restrict__ spmean) {
  const int w = threadIdx.x >> 6, l = threadIdx.x & 63;
  const int rsub = l >> 4, c4 = (l & 15) << 2;
  int r = blockIdx.x * 16 + w * 4 + rsub;
  if (r >= n) return;
  float4 cwv = *(const float4*)(cw + c4);
  float4 v = *(const float4*)(buf + (size_t)r * 64 + c4);
  v.x *= cwv.x; v.y *= cwv.y; v.z *= cwv.z; v.w *= cwv.w;
  *(float4*)(buf + (size_t)r * 64 + c4) = v;
  float mx = fmaxf(fmaxf(v.x, v.y), fmaxf(v.z, v.w));
  float sm = v.x + v.y + v.z + v.w;
#pragma unroll
  for (int d = 1; d < 16; d <<= 1) {
    mx = fmaxf(mx, __shfl_xor(mx, d));
    sm += __shfl_xor(sm, d);
  }
  if ((l & 15) == 0) {
    spmax[r] = mx;
    spmean[r] = sm * (1.0f / 64.0f);
  }
}

__global__ __launch_bounds__(256) void k_conv(const float* __restrict__ spmax, const float* __restrict__ spmean,
                                              int n, const float* __restrict__ w1, const float* __restrict__ b1,
                                              const float* __restrict__ w2, const float* __restrict__ b2,
                                              float* __restrict__ s) {
  __shared__ float tl[258];
  int base = blockIdx.x * 256;
  for (int q = threadIdx.x; q < 258; q += 256) {
    int p = base - 1 + q;
    float t = 0.0f;
    if (p >= 0 && p < n) {
      float a = b1[0];
#pragma unroll
      for (int h = 0; h < 5; ++h) {
        int pp = p + h - 2;
        if (pp >= 0 && pp < n) a += spmax[pp] * w1[h] + spmean[pp] * w1[5 + h];
      }
      t = fmaxf(a, 0.0f);
    }
    tl[q] = t;
  }
  __syncthreads();
  int o = base + threadIdx.x;
  if (o < n) {
    float a = b2[0] + tl[threadIdx.x] * w2[0] + tl[threadIdx.x + 1] * w2[1] + tl[threadIdx.x + 2] * w2[2];
    s[o] = sigm(a);
  }
}

__global__ __launch_bounds__(256) void k_row_scale(float* __restrict__ buf, int n, const float* __restrict__ s) {
  int i4 = blockIdx.x * 256 + threadIdx.x;
  if (i4 >= n * 16) return;
  int r = i4 >> 4;
  float sc = s[r];
  float4 v = *(const float4*)(buf + (size_t)i4 * 4);
  v.x *= sc; v.y *= sc; v.z *= sc; v.w *= sc;
  *(float4*)(buf + (size_t)i4 * 4) = v;
}

// ---------------- agg + concat-LN (bf16 out) ----------------
__global__ __launch_bounds__(256) void k_aggcomb(const float* __restrict__ ef, const float* __restrict__ nf,
                                                 const int* __restrict__ off, const int* __restrict__ elist,
                                                 unsigned short* __restrict__ comb, const float* __restrict__ g,
                                                 const float* __restrict__ b, int N) {
  int n = blockIdx.x * 4 + (threadIdx.x >> 6);
  int lane = threadIdx.x & 63;
  if (n >= N) return;
  float agg = 0.0f;
  int i0 = off[n], i1 = off[n + 1];
  for (int idx = i0; idx < i1; ++idx) agg += ef[(size_t)elist[idx] * 64 + lane];
  float y0 = nf[(size_t)n * 64 + lane];
  float y1 = agg - y0;
  float s1 = wsum(y0 + y1);
  float s2 = wsum(y0 * y0 + y1 * y1);
  float mu = s1 * (1.0f / 128.0f);
  float var = s2 * (1.0f / 128.0f) - mu * mu;
  float rs = rsqrtf(fmaxf(var, 0.0f) + LN_EPS);
  comb[(size_t)n * 128 + lane] = f2bf((y0 - mu) * rs * g[lane] + b[lane]);
  comb[(size_t)n * 128 + 64 + lane] = f2bf((y1 - mu) * rs * g[64 + lane] + b[64 + lane]);
}

// ---------------- MFMA GEMM: C[M,NC] = A[M,K](bf16) @ Bt[NC,K](bf16) -------
// Full-K=128 LDS chunks: one load-wait + one barrier per chunk.
// MODE 0: NC=1024, bf16 epilogue split Q|K|V|S. MODE 1: fp32 out ld=256.
template <int MODE>
__global__ __launch_bounds__(256) void gemm_mfma(
    const unsigned short* __restrict__ A, int M, int K,
    const unsigned short* __restrict__ Bt, const float* __restrict__ bias,
    float* __restrict__ outF, unsigned short* __restrict__ outQ,
    unsigned short* __restrict__ outK, unsigned short* __restrict__ outS) {
  __shared__ unsigned short As[128 * 128];
  __shared__ unsigned short Bs[128 * 128];
  const int tid = threadIdx.x;
  const int bm = blockIdx.x * 128;
  const int bn = blockIdx.y * 128;
  const int wid = tid >> 6, lane = tid & 63;
  const int wr = (wid >> 1) * 64, wc = (wid & 1) * 64;
  const int lrow = lane & 15, lkb = (lane >> 4) * 8;
  f32x4 acc[4][4];
#pragma unroll
  for (int m = 0; m < 4; ++m)
#pragma unroll
    for (int n = 0; n < 4; ++n) acc[m][n] = (f32x4){0.f, 0.f, 0.f, 0.f};

  for (int k0 = 0; k0 < K; k0 += 128) {
    if (k0) __syncthreads();
#pragma unroll
    for (int l = 0; l < 8; ++l) {
      int c = tid + l * 256;             // 0..2047
      int row = c >> 4;                  // 0..127
      int kc = (c & 15) * 8;             // 0..120
      int sw = row * 128 + (kc ^ ((row & 7) << 3));
      int grow = bm + row;
      bf16x8 v = {0, 0, 0, 0, 0, 0, 0, 0};
      if (grow < M) v = *(const bf16x8*)(A + (size_t)grow * K + k0 + kc);
      *(bf16x8*)&As[sw] = v;
      int gcol = bn + row;
      *(bf16x8*)&Bs[sw] = *(const bf16x8*)(Bt + (size_t)gcol * K + k0 + kc);
    }
    __syncthreads();
#pragma unroll
    for (int ks = 0; ks < 4; ++ks) {
      const int ke = ks * 32 + lkb;
      bf16x8 af[4], bfr[4];
#pragma unroll
      for (int m = 0; m < 4; ++m) {
        int row = wr + m * 16 + lrow;
        af[m] = *(const bf16x8*)&As[row * 128 + (ke ^ ((row & 7) << 3))];
      }
#pragma unroll
      for (int n = 0; n < 4; ++n) {
        int col = wc + n * 16 + lrow;
        bfr[n] = *(const bf16x8*)&Bs[col * 128 + (ke ^ ((col & 7) << 3))];
      }
#pragma unroll
      for (int m = 0; m < 4; ++m)
#pragma unroll
        for (int n = 0; n < 4; ++n)
          acc[m][n] = __builtin_amdgcn_mfma_f32_16x16x32_bf16(af[m], bfr[n], acc[m][n], 0, 0, 0);
    }
  }

  const int colw = lane & 15, rq = (lane >> 4) * 4;
  const int proj = bn >> 8;
#pragma unroll
  for (int m = 0; m < 4; ++m) {
#pragma unroll
    for (int n = 0; n < 4; ++n) {
      int gcol = bn + wc + n * 16 + colw;
      float bv = bias[gcol];
#pragma unroll
      for (int r = 0; r < 4; ++r) {
        int grow = bm + wr + m * 16 + rq + r;
        if (grow >= M) continue;
        float v = acc[m][n][r] + bv;
        if (MODE == 1) {
          outF[(size_t)grow * 256 + gcol] = v;
        } else {
          int cc = gcol & 255;
          if (proj == 0) outQ[(size_t)grow * 256 + cc] = f2bf(v);
          else if (proj == 1) outK[(size_t)grow * 512 + cc] = f2bf(v);
          else if (proj == 2) outK[(size_t)grow * 512 + 256 + cc] = f2bf(v);
          else outS[(size_t)grow * 256 + cc] = f2bf(v);
        }
      }
    }
  }
}

// ------ MFMA [M,64]@[64,64] with fused epilogue ------
template <int UPD>
__global__ __launch_bounds__(256) void gemm_gate(
    const float* __restrict__ Af, int M, const unsigned short* __restrict__ Wt,
    const float* __restrict__ P, const float* __restrict__ bgv,
    const int* __restrict__ ei, float* __restrict__ upd) {
  __shared__ unsigned short As[128 * 64];
  __shared__ unsigned short Ws[64 * 64];
  const int tid = threadIdx.x;
  const int bm = blockIdx.x * 128;
#pragma unroll
  for (int l = 0; l < 8; ++l) {
    int u = tid + l * 256;
    int row = u >> 4, k4 = (u & 15) << 2;
    int grow = bm + row;
    float4 v = make_float4(0.f, 0.f, 0.f, 0.f);
    if (grow < M) v = *(const float4*)(Af + (size_t)grow * 64 + k4);
    union { unsigned short h[4]; uint2 q; } pk;
    pk.h[0] = f2bf(v.x); pk.h[1] = f2bf(v.y); pk.h[2] = f2bf(v.z); pk.h[3] = f2bf(v.w);
    *(uint2*)&As[row * 64 + (k4 ^ ((row & 7) << 3))] = pk.q;
  }
#pragma unroll
  for (int l = 0; l < 2; ++l) {
    int u = tid + l * 256;
    int row = u >> 3, kc = (u & 7) * 8;
    *(bf16x8*)&Ws[row * 64 + (kc ^ ((row & 7) << 3))] = *(const bf16x8*)(Wt + row * 64 + kc);
  }
  __syncthreads();
  const int wid = tid >> 6, lane = tid & 63;
  const int wr = wid * 32;
  const int lrow = lane & 15, lkb = (lane >> 4) * 8;
  f32x4 acc[2][4];
#pragma unroll
  for (int m = 0; m < 2; ++m)
#pragma unroll
    for (int n = 0; n < 4; ++n) acc[m][n] = (f32x4){0.f, 0.f, 0.f, 0.f};
#pragma unroll
  for (int ks = 0; ks < 2; ++ks) {
    const int ke = ks * 32 + lkb;
    bf16x8 af[2], wf[4];
#pragma unroll
    for (int m = 0; m < 2; ++m) {
      int row = wr + m * 16 + lrow;
      af[m] = *(const bf16x8*)&As[row * 64 + (ke ^ ((row & 7) << 3))];
    }
#pragma unroll
    for (int n = 0; n < 4; ++n) {
      int col = n * 16 + lrow;
      wf[n] = *(const bf16x8*)&Ws[col * 64 + (ke ^ ((col & 7) << 3))];
    }
#pragma unroll
    for (int m = 0; m < 2; ++m)
#pragma unroll
      for (int n = 0; n < 4; ++n)
        acc[m][n] = __builtin_amdgcn_mfma_f32_16x16x32_bf16(af[m], wf[n], acc[m][n], 0, 0, 0);
  }
  const int colw = lane & 15, rq = (lane >> 4) * 4;
#pragma unroll
  for (int m = 0; m < 2; ++m) {
#pragma unroll
    for (int r = 0; r < 4; ++r) {
      int e = bm + wr + m * 16 + rq + r;
      if (e >= M) continue;
      if (UPD == 0) {
#pragma unroll
        for (int n = 0; n < 4; ++n) upd[(size_t)e * 64 + n * 16 + colw] = acc[m][n][r];
      } else {
        int s = (UPD == 2) ? ei[e] : e;
        const float* Pr = P + (size_t)s * 256;
        const int voff = (UPD == 1) ? 128 : 192;
        const int poff = (UPD == 1) ? 0 : 64;
#pragma unroll
        for (int n = 0; n < 4; ++n) {
          int c = n * 16 + colw;
          float g = sigm(acc[m][n][r] + Pr[voff + c] + bgv[c]);
          size_t oi = (size_t)e * 64 + c;
          upd[oi] = upd[oi] * g + Pr[poff + c] * (1.0f - g);
        }
      }
    }
  }
}

// ---------------- attention: lane = (head, 4 cols); wide loads ----------
__global__ __launch_bounds__(256) void k_attn(const unsigned short* __restrict__ qo,
                                              const unsigned short* __restrict__ kv,
                                              const unsigned short* __restrict__ skipb, const int* __restrict__ off,
                                              const int* __restrict__ elist, const int* __restrict__ ei,
                                              unsigned short* __restrict__ aob,
                                              const float* __restrict__ g, const float* __restrict__ b, int N) {
  int n = blockIdx.x * 4 + (threadIdx.x >> 6);
  int lane = threadIdx.x & 63;
  if (n >= N) return;
  union { uint2 u; unsigned short h[4]; } qq;
  qq.u = *(const uint2*)(qo + (size_t)n * 256 + 4 * lane);
  float q0 = bf2f(qq.h[0]), q1 = bf2f(qq.h[1]), q2 = bf2f(qq.h[2]), q3 = bf2f(qq.h[3]);
  float m = -INFINITY, lsum = 0.f;
  float a0 = 0.f, a1 = 0.f, a2 = 0.f, a3 = 0.f;
  int i0 = off[n], i1 = off[n + 1];
  for (int idx = i0; idx < i1; ++idx) {
    int eid = elist[idx];
    int s = ei[eid];
    const unsigned short* kb = kv + (size_t)s * 512;
    union { uint2 u; unsigned short h[4]; } kk, vv;
    kk.u = *(const uint2*)(kb + 4 * lane);
    vv.u = *(const uint2*)(kb + 256 + 4 * lane);
    float d = q0 * bf2f(kk.h[0]) + q1 * bf2f(kk.h[1]) + q2 * bf2f(kk.h[2]) + q3 * bf2f(kk.h[3]);
#pragma unroll
    for (int dd = 1; dd < 16; dd <<= 1) d += __shfl_xor(d, dd);
    d *= 0.125f;
    float nm = fmaxf(m, d);
    float sc = __expf(m - nm);
    float p = __expf(d - nm);
    lsum = lsum * sc + p;
    a0 = fmaf(p, bf2f(vv.h[0]), a0 * sc);
    a1 = fmaf(p, bf2f(vv.h[1]), a1 * sc);
    a2 = fmaf(p, bf2f(vv.h[2]), a2 * sc);
    a3 = fmaf(p, bf2f(vv.h[3]), a3 * sc);
    m = nm;
  }
  union { uint2 u; unsigned short h[4]; } sb;
  sb.u = *(const uint2*)(skipb + (size_t)n * 256 + 4 * lane);
  float inv = (lsum > 0.f) ? 1.0f / lsum : 0.f;
  float v0 = bf2f(sb.h[0]) + a0 * inv;
  float v1 = bf2f(sb.h[1]) + a1 * inv;
  float v2 = bf2f(sb.h[2]) + a2 * inv;
  float v3 = bf2f(sb.h[3]) + a3 * inv;
  float s1 = wsum(v0 + v1 + v2 + v3);
  float s2 = wsum(v0 * v0 + v1 * v1 + v2 * v2 + v3 * v3);
  float mu = s1 * (1.0f / 256.0f);
  float var = s2 * (1.0f / 256.0f) - mu * mu;
  float rs = rsqrtf(fmaxf(var, 0.0f) + LN_EPS);
  float4 g4 = *(const float4*)(g + 4 * lane);
  float4 b4 = *(const float4*)(b + 4 * lane);
  union { uint2 u; unsigned short h[4]; } ob;
  ob.h[0] = f2bf((v0 - mu) * rs * g4.x + b4.x);
  ob.h[1] = f2bf((v1 - mu) * rs * g4.y + b4.y);
  ob.h[2] = f2bf((v2 - mu) * rs * g4.z + b4.z);
  ob.h[3] = f2bf((v3 - mu) * rs * g4.w + b4.w);
  *(uint2*)(aob + (size_t)n * 256 + 4 * lane) = ob.u;
}

// ---------------- classifier pair kernel ----------------
__global__ __launch_bounds__(256) void k_clf_pair(const float* __restrict__ ABt, const float* __restrict__ ABb,
                                                  const int* __restrict__ ei, const float* __restrict__ bc1,
                                                  const float* __restrict__ Wc2, const float* __restrict__ bc2,
                                                  float* __restrict__ out, int E) {
  int e = blockIdx.x * 4 + (threadIdx.x >> 6);
  int lane = threadIdx.x & 63;
  if (e >= E) return;
  int s = ei[e], t = ei[E + e];
  float h = fmaxf(ABt[(size_t)s * 64 + lane] + ABb[(size_t)t * 64 + lane] + bc1[lane], 0.0f);
  float r = wsum(h * Wc2[lane]);
  if (lane == 0) out[e] = r + bc2[0];
}

// ============================================================================
extern "C" void kernel_launch(void* const* d_in, const int* in_sizes, int n_in,
                              void* d_out, int out_size, void* d_ws, size_t ws_size,
                              hipStream_t stream) {
  const float* x = (const float*)d_in[0];
  const float* edge_attr = (const float*)d_in[1];
  const int* ei = (const int*)d_in[2];
  const int* zk = (const int*)d_in[3];
  const float* z_table = (const float*)d_in[4];
  const float* W_node = (const float*)d_in[5];
  const float* b_node = (const float*)d_in[6];
  const float* W_edge = (const float*)d_in[7];
  const float* b_edge = (const float*)d_in[8];
  const float* cn_w1 = (const float*)d_in[9];
  const float* cn_b1 = (const float*)d_in[10];
  const float* cn_w2 = (const float*)d_in[11];
  const float* cn_b2 = (const float*)d_in[12];
  const float* cn_cw1 = (const float*)d_in[13];
  const float* cn_cb1 = (const float*)d_in[14];
  const float* cn_cw2 = (const float*)d_in[15];
  const float* cn_cb2 = (const float*)d_in[16];
  const float* ce_w1 = (const float*)d_in[17];
  const float* ce_b1 = (const float*)d_in[18];
  const float* ce_w2 = (const float*)d_in[19];
  const float* ce_b2 = (const float*)d_in[20];
  const float* ce_cw1 = (const float*)d_in[21];
  const float* ce_cb1 = (const float*)d_in[22];
  const float* ce_cw2 = (const float*)d_in[23];
  const float* ce_cb2 = (const float*)d_in[24];
  const float* ln_comb_g = (const float*)d_in[25];
  const float* ln_comb_b = (const float*)d_in[26];
  const float* Wq = (const float*)d_in[27];
  const float* bq = (const float*)d_in[28];
  const float* Wk = (const float*)d_in[29];
  const float* bk = (const float*)d_in[30];
  const float* Wv = (const float*)d_in[31];
  const float* bv = (const float*)d_in[32];
  const float* Wskip = (const float*)d_in[33];
  const float* bskip = (const float*)d_in[34];
  const float* ln_tc_g = (const float*)d_in[35];
  const float* ln_tc_b = (const float*)d_in[36];
  const float* Wpn = (const float*)d_in[37];
  const float* bpn = (const float*)d_in[38];
  const float* Wpe = (const float*)d_in[39];
  const float* bpe = (const float*)d_in[40];
  const float* Wg = (const float*)d_in[41];
  const float* bg = (const float*)d_in[42];
  const float* Wc1 = (const float*)d_in[43];
  const float* bc1 = (const float*)d_in[44];
  const float* Wc2 = (const float*)d_in[45];
  const float* bc2 = (const float*)d_in[46];
  float* out = (float*)d_out;

  const int N = in_sizes[0] / 6;   // 50000
  const int E = in_sizes[2] / 2;   // 100000
  const int E2 = 2 * E;

  // ---- workspace carve (~214 MB peak) ----
  char* p = (char*)d_ws;
  auto carve = [&](size_t bytes) -> void* {
    void* r = (void*)p;
    p += (bytes + 255) & ~(size_t)255;
    return r;
  };
  unsigned short* qo = (unsigned short*)carve((size_t)N * 256 * 2);    // Q bf16
  unsigned short* skipb = (unsigned short*)carve((size_t)N * 256 * 2); // skip bf16 | P(fp32) aliases here
  unsigned short* kvb = (unsigned short*)carve((size_t)N * 512 * 2);   // K|V bf16
  unsigned short* aob = (unsigned short*)carve((size_t)N * 256 * 2);   // attn out bf16 -> AB f32
  float* ef = (float*)carve((size_t)E2 * 64 * 4);
  float* nf = (float*)carve((size_t)N * 64 * 4);
  unsigned short* comb = (unsigned short*)carve((size_t)N * 128 * 2);
  unsigned short* W1t = (unsigned short*)carve((size_t)3 * 1024 * 128 * 2);
  float* bias1 = (float*)carve((size_t)3 * 1024 * 4);
  unsigned short* B2t = (unsigned short*)carve((size_t)3 * 256 * 256 * 2);
  float* bias2 = (float*)carve((size_t)3 * 256 * 4);
  unsigned short* Wg1t = (unsigned short*)carve((size_t)3 * 64 * 64 * 2);
  unsigned short* Wc1t = (unsigned short*)carve((size_t)2 * 64 * 64 * 2);
  int* cnt = (int*)carve((size_t)N * 4);
  int* cur = (int*)carve((size_t)N * 4);
  int* off = (int*)carve((size_t)(N + 1) * 4);
  int* elist = (int*)carve((size_t)E2 * 4);
  int* bsum = (int*)carve((size_t)256 * 4);
  int* boff = (int*)carve((size_t)256 * 4);
  float* pm = (float*)carve((size_t)PBLK * 64 * 4);
  float* ps = (float*)carve((size_t)PBLK * 64 * 4);
  float* cwv = (float*)carve(64 * 4);
  float* spmax = (float*)carve((size_t)E2 * 4);
  float* spmean = (float*)carve((size_t)E2 * 4);
  float* sconv = (float*)carve((size_t)E2 * 4);
  size_t need = (size_t)(p - (char*)d_ws);

  // P [N,256] fp32 (51.2MB) aliases skipb(25.6) + first half of kvb(25.6):
  // both are dead once k_attn has run; P is consumed by the gate kernels
  // before the next iteration's QKVS GEMM rewrites skipb/kvb.
  float* P = (float*)skipb;
  float* ABt = (float*)aob;
  float* ABb = (float*)aob + (size_t)N * 64;

  auto cdiv = [](int a, int b) { return (a + b - 1) / b; };

  if (ws_size < need) {
    k_sentinel<<<cdiv(E, 256), 256, 0, stream>>>(out, E);
    return;
  }

  // ---- CSR by dst (multi-block scan) ----
  k_zero2<<<cdiv(N, 256), 256, 0, stream>>>(cnt, cur, N);
  k_hist<<<cdiv(E2, 256), 256, 0, stream>>>(ei, cnt, E);
  const int nblk = cdiv(N, 1024);
  k_scan1<<<nblk, 256, 0, stream>>>(cnt, off, bsum, N);
  k_scan2<<<1, 64, 0, stream>>>(bsum, boff, off, N, nblk);
  k_scan3<<<cdiv(N, 256), 256, 0, stream>>>(off, boff, N);
  k_scatter<<<cdiv(E2, 256), 256, 0, stream>>>(ei, off, cur, elist, E);

  // ---- pack weights (bf16 transposed) ----
  const int PACK = 3 * 1024 * 128 + 3 * 1024 + 3 * 256 * 256 + 3 * 256 + 3 * 64 * 64 + 2 * 64 * 64;
  k_packW<<<cdiv(PACK, 256), 256, 0, stream>>>(Wq, Wk, Wv, Wskip, bq, bk, bv, bskip,
                                               Wpn, Wpe, bpn, bpe, Wg, Wc1,
                                               W1t, bias1, B2t, bias2, Wg1t, Wc1t);

  // ---- embeddings ----
  k_node_embed<<<cdiv(N, 4), 256, 0, stream>>>(x, zk, z_table, W_node, b_node, nf, N);
  k_edge_embed<<<cdiv(E2, 4), 256, 0, stream>>>(x, edge_attr, ei, W_edge, b_edge, ef, E);

  // ---- CBAM on nodes then edges ----
  auto run_cbam = [&](float* buf, int rows, const float* w1, const float* b1, const float* w2,
                      const float* b2, const float* cw1, const float* cb1, const float* cw2,
                      const float* cb2) {
    k_pool_partial<<<PBLK, 256, 0, stream>>>(buf, rows, pm, ps);
    k_pool_final<<<1, 256, 0, stream>>>(pm, ps, rows, PBLK, w1, b1, w2, b2, cwv);
    k_chan_sp<<<cdiv(rows, 16), 256, 0, stream>>>(buf, rows, cwv, spmax, spmean);
    k_conv<<<cdiv(rows, 256), 256, 0, stream>>>(spmax, spmean, rows, cw1, cb1, cw2, cb2, sconv);
    k_row_scale<<<cdiv(rows * 16, 256), 256, 0, stream>>>(buf, rows, sconv);
  };
  run_cbam(nf, N, cn_w1, cn_b1, cn_w2, cn_b2, cn_cw1, cn_cb1, cn_cw2, cn_cb2);
  run_cbam(ef, E2, ce_w1, ce_b1, ce_w2, ce_b2, ce_cw1, ce_cb1, ce_cw2, ce_cb2);

  // ---- T = 3 message-passing iterations ----
  dim3 gqkvs(cdiv(N, 128), 8);
  dim3 gp(cdiv(N, 128), 2);
  for (int i = 0; i < 3; ++i) {
    k_aggcomb<<<cdiv(N, 4), 256, 0, stream>>>(ef, nf, off, elist, comb,
                                              ln_comb_g + (size_t)i * 128, ln_comb_b + (size_t)i * 128, N);
    gemm_mfma<0><<<gqkvs, 256, 0, stream>>>(comb, N, 128, W1t + (size_t)i * 131072,
                                            bias1 + (size_t)i * 1024, nullptr, qo, kvb, skipb);
    k_attn<<<cdiv(N, 4), 256, 0, stream>>>(qo, kvb, skipb, off, elist, ei, aob,
                                           ln_tc_g + (size_t)i * 256, ln_tc_b + (size_t)i * 256, N);
    gemm_mfma<1><<<gp, 256, 0, stream>>>(aob, N, 256, B2t + (size_t)i * 65536,
                                         bias2 + (size_t)i * 256, P, nullptr, nullptr, nullptr);
    gemm_gate<1><<<cdiv(N, 128), 256, 0, stream>>>(nf, N, Wg1t + (size_t)i * 4096, P,
                                                   bg + (size_t)i * 64, nullptr, nf);
    gemm_gate<2><<<cdiv(E2, 128), 256, 0, stream>>>(ef, E2, Wg1t + (size_t)i * 4096, P,
                                                    bg + (size_t)i * 64, ei, ef);
  }

  // ---- classifier ----
  gemm_gate<0><<<cdiv(N, 128), 256, 0, stream>>>(nf, N, Wc1t, nullptr, nullptr, nullptr, ABt);
  gemm_gate<0><<<cdiv(N, 128), 256, 0, stream>>>(nf, N, Wc1t + 4096, nullptr, nullptr, nullptr, ABb);
  k_clf_pair<<<cdiv(E, 4), 256, 0, stream>>>(ABt, ABb, ei, bc1, Wc2, bc2, out, E);
  (void)out_size;
  (void)n_in;
}

// Round 8
// 1009.362 us; speedup vs baseline: 1.0506x; 1.0506x over previous
//
#include <hip/hip_runtime.h>

// ============================================================================
// New_LinkNet GNN forward — MFMA bf16 GEMMs + fused gate updates.
// Round-8: REVERT gemm_mfma to round-6 structure (64-wide K chunks, 32KB LDS,
// 0 bank conflicts) after round-7's full-K=128 tile regressed (256B row
// stride broke the XOR swizzle -> 1.6M conflicts, occupancy 27->19%).
// KEPT from round 7: Q stored bf16 (-27MB HBM write+read), P aliasing (~214MB).
// ============================================================================

#define LN_EPS 1e-5f
#define PBLK 512

typedef __attribute__((ext_vector_type(8))) short bf16x8;
typedef __attribute__((ext_vector_type(4))) float f32x4;

static __device__ __forceinline__ float wsum(float v) {
#pragma unroll
  for (int d = 32; d > 0; d >>= 1) v += __shfl_xor(v, d);
  return v;
}
static __device__ __forceinline__ float sigm(float x) { return 1.0f / (1.0f + __expf(-x)); }
static __device__ __forceinline__ unsigned short f2bf(float f) {
  unsigned int u = __float_as_uint(f);
  u += 0x7FFFu + ((u >> 16) & 1u);
  return (unsigned short)(u >> 16);
}
static __device__ __forceinline__ float bf2f(unsigned short b) {
  return __uint_as_float(((unsigned int)b) << 16);
}

// ---------------- util ----------------
__global__ __launch_bounds__(256) void k_zero2(int* __restrict__ a, int* __restrict__ b, int n) {
  int i = blockIdx.x * 256 + threadIdx.x;
  if (i < n) { a[i] = 0; b[i] = 0; }
}

__global__ __launch_bounds__(256) void k_sentinel(float* __restrict__ out, int n) {
  int i = blockIdx.x * 256 + threadIdx.x;
  if (i < n) out[i] = 1.0e6f;
}

// ---------------- CSR build (by dst) ----------------
__global__ __launch_bounds__(256) void k_hist(const int* __restrict__ ei, int* __restrict__ cnt, int E) {
  int e = blockIdx.x * 256 + threadIdx.x;
  if (e >= 2 * E) return;
  int d = (e < E) ? ei[E + e] : ei[e - E];
  atomicAdd(&cnt[d], 1);
}

__global__ __launch_bounds__(256) void k_scan1(const int* __restrict__ cnt, int* __restrict__ off,
                                               int* __restrict__ bsum, int n) {
  const int t = threadIdx.x;
  const int lane = t & 63, w = t >> 6;
  const int i0 = blockIdx.x * 1024 + t * 4;
  int v0 = (i0 + 0 < n) ? cnt[i0 + 0] : 0;
  int v1 = (i0 + 1 < n) ? cnt[i0 + 1] : 0;
  int v2 = (i0 + 2 < n) ? cnt[i0 + 2] : 0;
  int v3 = (i0 + 3 < n) ? cnt[i0 + 3] : 0;
  int s = v0 + v1 + v2 + v3;
  int sc = s;
#pragma unroll
  for (int d = 1; d < 64; d <<= 1) {
    int tv = __shfl_up(sc, d);
    if (lane >= d) sc += tv;
  }
  __shared__ int wsums[4];
  if (lane == 63) wsums[w] = sc;
  __syncthreads();
  int wbase = 0;
#pragma unroll
  for (int k = 0; k < 4; ++k)
    if (k < w) wbase += wsums[k];
  int run = wbase + sc - s;
  if (i0 + 0 < n) off[i0 + 0] = run; run += v0;
  if (i0 + 1 < n) off[i0 + 1] = run; run += v1;
  if (i0 + 2 < n) off[i0 + 2] = run; run += v2;
  if (i0 + 3 < n) off[i0 + 3] = run;
  if (t == 255) bsum[blockIdx.x] = wbase + sc;
}

__global__ __launch_bounds__(64) void k_scan2(const int* __restrict__ bsum, int* __restrict__ boff,
                                              int* __restrict__ off, int n, int nblk) {
  const int lane = threadIdx.x;
  int carry = 0;
  for (int base = 0; base < nblk; base += 64) {
    int i = base + lane;
    int v = (i < nblk) ? bsum[i] : 0;
    int sc = v;
#pragma unroll
    for (int d = 1; d < 64; d <<= 1) {
      int tv = __shfl_up(sc, d);
      if (lane >= d) sc += tv;
    }
    if (i < nblk) boff[i] = carry + sc - v;
    carry += __shfl(sc, 63);
  }
  if (lane == 0) off[n] = carry;
}

__global__ __launch_bounds__(256) void k_scan3(int* __restrict__ off, const int* __restrict__ boff, int n) {
  int i = blockIdx.x * 256 + threadIdx.x;
  if (i < n) off[i] += boff[i >> 10];
}

__global__ __launch_bounds__(256) void k_scatter(const int* __restrict__ ei, const int* __restrict__ off,
                                                 int* __restrict__ cur, int* __restrict__ elist, int E) {
  int e = blockIdx.x * 256 + threadIdx.x;
  if (e >= 2 * E) return;
  int d = (e < E) ? ei[E + e] : ei[e - E];
  int pos = atomicAdd(&cur[d], 1);
  elist[off[d] + pos] = e;
}

// ---------------- pack all transposed bf16 weights ----------------
__global__ __launch_bounds__(256) void k_packW(
    const float* __restrict__ Wq, const float* __restrict__ Wk, const float* __restrict__ Wv,
    const float* __restrict__ Ws, const float* __restrict__ bq, const float* __restrict__ bk,
    const float* __restrict__ bv, const float* __restrict__ bs,
    const float* __restrict__ Wpn, const float* __restrict__ Wpe,
    const float* __restrict__ bpn, const float* __restrict__ bpe,
    const float* __restrict__ Wg, const float* __restrict__ Wc1,
    unsigned short* __restrict__ W1t, float* __restrict__ bias1,
    unsigned short* __restrict__ B2t, float* __restrict__ bias2,
    unsigned short* __restrict__ Wg1t, unsigned short* __restrict__ Wc1t) {
  const int S1 = 3 * 1024 * 128, S2 = 3 * 1024, S3 = 3 * 256 * 256, S4 = 3 * 256;
  const int S5 = 3 * 64 * 64, S6 = 2 * 64 * 64;
  int idx = blockIdx.x * 256 + threadIdx.x;
  if (idx < S1) {
    int i = idx / 131072, r = idx % 131072;
    int col = r >> 7, k = r & 127;
    int m = col >> 8, cc = col & 255;
    const float* W = (m == 0) ? Wq : (m == 1) ? Wk : (m == 2) ? Wv : Ws;
    W1t[idx] = f2bf(W[i * 32768 + k * 256 + cc]);
  } else if (idx < S1 + S2) {
    int j = idx - S1;
    int i = j >> 10, col = j & 1023;
    int m = col >> 8, cc = col & 255;
    const float* bsrc = (m == 0) ? bq : (m == 1) ? bk : (m == 2) ? bv : bs;
    bias1[j] = bsrc[i * 256 + cc];
  } else if (idx < S1 + S2 + S3) {
    int j = idx - S1 - S2;
    int i = j / 65536, r = j % 65536;
    int col = r >> 8, k = r & 255;
    float v;
    if (col < 64) v = Wpn[i * 16384 + k * 64 + col];
    else if (col < 128) v = Wpe[i * 16384 + k * 64 + (col - 64)];
    else {
      const float* Wsrc = (col < 192) ? Wpn : Wpe;
      int cc = col & 63;
      float acc = 0.f;
      for (int jj = 0; jj < 64; ++jj)
        acc = fmaf(Wsrc[i * 16384 + k * 64 + jj], Wg[i * 8192 + (64 + jj) * 64 + cc], acc);
      v = acc;
    }
    B2t[j] = f2bf(v);
  } else if (idx < S1 + S2 + S3 + S4) {
    int j = idx - S1 - S2 - S3;
    int i = j >> 8, col = j & 255;
    float v;
    if (col < 64) v = bpn[i * 64 + col];
    else if (col < 128) v = bpe[i * 64 + col - 64];
    else {
      const float* bsrc = (col < 192) ? bpn : bpe;
      int cc = col & 63;
      float acc = 0.f;
      for (int jj = 0; jj < 64; ++jj)
        acc = fmaf(bsrc[i * 64 + jj], Wg[i * 8192 + (64 + jj) * 64 + cc], acc);
      v = acc;
    }
    bias2[j] = v;
  } else if (idx < S1 + S2 + S3 + S4 + S5) {
    int j = idx - S1 - S2 - S3 - S4;
    int i = j / 4096, r = j % 4096;
    int col = r >> 6, k = r & 63;
    Wg1t[j] = f2bf(Wg[i * 8192 + k * 64 + col]);
  } else if (idx < S1 + S2 + S3 + S4 + S5 + S6) {
    int j = idx - S1 - S2 - S3 - S4 - S5;
    int h = j / 4096, r = j % 4096;
    int col = r >> 6, k = r & 63;
    Wc1t[j] = f2bf(Wc1[(h * 64 + k) * 64 + col]);
  }
}

// ---------------- embeddings ----------------
__global__ __launch_bounds__(256) void k_node_embed(
    const float* __restrict__ x, const int* __restrict__ zk, const float* __restrict__ zt,
    const float* __restrict__ Wn, const float* __restrict__ bn, float* __restrict__ nf, int N) {
  int n = blockIdx.x * 4 + (threadIdx.x >> 6);
  int lane = threadIdx.x & 63;
  if (n >= N) return;
  const float* xr = x + (size_t)n * 6;
  float acc = bn[lane];
#pragma unroll
  for (int d = 0; d < 6; ++d) acc = fmaf(xr[d], Wn[d * 64 + lane], acc);
  int zi = __float2int_rn(xr[2]);
  int idx = 0;
#pragma unroll
  for (int t = 5; t >= 0; --t)
    if (zi == zk[t]) idx = t;
  nf[(size_t)n * 64 + lane] = fmaxf(acc, 0.0f) + zt[idx * 64 + lane];
}

__global__ __launch_bounds__(256) void k_edge_embed(
    const float* __restrict__ x, const float* __restrict__ ea, const int* __restrict__ ei,
    const float* __restrict__ We, const float* __restrict__ be, float* __restrict__ ef, int E) {
  int e = blockIdx.x * 4 + (threadIdx.x >> 6);
  int lane = threadIdx.x & 63;
  if (e >= 2 * E) return;
  int e0 = (e < E) ? e : e - E;
  int s = ei[e];
  int d = (e < E) ? ei[E + e] : ei[e - E];
  const float* ar = ea + (size_t)e0 * 4;
  const float* xs = x + (size_t)s * 6;
  const float* xd = x + (size_t)d * 6;
  float in[7];
  in[0] = ar[0]; in[1] = ar[1]; in[2] = ar[2]; in[3] = ar[3];
  in[4] = xs[0] - xd[0]; in[5] = xs[1] - xd[1]; in[6] = xs[2] - xd[2];
  float acc = be[lane];
#pragma unroll
  for (int dd = 0; dd < 7; ++dd) acc = fmaf(in[dd], We[dd * 64 + lane], acc);
  ef[(size_t)e * 64 + lane] = fmaxf(acc, 0.0f);
}

// ---------------- CBAM (vectorized) ----------------
__global__ __launch_bounds__(256) void k_pool_partial(const float* __restrict__ buf, int n,
                                                      float* __restrict__ pm, float* __restrict__ ps) {
  const int w = threadIdx.x >> 6, l = threadIdx.x & 63;
  const int rsub = l >> 4, c4 = (l & 15) << 2;
  float4 mx = make_float4(-INFINITY, -INFINITY, -INFINITY, -INFINITY);
  float4 sm = make_float4(0.f, 0.f, 0.f, 0.f);
  for (int r = blockIdx.x * 16 + w * 4 + rsub; r < n; r += gridDim.x * 16) {
    float4 v = *(const float4*)(buf + (size_t)r * 64 + c4);
    mx.x = fmaxf(mx.x, v.x); mx.y = fmaxf(mx.y, v.y);
    mx.z = fmaxf(mx.z, v.z); mx.w = fmaxf(mx.w, v.w);
    sm.x += v.x; sm.y += v.y; sm.z += v.z; sm.w += v.w;
  }
#pragma unroll
  for (int d = 16; d < 64; d <<= 1) {
    mx.x = fmaxf(mx.x, __shfl_xor(mx.x, d)); mx.y = fmaxf(mx.y, __shfl_xor(mx.y, d));
    mx.z = fmaxf(mx.z, __shfl_xor(mx.z, d)); mx.w = fmaxf(mx.w, __shfl_xor(mx.w, d));
    sm.x += __shfl_xor(sm.x, d); sm.y += __shfl_xor(sm.y, d);
    sm.z += __shfl_xor(sm.z, d); sm.w += __shfl_xor(sm.w, d);
  }
  __shared__ float smx[4][64], ssm[4][64];
  if (l < 16) {
    *(float4*)&smx[w][c4] = mx;
    *(float4*)&ssm[w][c4] = sm;
  }
  __syncthreads();
  if (threadIdx.x < 64) {
    int t = threadIdx.x;
    float m2 = fmaxf(fmaxf(smx[0][t], smx[1][t]), fmaxf(smx[2][t], smx[3][t]));
    float s2 = ssm[0][t] + ssm[1][t] + ssm[2][t] + ssm[3][t];
    pm[blockIdx.x * 64 + t] = m2;
    ps[blockIdx.x * 64 + t] = s2;
  }
}

__global__ __launch_bounds__(256) void k_pool_final(
    const float* __restrict__ pm, const float* __restrict__ ps, int n, int nblk,
    const float* __restrict__ w1, const float* __restrict__ b1,
    const float* __restrict__ w2, const float* __restrict__ b2, float* __restrict__ cw) {
  __shared__ float redm[4][64], reds[4][64];
  __shared__ float cat[128];
  __shared__ float hid[4];
  int t = threadIdx.x;
  int g = t >> 6, col = t & 63;
  float mx = -INFINITY, sm = 0.0f;
  for (int p = g; p < nblk; p += 4) {
    mx = fmaxf(mx, pm[p * 64 + col]);
    sm += ps[p * 64 + col];
  }
  redm[g][col] = mx;
  reds[g][col] = sm;
  __syncthreads();
  if (t < 64) {
    float m2 = fmaxf(fmaxf(redm[0][t], redm[1][t]), fmaxf(redm[2][t], redm[3][t]));
    float s2 = reds[0][t] + reds[1][t] + reds[2][t] + reds[3][t];
    cat[t] = m2;
    cat[64 + t] = s2 / (float)n;
  }
  __syncthreads();
  if (t < 4) {
    float a = b1[t];
    for (int k = 0; k < 128; ++k) a = fmaf(cat[k], w1[k * 4 + t], a);
    hid[t] = fmaxf(a, 0.0f);
  }
  __syncthreads();
  if (t < 64) {
    float a = b2[t];
#pragma unroll
    for (int h = 0; h < 4; ++h) a = fmaf(hid[h], w2[h * 64 + t], a);
    cw[t] = sigm(a);
  }
}

__global__ __launch_bounds__(256) void k_chan_sp(float* __restrict__ buf, int n,
                                                 const float* __restrict__ cw,
                                                 float* __restrict__ spmax, float* __restrict__ spmean) {
  const int w = threadIdx.x >> 6, l = threadIdx.x & 63;
  const int rsub = l >> 4, c4 = (l & 15) << 2;
  int r = blockIdx.x * 16 + w * 4 + rsub;
  if (r >= n) return;
  float4 cwv = *(const float4*)(cw + c4);
  float4 v = *(const float4*)(buf + (size_t)r * 64 + c4);
  v.x *= cwv.x; v.y *= cwv.y; v.z *= cwv.z; v.w *= cwv.w;
  *(float4*)(buf + (size_t)r * 64 + c4) = v;
  float mx = fmaxf(fmaxf(v.x, v.y), fmaxf(v.z, v.w));
  float sm = v.x + v.y + v.z + v.w;
#pragma unroll
  for (int d = 1; d < 16; d <<= 1) {
    mx = fmaxf(mx, __shfl_xor(mx, d));
    sm += __shfl_xor(sm, d);
  }
  if ((l & 15) == 0) {
    spmax[r] = mx;
    spmean[r] = sm * (1.0f / 64.0f);
  }
}

__global__ __launch_bounds__(256) void k_conv(const float* __restrict__ spmax, const float* __restrict__ spmean,
                                              int n, const float* __restrict__ w1, const float* __restrict__ b1,
                                              const float* __restrict__ w2, const float* __restrict__ b2,
                                              float* __restrict__ s) {
  __shared__ float tl[258];
  int base = blockIdx.x * 256;
  for (int q = threadIdx.x; q < 258; q += 256) {
    int p = base - 1 + q;
    float t = 0.0f;
    if (p >= 0 && p < n) {
      float a = b1[0];
#pragma unroll
      for (int h = 0; h < 5; ++h) {
        int pp = p + h - 2;
        if (pp >= 0 && pp < n) a += spmax[pp] * w1[h] + spmean[pp] * w1[5 + h];
      }
      t = fmaxf(a, 0.0f);
    }
    tl[q] = t;
  }
  __syncthreads();
  int o = base + threadIdx.x;
  if (o < n) {
    float a = b2[0] + tl[threadIdx.x] * w2[0] + tl[threadIdx.x + 1] * w2[1] + tl[threadIdx.x + 2] * w2[2];
    s[o] = sigm(a);
  }
}

__global__ __launch_bounds__(256) void k_row_scale(float* __restrict__ buf, int n, const float* __restrict__ s) {
  int i4 = blockIdx.x * 256 + threadIdx.x;
  if (i4 >= n * 16) return;
  int r = i4 >> 4;
  float sc = s[r];
  float4 v = *(const float4*)(buf + (size_t)i4 * 4);
  v.x *= sc; v.y *= sc; v.z *= sc; v.w *= sc;
  *(float4*)(buf + (size_t)i4 * 4) = v;
}

// ---------------- agg + concat-LN (bf16 out) ----------------
__global__ __launch_bounds__(256) void k_aggcomb(const float* __restrict__ ef, const float* __restrict__ nf,
                                                 const int* __restrict__ off, const int* __restrict__ elist,
                                                 unsigned short* __restrict__ comb, const float* __restrict__ g,
                                                 const float* __restrict__ b, int N) {
  int n = blockIdx.x * 4 + (threadIdx.x >> 6);
  int lane = threadIdx.x & 63;
  if (n >= N) return;
  float agg = 0.0f;
  int i0 = off[n], i1 = off[n + 1];
  for (int idx = i0; idx < i1; ++idx) agg += ef[(size_t)elist[idx] * 64 + lane];
  float y0 = nf[(size_t)n * 64 + lane];
  float y1 = agg - y0;
  float s1 = wsum(y0 + y1);
  float s2 = wsum(y0 * y0 + y1 * y1);
  float mu = s1 * (1.0f / 128.0f);
  float var = s2 * (1.0f / 128.0f) - mu * mu;
  float rs = rsqrtf(fmaxf(var, 0.0f) + LN_EPS);
  comb[(size_t)n * 128 + lane] = f2bf((y0 - mu) * rs * g[lane] + b[lane]);
  comb[(size_t)n * 128 + 64 + lane] = f2bf((y1 - mu) * rs * g[64 + lane] + b[64 + lane]);
}

// ---------------- MFMA GEMM: C[M,NC] = A[M,K](bf16) @ Bt[NC,K](bf16) -------
// Round-6 structure: 64-wide K chunks, 32KB LDS, 0 bank conflicts.
// MODE 0: NC=1024, bf16 epilogue split Q|K|V|S. MODE 1: fp32 out ld=256.
template <int MODE>
__global__ __launch_bounds__(256) void gemm_mfma(
    const unsigned short* __restrict__ A, int M, int K,
    const unsigned short* __restrict__ Bt, const float* __restrict__ bias,
    float* __restrict__ outF, unsigned short* __restrict__ outQ,
    unsigned short* __restrict__ outK, unsigned short* __restrict__ outS) {
  __shared__ unsigned short As[128 * 64];
  __shared__ unsigned short Bs[128 * 64];
  const int tid = threadIdx.x;
  const int bm = blockIdx.x * 128;
  const int bn = blockIdx.y * 128;
  const int wid = tid >> 6, lane = tid & 63;
  const int wr = (wid >> 1) * 64, wc = (wid & 1) * 64;
  const int lrow = lane & 15, lkb = (lane >> 4) * 8;
  f32x4 acc[4][4];
#pragma unroll
  for (int m = 0; m < 4; ++m)
#pragma unroll
    for (int n = 0; n < 4; ++n) acc[m][n] = (f32x4){0.f, 0.f, 0.f, 0.f};

  for (int k0 = 0; k0 < K; k0 += 64) {
#pragma unroll
    for (int l = 0; l < 4; ++l) {
      int c = tid + l * 256;
      int row = c >> 3, kc = (c & 7) * 8;
      int sw = row * 64 + (kc ^ ((row & 7) << 3));
      int grow = bm + row;
      bf16x8 v = {0, 0, 0, 0, 0, 0, 0, 0};
      if (grow < M) v = *(const bf16x8*)(A + (size_t)grow * K + k0 + kc);
      *(bf16x8*)&As[sw] = v;
      int gcol = bn + row;
      *(bf16x8*)&Bs[sw] = *(const bf16x8*)(Bt + (size_t)gcol * K + k0 + kc);
    }
    __syncthreads();
#pragma unroll
    for (int ks = 0; ks < 2; ++ks) {
      const int ke = ks * 32 + lkb;
      bf16x8 af[4], bfr[4];
#pragma unroll
      for (int m = 0; m < 4; ++m) {
        int row = wr + m * 16 + lrow;
        af[m] = *(const bf16x8*)&As[row * 64 + (ke ^ ((row & 7) << 3))];
      }
#pragma unroll
      for (int n = 0; n < 4; ++n) {
        int col = wc + n * 16 + lrow;
        bfr[n] = *(const bf16x8*)&Bs[col * 64 + (ke ^ ((col & 7) << 3))];
      }
#pragma unroll
      for (int m = 0; m < 4; ++m)
#pragma unroll
        for (int n = 0; n < 4; ++n)
          acc[m][n] = __builtin_amdgcn_mfma_f32_16x16x32_bf16(af[m], bfr[n], acc[m][n], 0, 0, 0);
    }
    __syncthreads();
  }

  const int colw = lane & 15, rq = (lane >> 4) * 4;
  const int proj = bn >> 8;
#pragma unroll
  for (int m = 0; m < 4; ++m) {
#pragma unroll
    for (int n = 0; n < 4; ++n) {
      int gcol = bn + wc + n * 16 + colw;
      float bv = bias[gcol];
#pragma unroll
      for (int r = 0; r < 4; ++r) {
        int grow = bm + wr + m * 16 + rq + r;
        if (grow >= M) continue;
        float v = acc[m][n][r] + bv;
        if (MODE == 1) {
          outF[(size_t)grow * 256 + gcol] = v;
        } else {
          int cc = gcol & 255;
          if (proj == 0) outQ[(size_t)grow * 256 + cc] = f2bf(v);
          else if (proj == 1) outK[(size_t)grow * 512 + cc] = f2bf(v);
          else if (proj == 2) outK[(size_t)grow * 512 + 256 + cc] = f2bf(v);
          else outS[(size_t)grow * 256 + cc] = f2bf(v);
        }
      }
    }
  }
}

// ------ MFMA [M,64]@[64,64] with fused epilogue ------
template <int UPD>
__global__ __launch_bounds__(256) void gemm_gate(
    const float* __restrict__ Af, int M, const unsigned short* __restrict__ Wt,
    const float* __restrict__ P, const float* __restrict__ bgv,
    const int* __restrict__ ei, float* __restrict__ upd) {
  __shared__ unsigned short As[128 * 64];
  __shared__ unsigned short Ws[64 * 64];
  const int tid = threadIdx.x;
  const int bm = blockIdx.x * 128;
#pragma unroll
  for (int l = 0; l < 8; ++l) {
    int u = tid + l * 256;
    int row = u >> 4, k4 = (u & 15) << 2;
    int grow = bm + row;
    float4 v = make_float4(0.f, 0.f, 0.f, 0.f);
    if (grow < M) v = *(const float4*)(Af + (size_t)grow * 64 + k4);
    union { unsigned short h[4]; uint2 q; } pk;
    pk.h[0] = f2bf(v.x); pk.h[1] = f2bf(v.y); pk.h[2] = f2bf(v.z); pk.h[3] = f2bf(v.w);
    *(uint2*)&As[row * 64 + (k4 ^ ((row & 7) << 3))] = pk.q;
  }
#pragma unroll
  for (int l = 0; l < 2; ++l) {
    int u = tid + l * 256;
    int row = u >> 3, kc = (u & 7) * 8;
    *(bf16x8*)&Ws[row * 64 + (kc ^ ((row & 7) << 3))] = *(const bf16x8*)(Wt + row * 64 + kc);
  }
  __syncthreads();
  const int wid = tid >> 6, lane = tid & 63;
  const int wr = wid * 32;
  const int lrow = lane & 15, lkb = (lane >> 4) * 8;
  f32x4 acc[2][4];
#pragma unroll
  for (int m = 0; m < 2; ++m)
#pragma unroll
    for (int n = 0; n < 4; ++n) acc[m][n] = (f32x4){0.f, 0.f, 0.f, 0.f};
#pragma unroll
  for (int ks = 0; ks < 2; ++ks) {
    const int ke = ks * 32 + lkb;
    bf16x8 af[2], wf[4];
#pragma unroll
    for (int m = 0; m < 2; ++m) {
      int row = wr + m * 16 + lrow;
      af[m] = *(const bf16x8*)&As[row * 64 + (ke ^ ((row & 7) << 3))];
    }
#pragma unroll
    for (int n = 0; n < 4; ++n) {
      int col = n * 16 + lrow;
      wf[n] = *(const bf16x8*)&Ws[col * 64 + (ke ^ ((col & 7) << 3))];
    }
#pragma unroll
    for (int m = 0; m < 2; ++m)
#pragma unroll
      for (int n = 0; n < 4; ++n)
        acc[m][n] = __builtin_amdgcn_mfma_f32_16x16x32_bf16(af[m], wf[n], acc[m][n], 0, 0, 0);
  }
  const int colw = lane & 15, rq = (lane >> 4) * 4;
#pragma unroll
  for (int m = 0; m < 2; ++m) {
#pragma unroll
    for (int r = 0; r < 4; ++r) {
      int e = bm + wr + m * 16 + rq + r;
      if (e >= M) continue;
      if (UPD == 0) {
#pragma unroll
        for (int n = 0; n < 4; ++n) upd[(size_t)e * 64 + n * 16 + colw] = acc[m][n][r];
      } else {
        int s = (UPD == 2) ? ei[e] : e;
        const float* Pr = P + (size_t)s * 256;
        const int voff = (UPD == 1) ? 128 : 192;
        const int poff = (UPD == 1) ? 0 : 64;
#pragma unroll
        for (int n = 0; n < 4; ++n) {
          int c = n * 16 + colw;
          float g = sigm(acc[m][n][r] + Pr[voff + c] + bgv[c]);
          size_t oi = (size_t)e * 64 + c;
          upd[oi] = upd[oi] * g + Pr[poff + c] * (1.0f - g);
        }
      }
    }
  }
}

// ---------------- attention: lane = (head, 4 cols); wide loads ----------
__global__ __launch_bounds__(256) void k_attn(const unsigned short* __restrict__ qo,
                                              const unsigned short* __restrict__ kv,
                                              const unsigned short* __restrict__ skipb, const int* __restrict__ off,
                                              const int* __restrict__ elist, const int* __restrict__ ei,
                                              unsigned short* __restrict__ aob,
                                              const float* __restrict__ g, const float* __restrict__ b, int N) {
  int n = blockIdx.x * 4 + (threadIdx.x >> 6);
  int lane = threadIdx.x & 63;
  if (n >= N) return;
  union { uint2 u; unsigned short h[4]; } qq;
  qq.u = *(const uint2*)(qo + (size_t)n * 256 + 4 * lane);
  float q0 = bf2f(qq.h[0]), q1 = bf2f(qq.h[1]), q2 = bf2f(qq.h[2]), q3 = bf2f(qq.h[3]);
  float m = -INFINITY, lsum = 0.f;
  float a0 = 0.f, a1 = 0.f, a2 = 0.f, a3 = 0.f;
  int i0 = off[n], i1 = off[n + 1];
  for (int idx = i0; idx < i1; ++idx) {
    int eid = elist[idx];
    int s = ei[eid];
    const unsigned short* kb = kv + (size_t)s * 512;
    union { uint2 u; unsigned short h[4]; } kk, vv;
    kk.u = *(const uint2*)(kb + 4 * lane);
    vv.u = *(const uint2*)(kb + 256 + 4 * lane);
    float d = q0 * bf2f(kk.h[0]) + q1 * bf2f(kk.h[1]) + q2 * bf2f(kk.h[2]) + q3 * bf2f(kk.h[3]);
#pragma unroll
    for (int dd = 1; dd < 16; dd <<= 1) d += __shfl_xor(d, dd);
    d *= 0.125f;
    float nm = fmaxf(m, d);
    float sc = __expf(m - nm);
    float p = __expf(d - nm);
    lsum = lsum * sc + p;
    a0 = fmaf(p, bf2f(vv.h[0]), a0 * sc);
    a1 = fmaf(p, bf2f(vv.h[1]), a1 * sc);
    a2 = fmaf(p, bf2f(vv.h[2]), a2 * sc);
    a3 = fmaf(p, bf2f(vv.h[3]), a3 * sc);
    m = nm;
  }
  union { uint2 u; unsigned short h[4]; } sb;
  sb.u = *(const uint2*)(skipb + (size_t)n * 256 + 4 * lane);
  float inv = (lsum > 0.f) ? 1.0f / lsum : 0.f;
  float v0 = bf2f(sb.h[0]) + a0 * inv;
  float v1 = bf2f(sb.h[1]) + a1 * inv;
  float v2 = bf2f(sb.h[2]) + a2 * inv;
  float v3 = bf2f(sb.h[3]) + a3 * inv;
  float s1 = wsum(v0 + v1 + v2 + v3);
  float s2 = wsum(v0 * v0 + v1 * v1 + v2 * v2 + v3 * v3);
  float mu = s1 * (1.0f / 256.0f);
  float var = s2 * (1.0f / 256.0f) - mu * mu;
  float rs = rsqrtf(fmaxf(var, 0.0f) + LN_EPS);
  float4 g4 = *(const float4*)(g + 4 * lane);
  float4 b4 = *(const float4*)(b + 4 * lane);
  union { uint2 u; unsigned short h[4]; } ob;
  ob.h[0] = f2bf((v0 - mu) * rs * g4.x + b4.x);
  ob.h[1] = f2bf((v1 - mu) * rs * g4.y + b4.y);
  ob.h[2] = f2bf((v2 - mu) * rs * g4.z + b4.z);
  ob.h[3] = f2bf((v3 - mu) * rs * g4.w + b4.w);
  *(uint2*)(aob + (size_t)n * 256 + 4 * lane) = ob.u;
}

// ---------------- classifier pair kernel ----------------
__global__ __launch_bounds__(256) void k_clf_pair(const float* __restrict__ ABt, const float* __restrict__ ABb,
                                                  const int* __restrict__ ei, const float* __restrict__ bc1,
                                                  const float* __restrict__ Wc2, const float* __restrict__ bc2,
                                                  float* __restrict__ out, int E) {
  int e = blockIdx.x * 4 + (threadIdx.x >> 6);
  int lane = threadIdx.x & 63;
  if (e >= E) return;
  int s = ei[e], t = ei[E + e];
  float h = fmaxf(ABt[(size_t)s * 64 + lane] + ABb[(size_t)t * 64 + lane] + bc1[lane], 0.0f);
  float r = wsum(h * Wc2[lane]);
  if (lane == 0) out[e] = r + bc2[0];
}

// ============================================================================
extern "C" void kernel_launch(void* const* d_in, const int* in_sizes, int n_in,
                              void* d_out, int out_size, void* d_ws, size_t ws_size,
                              hipStream_t stream) {
  const float* x = (const float*)d_in[0];
  const float* edge_attr = (const float*)d_in[1];
  const int* ei = (const int*)d_in[2];
  const int* zk = (const int*)d_in[3];
  const float* z_table = (const float*)d_in[4];
  const float* W_node = (const float*)d_in[5];
  const float* b_node = (const float*)d_in[6];
  const float* W_edge = (const float*)d_in[7];
  const float* b_edge = (const float*)d_in[8];
  const float* cn_w1 = (const float*)d_in[9];
  const float* cn_b1 = (const float*)d_in[10];
  const float* cn_w2 = (const float*)d_in[11];
  const float* cn_b2 = (const float*)d_in[12];
  const float* cn_cw1 = (const float*)d_in[13];
  const float* cn_cb1 = (const float*)d_in[14];
  const float* cn_cw2 = (const float*)d_in[15];
  const float* cn_cb2 = (const float*)d_in[16];
  const float* ce_w1 = (const float*)d_in[17];
  const float* ce_b1 = (const float*)d_in[18];
  const float* ce_w2 = (const float*)d_in[19];
  const float* ce_b2 = (const float*)d_in[20];
  const float* ce_cw1 = (const float*)d_in[21];
  const float* ce_cb1 = (const float*)d_in[22];
  const float* ce_cw2 = (const float*)d_in[23];
  const float* ce_cb2 = (const float*)d_in[24];
  const float* ln_comb_g = (const float*)d_in[25];
  const float* ln_comb_b = (const float*)d_in[26];
  const float* Wq = (const float*)d_in[27];
  const float* bq = (const float*)d_in[28];
  const float* Wk = (const float*)d_in[29];
  const float* bk = (const float*)d_in[30];
  const float* Wv = (const float*)d_in[31];
  const float* bv = (const float*)d_in[32];
  const float* Wskip = (const float*)d_in[33];
  const float* bskip = (const float*)d_in[34];
  const float* ln_tc_g = (const float*)d_in[35];
  const float* ln_tc_b = (const float*)d_in[36];
  const float* Wpn = (const float*)d_in[37];
  const float* bpn = (const float*)d_in[38];
  const float* Wpe = (const float*)d_in[39];
  const float* bpe = (const float*)d_in[40];
  const float* Wg = (const float*)d_in[41];
  const float* bg = (const float*)d_in[42];
  const float* Wc1 = (const float*)d_in[43];
  const float* bc1 = (const float*)d_in[44];
  const float* Wc2 = (const float*)d_in[45];
  const float* bc2 = (const float*)d_in[46];
  float* out = (float*)d_out;

  const int N = in_sizes[0] / 6;   // 50000
  const int E = in_sizes[2] / 2;   // 100000
  const int E2 = 2 * E;

  // ---- workspace carve (~214 MB peak) ----
  char* p = (char*)d_ws;
  auto carve = [&](size_t bytes) -> void* {
    void* r = (void*)p;
    p += (bytes + 255) & ~(size_t)255;
    return r;
  };
  unsigned short* qo = (unsigned short*)carve((size_t)N * 256 * 2);    // Q bf16
  unsigned short* skipb = (unsigned short*)carve((size_t)N * 256 * 2); // skip bf16 | P(fp32) aliases here
  unsigned short* kvb = (unsigned short*)carve((size_t)N * 512 * 2);   // K|V bf16
  unsigned short* aob = (unsigned short*)carve((size_t)N * 256 * 2);   // attn out bf16 -> AB f32
  float* ef = (float*)carve((size_t)E2 * 64 * 4);
  float* nf = (float*)carve((size_t)N * 64 * 4);
  unsigned short* comb = (unsigned short*)carve((size_t)N * 128 * 2);
  unsigned short* W1t = (unsigned short*)carve((size_t)3 * 1024 * 128 * 2);
  float* bias1 = (float*)carve((size_t)3 * 1024 * 4);
  unsigned short* B2t = (unsigned short*)carve((size_t)3 * 256 * 256 * 2);
  float* bias2 = (float*)carve((size_t)3 * 256 * 4);
  unsigned short* Wg1t = (unsigned short*)carve((size_t)3 * 64 * 64 * 2);
  unsigned short* Wc1t = (unsigned short*)carve((size_t)2 * 64 * 64 * 2);
  int* cnt = (int*)carve((size_t)N * 4);
  int* cur = (int*)carve((size_t)N * 4);
  int* off = (int*)carve((size_t)(N + 1) * 4);
  int* elist = (int*)carve((size_t)E2 * 4);
  int* bsum = (int*)carve((size_t)256 * 4);
  int* boff = (int*)carve((size_t)256 * 4);
  float* pm = (float*)carve((size_t)PBLK * 64 * 4);
  float* ps = (float*)carve((size_t)PBLK * 64 * 4);
  float* cwv = (float*)carve(64 * 4);
  float* spmax = (float*)carve((size_t)E2 * 4);
  float* spmean = (float*)carve((size_t)E2 * 4);
  float* sconv = (float*)carve((size_t)E2 * 4);
  size_t need = (size_t)(p - (char*)d_ws);

  // P [N,256] fp32 (51.2MB) aliases skipb(25.6) + first half of kvb(25.6):
  // both dead after k_attn; P consumed by gate kernels before next iter's
  // QKVS GEMM rewrites skipb/kvb. (Proven safe in round 7.)
  float* P = (float*)skipb;
  float* ABt = (float*)aob;
  float* ABb = (float*)aob + (size_t)N * 64;

  auto cdiv = [](int a, int b) { return (a + b - 1) / b; };

  if (ws_size < need) {
    k_sentinel<<<cdiv(E, 256), 256, 0, stream>>>(out, E);
    return;
  }

  // ---- CSR by dst (multi-block scan) ----
  k_zero2<<<cdiv(N, 256), 256, 0, stream>>>(cnt, cur, N);
  k_hist<<<cdiv(E2, 256), 256, 0, stream>>>(ei, cnt, E);
  const int nblk = cdiv(N, 1024);
  k_scan1<<<nblk, 256, 0, stream>>>(cnt, off, bsum, N);
  k_scan2<<<1, 64, 0, stream>>>(bsum, boff, off, N, nblk);
  k_scan3<<<cdiv(N, 256), 256, 0, stream>>>(off, boff, N);
  k_scatter<<<cdiv(E2, 256), 256, 0, stream>>>(ei, off, cur, elist, E);

  // ---- pack weights (bf16 transposed) ----
  const int PACK = 3 * 1024 * 128 + 3 * 1024 + 3 * 256 * 256 + 3 * 256 + 3 * 64 * 64 + 2 * 64 * 64;
  k_packW<<<cdiv(PACK, 256), 256, 0, stream>>>(Wq, Wk, Wv, Wskip, bq, bk, bv, bskip,
                                               Wpn, Wpe, bpn, bpe, Wg, Wc1,
                                               W1t, bias1, B2t, bias2, Wg1t, Wc1t);

  // ---- embeddings ----
  k_node_embed<<<cdiv(N, 4), 256, 0, stream>>>(x, zk, z_table, W_node, b_node, nf, N);
  k_edge_embed<<<cdiv(E2, 4), 256, 0, stream>>>(x, edge_attr, ei, W_edge, b_edge, ef, E);

  // ---- CBAM on nodes then edges ----
  auto run_cbam = [&](float* buf, int rows, const float* w1, const float* b1, const float* w2,
                      const float* b2, const float* cw1, const float* cb1, const float* cw2,
                      const float* cb2) {
    k_pool_partial<<<PBLK, 256, 0, stream>>>(buf, rows, pm, ps);
    k_pool_final<<<1, 256, 0, stream>>>(pm, ps, rows, PBLK, w1, b1, w2, b2, cwv);
    k_chan_sp<<<cdiv(rows, 16), 256, 0, stream>>>(buf, rows, cwv, spmax, spmean);
    k_conv<<<cdiv(rows, 256), 256, 0, stream>>>(spmax, spmean, rows, cw1, cb1, cw2, cb2, sconv);
    k_row_scale<<<cdiv(rows * 16, 256), 256, 0, stream>>>(buf, rows, sconv);
  };
  run_cbam(nf, N, cn_w1, cn_b1, cn_w2, cn_b2, cn_cw1, cn_cb1, cn_cw2, cn_cb2);
  run_cbam(ef, E2, ce_w1, ce_b1, ce_w2, ce_b2, ce_cw1, ce_cb1, ce_cw2, ce_cb2);

  // ---- T = 3 message-passing iterations ----
  dim3 gqkvs(cdiv(N, 128), 8);
  dim3 gp(cdiv(N, 128), 2);
  for (int i = 0; i < 3; ++i) {
    k_aggcomb<<<cdiv(N, 4), 256, 0, stream>>>(ef, nf, off, elist, comb,
                                              ln_comb_g + (size_t)i * 128, ln_comb_b + (size_t)i * 128, N);
    gemm_mfma<0><<<gqkvs, 256, 0, stream>>>(comb, N, 128, W1t + (size_t)i * 131072,
                                            bias1 + (size_t)i * 1024, nullptr, qo, kvb, skipb);
    k_attn<<<cdiv(N, 4), 256, 0, stream>>>(qo, kvb, skipb, off, elist, ei, aob,
                                           ln_tc_g + (size_t)i * 256, ln_tc_b + (size_t)i * 256, N);
    gemm_mfma<1><<<gp, 256, 0, stream>>>(aob, N, 256, B2t + (size_t)i * 65536,
                                         bias2 + (size_t)i * 256, P, nullptr, nullptr, nullptr);
    gemm_gate<1><<<cdiv(N, 128), 256, 0, stream>>>(nf, N, Wg1t + (size_t)i * 4096, P,
                                                   bg + (size_t)i * 64, nullptr, nf);
    gemm_gate<2><<<cdiv(E2, 128), 256, 0, stream>>>(ef, E2, Wg1t + (size_t)i * 4096, P,
                                                    bg + (size_t)i * 64, ei, ef);
  }

  // ---- classifier ----
  gemm_gate<0><<<cdiv(N, 128), 256, 0, stream>>>(nf, N, Wc1t, nullptr, nullptr, nullptr, ABt);
  gemm_gate<0><<<cdiv(N, 128), 256, 0, stream>>>(nf, N, Wc1t + 4096, nullptr, nullptr, nullptr, ABb);
  k_clf_pair<<<cdiv(E, 4), 256, 0, stream>>>(ABt, ABb, ei, bc1, Wc2, bc2, out, E);
  (void)out_size;
  (void)n_in;
}

// Round 9
// 868.693 us; speedup vs baseline: 1.2207x; 1.1619x over previous
//
#include <hip/hip_runtime.h>

// ============================================================================
// New_LinkNet GNN forward — MFMA bf16 GEMMs + fused gate updates.
// Round-9 changes vs round 8 (1009us; gemm_mfma<0> 84us with 16 scalar 2B
// stores/thread = 32B write segments; k_attn 2-deep dependent gather chain):
//  - gemm_mfma MODE0 epilogue: stage C-tile in LDS ([128][136] bf16, 16B
//    aligned rows) -> 8x uint4 contiguous global stores per thread.
//  - k_scatter emits slist (src node id) alongside elist; k_attn reads
//    slist[idx] directly (one load instead of elist->ei chain).
// ============================================================================

#define LN_EPS 1e-5f
#define PBLK 512

typedef __attribute__((ext_vector_type(8))) short bf16x8;
typedef __attribute__((ext_vector_type(4))) float f32x4;

static __device__ __forceinline__ float wsum(float v) {
#pragma unroll
  for (int d = 32; d > 0; d >>= 1) v += __shfl_xor(v, d);
  return v;
}
static __device__ __forceinline__ float sigm(float x) { return 1.0f / (1.0f + __expf(-x)); }
static __device__ __forceinline__ unsigned short f2bf(float f) {
  unsigned int u = __float_as_uint(f);
  u += 0x7FFFu + ((u >> 16) & 1u);
  return (unsigned short)(u >> 16);
}
static __device__ __forceinline__ float bf2f(unsigned short b) {
  return __uint_as_float(((unsigned int)b) << 16);
}

// ---------------- util ----------------
__global__ __launch_bounds__(256) void k_zero2(int* __restrict__ a, int* __restrict__ b, int n) {
  int i = blockIdx.x * 256 + threadIdx.x;
  if (i < n) { a[i] = 0; b[i] = 0; }
}

__global__ __launch_bounds__(256) void k_sentinel(float* __restrict__ out, int n) {
  int i = blockIdx.x * 256 + threadIdx.x;
  if (i < n) out[i] = 1.0e6f;
}

// ---------------- CSR build (by dst) ----------------
__global__ __launch_bounds__(256) void k_hist(const int* __restrict__ ei, int* __restrict__ cnt, int E) {
  int e = blockIdx.x * 256 + threadIdx.x;
  if (e >= 2 * E) return;
  int d = (e < E) ? ei[E + e] : ei[e - E];
  atomicAdd(&cnt[d], 1);
}

__global__ __launch_bounds__(256) void k_scan1(const int* __restrict__ cnt, int* __restrict__ off,
                                               int* __restrict__ bsum, int n) {
  const int t = threadIdx.x;
  const int lane = t & 63, w = t >> 6;
  const int i0 = blockIdx.x * 1024 + t * 4;
  int v0 = (i0 + 0 < n) ? cnt[i0 + 0] : 0;
  int v1 = (i0 + 1 < n) ? cnt[i0 + 1] : 0;
  int v2 = (i0 + 2 < n) ? cnt[i0 + 2] : 0;
  int v3 = (i0 + 3 < n) ? cnt[i0 + 3] : 0;
  int s = v0 + v1 + v2 + v3;
  int sc = s;
#pragma unroll
  for (int d = 1; d < 64; d <<= 1) {
    int tv = __shfl_up(sc, d);
    if (lane >= d) sc += tv;
  }
  __shared__ int wsums[4];
  if (lane == 63) wsums[w] = sc;
  __syncthreads();
  int wbase = 0;
#pragma unroll
  for (int k = 0; k < 4; ++k)
    if (k < w) wbase += wsums[k];
  int run = wbase + sc - s;
  if (i0 + 0 < n) off[i0 + 0] = run; run += v0;
  if (i0 + 1 < n) off[i0 + 1] = run; run += v1;
  if (i0 + 2 < n) off[i0 + 2] = run; run += v2;
  if (i0 + 3 < n) off[i0 + 3] = run;
  if (t == 255) bsum[blockIdx.x] = wbase + sc;
}

__global__ __launch_bounds__(64) void k_scan2(const int* __restrict__ bsum, int* __restrict__ boff,
                                              int* __restrict__ off, int n, int nblk) {
  const int lane = threadIdx.x;
  int carry = 0;
  for (int base = 0; base < nblk; base += 64) {
    int i = base + lane;
    int v = (i < nblk) ? bsum[i] : 0;
    int sc = v;
#pragma unroll
    for (int d = 1; d < 64; d <<= 1) {
      int tv = __shfl_up(sc, d);
      if (lane >= d) sc += tv;
    }
    if (i < nblk) boff[i] = carry + sc - v;
    carry += __shfl(sc, 63);
  }
  if (lane == 0) off[n] = carry;
}

__global__ __launch_bounds__(256) void k_scan3(int* __restrict__ off, const int* __restrict__ boff, int n) {
  int i = blockIdx.x * 256 + threadIdx.x;
  if (i < n) off[i] += boff[i >> 10];
}

__global__ __launch_bounds__(256) void k_scatter(const int* __restrict__ ei, const int* __restrict__ off,
                                                 int* __restrict__ cur, int* __restrict__ elist,
                                                 int* __restrict__ slist, int E) {
  int e = blockIdx.x * 256 + threadIdx.x;
  if (e >= 2 * E) return;
  int d = (e < E) ? ei[E + e] : ei[e - E];
  int pos = atomicAdd(&cur[d], 1);
  int base = off[d] + pos;
  elist[base] = e;
  slist[base] = ei[e];  // src of concatenated edge list
}

// ---------------- pack all transposed bf16 weights ----------------
__global__ __launch_bounds__(256) void k_packW(
    const float* __restrict__ Wq, const float* __restrict__ Wk, const float* __restrict__ Wv,
    const float* __restrict__ Ws, const float* __restrict__ bq, const float* __restrict__ bk,
    const float* __restrict__ bv, const float* __restrict__ bs,
    const float* __restrict__ Wpn, const float* __restrict__ Wpe,
    const float* __restrict__ bpn, const float* __restrict__ bpe,
    const float* __restrict__ Wg, const float* __restrict__ Wc1,
    unsigned short* __restrict__ W1t, float* __restrict__ bias1,
    unsigned short* __restrict__ B2t, float* __restrict__ bias2,
    unsigned short* __restrict__ Wg1t, unsigned short* __restrict__ Wc1t) {
  const int S1 = 3 * 1024 * 128, S2 = 3 * 1024, S3 = 3 * 256 * 256, S4 = 3 * 256;
  const int S5 = 3 * 64 * 64, S6 = 2 * 64 * 64;
  int idx = blockIdx.x * 256 + threadIdx.x;
  if (idx < S1) {
    int i = idx / 131072, r = idx % 131072;
    int col = r >> 7, k = r & 127;
    int m = col >> 8, cc = col & 255;
    const float* W = (m == 0) ? Wq : (m == 1) ? Wk : (m == 2) ? Wv : Ws;
    W1t[idx] = f2bf(W[i * 32768 + k * 256 + cc]);
  } else if (idx < S1 + S2) {
    int j = idx - S1;
    int i = j >> 10, col = j & 1023;
    int m = col >> 8, cc = col & 255;
    const float* bsrc = (m == 0) ? bq : (m == 1) ? bk : (m == 2) ? bv : bs;
    bias1[j] = bsrc[i * 256 + cc];
  } else if (idx < S1 + S2 + S3) {
    int j = idx - S1 - S2;
    int i = j / 65536, r = j % 65536;
    int col = r >> 8, k = r & 255;
    float v;
    if (col < 64) v = Wpn[i * 16384 + k * 64 + col];
    else if (col < 128) v = Wpe[i * 16384 + k * 64 + (col - 64)];
    else {
      const float* Wsrc = (col < 192) ? Wpn : Wpe;
      int cc = col & 63;
      float acc = 0.f;
      for (int jj = 0; jj < 64; ++jj)
        acc = fmaf(Wsrc[i * 16384 + k * 64 + jj], Wg[i * 8192 + (64 + jj) * 64 + cc], acc);
      v = acc;
    }
    B2t[j] = f2bf(v);
  } else if (idx < S1 + S2 + S3 + S4) {
    int j = idx - S1 - S2 - S3;
    int i = j >> 8, col = j & 255;
    float v;
    if (col < 64) v = bpn[i * 64 + col];
    else if (col < 128) v = bpe[i * 64 + col - 64];
    else {
      const float* bsrc = (col < 192) ? bpn : bpe;
      int cc = col & 63;
      float acc = 0.f;
      for (int jj = 0; jj < 64; ++jj)
        acc = fmaf(bsrc[i * 64 + jj], Wg[i * 8192 + (64 + jj) * 64 + cc], acc);
      v = acc;
    }
    bias2[j] = v;
  } else if (idx < S1 + S2 + S3 + S4 + S5) {
    int j = idx - S1 - S2 - S3 - S4;
    int i = j / 4096, r = j % 4096;
    int col = r >> 6, k = r & 63;
    Wg1t[j] = f2bf(Wg[i * 8192 + k * 64 + col]);
  } else if (idx < S1 + S2 + S3 + S4 + S5 + S6) {
    int j = idx - S1 - S2 - S3 - S4 - S5;
    int h = j / 4096, r = j % 4096;
    int col = r >> 6, k = r & 63;
    Wc1t[j] = f2bf(Wc1[(h * 64 + k) * 64 + col]);
  }
}

// ---------------- embeddings ----------------
__global__ __launch_bounds__(256) void k_node_embed(
    const float* __restrict__ x, const int* __restrict__ zk, const float* __restrict__ zt,
    const float* __restrict__ Wn, const float* __restrict__ bn, float* __restrict__ nf, int N) {
  int n = blockIdx.x * 4 + (threadIdx.x >> 6);
  int lane = threadIdx.x & 63;
  if (n >= N) return;
  const float* xr = x + (size_t)n * 6;
  float acc = bn[lane];
#pragma unroll
  for (int d = 0; d < 6; ++d) acc = fmaf(xr[d], Wn[d * 64 + lane], acc);
  int zi = __float2int_rn(xr[2]);
  int idx = 0;
#pragma unroll
  for (int t = 5; t >= 0; --t)
    if (zi == zk[t]) idx = t;
  nf[(size_t)n * 64 + lane] = fmaxf(acc, 0.0f) + zt[idx * 64 + lane];
}

__global__ __launch_bounds__(256) void k_edge_embed(
    const float* __restrict__ x, const float* __restrict__ ea, const int* __restrict__ ei,
    const float* __restrict__ We, const float* __restrict__ be, float* __restrict__ ef, int E) {
  int e = blockIdx.x * 4 + (threadIdx.x >> 6);
  int lane = threadIdx.x & 63;
  if (e >= 2 * E) return;
  int e0 = (e < E) ? e : e - E;
  int s = ei[e];
  int d = (e < E) ? ei[E + e] : ei[e - E];
  const float* ar = ea + (size_t)e0 * 4;
  const float* xs = x + (size_t)s * 6;
  const float* xd = x + (size_t)d * 6;
  float in[7];
  in[0] = ar[0]; in[1] = ar[1]; in[2] = ar[2]; in[3] = ar[3];
  in[4] = xs[0] - xd[0]; in[5] = xs[1] - xd[1]; in[6] = xs[2] - xd[2];
  float acc = be[lane];
#pragma unroll
  for (int dd = 0; dd < 7; ++dd) acc = fmaf(in[dd], We[dd * 64 + lane], acc);
  ef[(size_t)e * 64 + lane] = fmaxf(acc, 0.0f);
}

// ---------------- CBAM (vectorized) ----------------
__global__ __launch_bounds__(256) void k_pool_partial(const float* __restrict__ buf, int n,
                                                      float* __restrict__ pm, float* __restrict__ ps) {
  const int w = threadIdx.x >> 6, l = threadIdx.x & 63;
  const int rsub = l >> 4, c4 = (l & 15) << 2;
  float4 mx = make_float4(-INFINITY, -INFINITY, -INFINITY, -INFINITY);
  float4 sm = make_float4(0.f, 0.f, 0.f, 0.f);
  for (int r = blockIdx.x * 16 + w * 4 + rsub; r < n; r += gridDim.x * 16) {
    float4 v = *(const float4*)(buf + (size_t)r * 64 + c4);
    mx.x = fmaxf(mx.x, v.x); mx.y = fmaxf(mx.y, v.y);
    mx.z = fmaxf(mx.z, v.z); mx.w = fmaxf(mx.w, v.w);
    sm.x += v.x; sm.y += v.y; sm.z += v.z; sm.w += v.w;
  }
#pragma unroll
  for (int d = 16; d < 64; d <<= 1) {
    mx.x = fmaxf(mx.x, __shfl_xor(mx.x, d)); mx.y = fmaxf(mx.y, __shfl_xor(mx.y, d));
    mx.z = fmaxf(mx.z, __shfl_xor(mx.z, d)); mx.w = fmaxf(mx.w, __shfl_xor(mx.w, d));
    sm.x += __shfl_xor(sm.x, d); sm.y += __shfl_xor(sm.y, d);
    sm.z += __shfl_xor(sm.z, d); sm.w += __shfl_xor(sm.w, d);
  }
  __shared__ float smx[4][64], ssm[4][64];
  if (l < 16) {
    *(float4*)&smx[w][c4] = mx;
    *(float4*)&ssm[w][c4] = sm;
  }
  __syncthreads();
  if (threadIdx.x < 64) {
    int t = threadIdx.x;
    float m2 = fmaxf(fmaxf(smx[0][t], smx[1][t]), fmaxf(smx[2][t], smx[3][t]));
    float s2 = ssm[0][t] + ssm[1][t] + ssm[2][t] + ssm[3][t];
    pm[blockIdx.x * 64 + t] = m2;
    ps[blockIdx.x * 64 + t] = s2;
  }
}

__global__ __launch_bounds__(256) void k_pool_final(
    const float* __restrict__ pm, const float* __restrict__ ps, int n, int nblk,
    const float* __restrict__ w1, const float* __restrict__ b1,
    const float* __restrict__ w2, const float* __restrict__ b2, float* __restrict__ cw) {
  __shared__ float redm[4][64], reds[4][64];
  __shared__ float cat[128];
  __shared__ float hid[4];
  int t = threadIdx.x;
  int g = t >> 6, col = t & 63;
  float mx = -INFINITY, sm = 0.0f;
  for (int p = g; p < nblk; p += 4) {
    mx = fmaxf(mx, pm[p * 64 + col]);
    sm += ps[p * 64 + col];
  }
  redm[g][col] = mx;
  reds[g][col] = sm;
  __syncthreads();
  if (t < 64) {
    float m2 = fmaxf(fmaxf(redm[0][t], redm[1][t]), fmaxf(redm[2][t], redm[3][t]));
    float s2 = reds[0][t] + reds[1][t] + reds[2][t] + reds[3][t];
    cat[t] = m2;
    cat[64 + t] = s2 / (float)n;
  }
  __syncthreads();
  if (t < 4) {
    float a = b1[t];
    for (int k = 0; k < 128; ++k) a = fmaf(cat[k], w1[k * 4 + t], a);
    hid[t] = fmaxf(a, 0.0f);
  }
  __syncthreads();
  if (t < 64) {
    float a = b2[t];
#pragma unroll
    for (int h = 0; h < 4; ++h) a = fmaf(hid[h], w2[h * 64 + t], a);
    cw[t] = sigm(a);
  }
}

__global__ __launch_bounds__(256) void k_chan_sp(float* __restrict__ buf, int n,
                                                 const float* __restrict__ cw,
                                                 float* __restrict__ spmax, float* __restrict__ spmean) {
  const int w = threadIdx.x >> 6, l = threadIdx.x & 63;
  const int rsub = l >> 4, c4 = (l & 15) << 2;
  int r = blockIdx.x * 16 + w * 4 + rsub;
  if (r >= n) return;
  float4 cwv = *(const float4*)(cw + c4);
  float4 v = *(const float4*)(buf + (size_t)r * 64 + c4);
  v.x *= cwv.x; v.y *= cwv.y; v.z *= cwv.z; v.w *= cwv.w;
  *(float4*)(buf + (size_t)r * 64 + c4) = v;
  float mx = fmaxf(fmaxf(v.x, v.y), fmaxf(v.z, v.w));
  float sm = v.x + v.y + v.z + v.w;
#pragma unroll
  for (int d = 1; d < 16; d <<= 1) {
    mx = fmaxf(mx, __shfl_xor(mx, d));
    sm += __shfl_xor(sm, d);
  }
  if ((l & 15) == 0) {
    spmax[r] = mx;
    spmean[r] = sm * (1.0f / 64.0f);
  }
}

__global__ __launch_bounds__(256) void k_conv(const float* __restrict__ spmax, const float* __restrict__ spmean,
                                              int n, const float* __restrict__ w1, const float* __restrict__ b1,
                                              const float* __restrict__ w2, const float* __restrict__ b2,
                                              float* __restrict__ s) {
  __shared__ float tl[258];
  int base = blockIdx.x * 256;
  for (int q = threadIdx.x; q < 258; q += 256) {
    int p = base - 1 + q;
    float t = 0.0f;
    if (p >= 0 && p < n) {
      float a = b1[0];
#pragma unroll
      for (int h = 0; h < 5; ++h) {
        int pp = p + h - 2;
        if (pp >= 0 && pp < n) a += spmax[pp] * w1[h] + spmean[pp] * w1[5 + h];
      }
      t = fmaxf(a, 0.0f);
    }
    tl[q] = t;
  }
  __syncthreads();
  int o = base + threadIdx.x;
  if (o < n) {
    float a = b2[0] + tl[threadIdx.x] * w2[0] + tl[threadIdx.x + 1] * w2[1] + tl[threadIdx.x + 2] * w2[2];
    s[o] = sigm(a);
  }
}

__global__ __launch_bounds__(256) void k_row_scale(float* __restrict__ buf, int n, const float* __restrict__ s) {
  int i4 = blockIdx.x * 256 + threadIdx.x;
  if (i4 >= n * 16) return;
  int r = i4 >> 4;
  float sc = s[r];
  float4 v = *(const float4*)(buf + (size_t)i4 * 4);
  v.x *= sc; v.y *= sc; v.z *= sc; v.w *= sc;
  *(float4*)(buf + (size_t)i4 * 4) = v;
}

// ---------------- agg + concat-LN (bf16 out) ----------------
__global__ __launch_bounds__(256) void k_aggcomb(const float* __restrict__ ef, const float* __restrict__ nf,
                                                 const int* __restrict__ off, const int* __restrict__ elist,
                                                 unsigned short* __restrict__ comb, const float* __restrict__ g,
                                                 const float* __restrict__ b, int N) {
  int n = blockIdx.x * 4 + (threadIdx.x >> 6);
  int lane = threadIdx.x & 63;
  if (n >= N) return;
  float agg = 0.0f;
  int i0 = off[n], i1 = off[n + 1];
  for (int idx = i0; idx < i1; ++idx) agg += ef[(size_t)elist[idx] * 64 + lane];
  float y0 = nf[(size_t)n * 64 + lane];
  float y1 = agg - y0;
  float s1 = wsum(y0 + y1);
  float s2 = wsum(y0 * y0 + y1 * y1);
  float mu = s1 * (1.0f / 128.0f);
  float var = s2 * (1.0f / 128.0f) - mu * mu;
  float rs = rsqrtf(fmaxf(var, 0.0f) + LN_EPS);
  comb[(size_t)n * 128 + lane] = f2bf((y0 - mu) * rs * g[lane] + b[lane]);
  comb[(size_t)n * 128 + 64 + lane] = f2bf((y1 - mu) * rs * g[64 + lane] + b[64 + lane]);
}

// ---------------- MFMA GEMM: C[M,NC] = A[M,K](bf16) @ Bt[NC,K](bf16) -------
// 64-wide K chunks, 0-conflict swizzle. MODE 0: NC=1024, LDS-staged bf16
// epilogue with uint4 stores. MODE 1: fp32 out ld=256 (scalar stores).
template <int MODE>
__global__ __launch_bounds__(256) void gemm_mfma(
    const unsigned short* __restrict__ A, int M, int K,
    const unsigned short* __restrict__ Bt, const float* __restrict__ bias,
    float* __restrict__ outF, unsigned short* __restrict__ outQ,
    unsigned short* __restrict__ outK, unsigned short* __restrict__ outS) {
  constexpr int SHN = (MODE == 0) ? (128 * 136) : (128 * 64 * 2);
  __shared__ unsigned short shmem[SHN];
  unsigned short* As = shmem;
  unsigned short* Bs = shmem + 128 * 64;
  const int tid = threadIdx.x;
  const int bm = blockIdx.x * 128;
  const int bn = blockIdx.y * 128;
  const int wid = tid >> 6, lane = tid & 63;
  const int wr = (wid >> 1) * 64, wc = (wid & 1) * 64;
  const int lrow = lane & 15, lkb = (lane >> 4) * 8;
  f32x4 acc[4][4];
#pragma unroll
  for (int m = 0; m < 4; ++m)
#pragma unroll
    for (int n = 0; n < 4; ++n) acc[m][n] = (f32x4){0.f, 0.f, 0.f, 0.f};

  for (int k0 = 0; k0 < K; k0 += 64) {
#pragma unroll
    for (int l = 0; l < 4; ++l) {
      int c = tid + l * 256;
      int row = c >> 3, kc = (c & 7) * 8;
      int sw = row * 64 + (kc ^ ((row & 7) << 3));
      int grow = bm + row;
      bf16x8 v = {0, 0, 0, 0, 0, 0, 0, 0};
      if (grow < M) v = *(const bf16x8*)(A + (size_t)grow * K + k0 + kc);
      *(bf16x8*)&As[sw] = v;
      int gcol = bn + row;
      *(bf16x8*)&Bs[sw] = *(const bf16x8*)(Bt + (size_t)gcol * K + k0 + kc);
    }
    __syncthreads();
#pragma unroll
    for (int ks = 0; ks < 2; ++ks) {
      const int ke = ks * 32 + lkb;
      bf16x8 af[4], bfr[4];
#pragma unroll
      for (int m = 0; m < 4; ++m) {
        int row = wr + m * 16 + lrow;
        af[m] = *(const bf16x8*)&As[row * 64 + (ke ^ ((row & 7) << 3))];
      }
#pragma unroll
      for (int n = 0; n < 4; ++n) {
        int col = wc + n * 16 + lrow;
        bfr[n] = *(const bf16x8*)&Bs[col * 64 + (ke ^ ((col & 7) << 3))];
      }
#pragma unroll
      for (int m = 0; m < 4; ++m)
#pragma unroll
        for (int n = 0; n < 4; ++n)
          acc[m][n] = __builtin_amdgcn_mfma_f32_16x16x32_bf16(af[m], bfr[n], acc[m][n], 0, 0, 0);
    }
    __syncthreads();
  }

  const int colw = lane & 15, rq = (lane >> 4) * 4;
  if (MODE == 1) {
#pragma unroll
    for (int m = 0; m < 4; ++m) {
#pragma unroll
      for (int n = 0; n < 4; ++n) {
        int gcol = bn + wc + n * 16 + colw;
        float bv = bias[gcol];
#pragma unroll
        for (int r = 0; r < 4; ++r) {
          int grow = bm + wr + m * 16 + rq + r;
          if (grow >= M) continue;
          outF[(size_t)grow * 256 + gcol] = acc[m][n][r] + bv;
        }
      }
    }
  } else {
    // LDS-staged bf16 epilogue: [128][136] (272B rows, 16B-aligned)
    unsigned short* Cs = shmem;
#pragma unroll
    for (int m = 0; m < 4; ++m) {
#pragma unroll
      for (int n = 0; n < 4; ++n) {
        int col = wc + n * 16 + colw;
        float bv = bias[bn + col];
#pragma unroll
        for (int r = 0; r < 4; ++r) {
          int row = wr + m * 16 + rq + r;
          Cs[row * 136 + col] = f2bf(acc[m][n][r] + bv);
        }
      }
    }
    __syncthreads();
    const int proj = bn >> 8;
    const int cbase = bn & 255;
    const int rsub = tid >> 4, c8 = (tid & 15) * 8;
#pragma unroll
    for (int i = 0; i < 8; ++i) {
      int row = i * 16 + rsub;
      int grow = bm + row;
      if (grow >= M) continue;
      uint4 v = *(const uint4*)&Cs[row * 136 + c8];
      int cc = cbase + c8;
      if (proj == 0) *(uint4*)(outQ + (size_t)grow * 256 + cc) = v;
      else if (proj == 1) *(uint4*)(outK + (size_t)grow * 512 + cc) = v;
      else if (proj == 2) *(uint4*)(outK + (size_t)grow * 512 + 256 + cc) = v;
      else *(uint4*)(outS + (size_t)grow * 256 + cc) = v;
    }
  }
}

// ------ MFMA [M,64]@[64,64] with fused epilogue ------
template <int UPD>
__global__ __launch_bounds__(256) void gemm_gate(
    const float* __restrict__ Af, int M, const unsigned short* __restrict__ Wt,
    const float* __restrict__ P, const float* __restrict__ bgv,
    const int* __restrict__ ei, float* __restrict__ upd) {
  __shared__ unsigned short As[128 * 64];
  __shared__ unsigned short Ws[64 * 64];
  const int tid = threadIdx.x;
  const int bm = blockIdx.x * 128;
#pragma unroll
  for (int l = 0; l < 8; ++l) {
    int u = tid + l * 256;
    int row = u >> 4, k4 = (u & 15) << 2;
    int grow = bm + row;
    float4 v = make_float4(0.f, 0.f, 0.f, 0.f);
    if (grow < M) v = *(const float4*)(Af + (size_t)grow * 64 + k4);
    union { unsigned short h[4]; uint2 q; } pk;
    pk.h[0] = f2bf(v.x); pk.h[1] = f2bf(v.y); pk.h[2] = f2bf(v.z); pk.h[3] = f2bf(v.w);
    *(uint2*)&As[row * 64 + (k4 ^ ((row & 7) << 3))] = pk.q;
  }
#pragma unroll
  for (int l = 0; l < 2; ++l) {
    int u = tid + l * 256;
    int row = u >> 3, kc = (u & 7) * 8;
    *(bf16x8*)&Ws[row * 64 + (kc ^ ((row & 7) << 3))] = *(const bf16x8*)(Wt + row * 64 + kc);
  }
  __syncthreads();
  const int wid = tid >> 6, lane = tid & 63;
  const int wr = wid * 32;
  const int lrow = lane & 15, lkb = (lane >> 4) * 8;
  f32x4 acc[2][4];
#pragma unroll
  for (int m = 0; m < 2; ++m)
#pragma unroll
    for (int n = 0; n < 4; ++n) acc[m][n] = (f32x4){0.f, 0.f, 0.f, 0.f};
#pragma unroll
  for (int ks = 0; ks < 2; ++ks) {
    const int ke = ks * 32 + lkb;
    bf16x8 af[2], wf[4];
#pragma unroll
    for (int m = 0; m < 2; ++m) {
      int row = wr + m * 16 + lrow;
      af[m] = *(const bf16x8*)&As[row * 64 + (ke ^ ((row & 7) << 3))];
    }
#pragma unroll
    for (int n = 0; n < 4; ++n) {
      int col = n * 16 + lrow;
      wf[n] = *(const bf16x8*)&Ws[col * 64 + (ke ^ ((col & 7) << 3))];
    }
#pragma unroll
    for (int m = 0; m < 2; ++m)
#pragma unroll
      for (int n = 0; n < 4; ++n)
        acc[m][n] = __builtin_amdgcn_mfma_f32_16x16x32_bf16(af[m], wf[n], acc[m][n], 0, 0, 0);
  }
  const int colw = lane & 15, rq = (lane >> 4) * 4;
#pragma unroll
  for (int m = 0; m < 2; ++m) {
#pragma unroll
    for (int r = 0; r < 4; ++r) {
      int e = bm + wr + m * 16 + rq + r;
      if (e >= M) continue;
      if (UPD == 0) {
#pragma unroll
        for (int n = 0; n < 4; ++n) upd[(size_t)e * 64 + n * 16 + colw] = acc[m][n][r];
      } else {
        int s = (UPD == 2) ? ei[e] : e;
        const float* Pr = P + (size_t)s * 256;
        const int voff = (UPD == 1) ? 128 : 192;
        const int poff = (UPD == 1) ? 0 : 64;
#pragma unroll
        for (int n = 0; n < 4; ++n) {
          int c = n * 16 + colw;
          float g = sigm(acc[m][n][r] + Pr[voff + c] + bgv[c]);
          size_t oi = (size_t)e * 64 + c;
          upd[oi] = upd[oi] * g + Pr[poff + c] * (1.0f - g);
        }
      }
    }
  }
}

// ---------------- attention: lane = (head, 4 cols); wide loads ----------
__global__ __launch_bounds__(256) void k_attn(const unsigned short* __restrict__ qo,
                                              const unsigned short* __restrict__ kv,
                                              const unsigned short* __restrict__ skipb, const int* __restrict__ off,
                                              const int* __restrict__ slist,
                                              unsigned short* __restrict__ aob,
                                              const float* __restrict__ g, const float* __restrict__ b, int N) {
  int n = blockIdx.x * 4 + (threadIdx.x >> 6);
  int lane = threadIdx.x & 63;
  if (n >= N) return;
  union { uint2 u; unsigned short h[4]; } qq;
  qq.u = *(const uint2*)(qo + (size_t)n * 256 + 4 * lane);
  float q0 = bf2f(qq.h[0]), q1 = bf2f(qq.h[1]), q2 = bf2f(qq.h[2]), q3 = bf2f(qq.h[3]);
  float m = -INFINITY, lsum = 0.f;
  float a0 = 0.f, a1 = 0.f, a2 = 0.f, a3 = 0.f;
  int i0 = off[n], i1 = off[n + 1];
  for (int idx = i0; idx < i1; ++idx) {
    int s = slist[idx];  // direct src id: single load (was elist->ei chain)
    const unsigned short* kb = kv + (size_t)s * 512;
    union { uint2 u; unsigned short h[4]; } kk, vv;
    kk.u = *(const uint2*)(kb + 4 * lane);
    vv.u = *(const uint2*)(kb + 256 + 4 * lane);
    float d = q0 * bf2f(kk.h[0]) + q1 * bf2f(kk.h[1]) + q2 * bf2f(kk.h[2]) + q3 * bf2f(kk.h[3]);
#pragma unroll
    for (int dd = 1; dd < 16; dd <<= 1) d += __shfl_xor(d, dd);
    d *= 0.125f;
    float nm = fmaxf(m, d);
    float sc = __expf(m - nm);
    float p = __expf(d - nm);
    lsum = lsum * sc + p;
    a0 = fmaf(p, bf2f(vv.h[0]), a0 * sc);
    a1 = fmaf(p, bf2f(vv.h[1]), a1 * sc);
    a2 = fmaf(p, bf2f(vv.h[2]), a2 * sc);
    a3 = fmaf(p, bf2f(vv.h[3]), a3 * sc);
    m = nm;
  }
  union { uint2 u; unsigned short h[4]; } sb;
  sb.u = *(const uint2*)(skipb + (size_t)n * 256 + 4 * lane);
  float inv = (lsum > 0.f) ? 1.0f / lsum : 0.f;
  float v0 = bf2f(sb.h[0]) + a0 * inv;
  float v1 = bf2f(sb.h[1]) + a1 * inv;
  float v2 = bf2f(sb.h[2]) + a2 * inv;
  float v3 = bf2f(sb.h[3]) + a3 * inv;
  float s1 = wsum(v0 + v1 + v2 + v3);
  float s2 = wsum(v0 * v0 + v1 * v1 + v2 * v2 + v3 * v3);
  float mu = s1 * (1.0f / 256.0f);
  float var = s2 * (1.0f / 256.0f) - mu * mu;
  float rs = rsqrtf(fmaxf(var, 0.0f) + LN_EPS);
  float4 g4 = *(const float4*)(g + 4 * lane);
  float4 b4 = *(const float4*)(b + 4 * lane);
  union { uint2 u; unsigned short h[4]; } ob;
  ob.h[0] = f2bf((v0 - mu) * rs * g4.x + b4.x);
  ob.h[1] = f2bf((v1 - mu) * rs * g4.y + b4.y);
  ob.h[2] = f2bf((v2 - mu) * rs * g4.z + b4.z);
  ob.h[3] = f2bf((v3 - mu) * rs * g4.w + b4.w);
  *(uint2*)(aob + (size_t)n * 256 + 4 * lane) = ob.u;
}

// ---------------- classifier pair kernel ----------------
__global__ __launch_bounds__(256) void k_clf_pair(const float* __restrict__ ABt, const float* __restrict__ ABb,
                                                  const int* __restrict__ ei, const float* __restrict__ bc1,
                                                  const float* __restrict__ Wc2, const float* __restrict__ bc2,
                                                  float* __restrict__ out, int E) {
  int e = blockIdx.x * 4 + (threadIdx.x >> 6);
  int lane = threadIdx.x & 63;
  if (e >= E) return;
  int s = ei[e], t = ei[E + e];
  float h = fmaxf(ABt[(size_t)s * 64 + lane] + ABb[(size_t)t * 64 + lane] + bc1[lane], 0.0f);
  float r = wsum(h * Wc2[lane]);
  if (lane == 0) out[e] = r + bc2[0];
}

// ============================================================================
extern "C" void kernel_launch(void* const* d_in, const int* in_sizes, int n_in,
                              void* d_out, int out_size, void* d_ws, size_t ws_size,
                              hipStream_t stream) {
  const float* x = (const float*)d_in[0];
  const float* edge_attr = (const float*)d_in[1];
  const int* ei = (const int*)d_in[2];
  const int* zk = (const int*)d_in[3];
  const float* z_table = (const float*)d_in[4];
  const float* W_node = (const float*)d_in[5];
  const float* b_node = (const float*)d_in[6];
  const float* W_edge = (const float*)d_in[7];
  const float* b_edge = (const float*)d_in[8];
  const float* cn_w1 = (const float*)d_in[9];
  const float* cn_b1 = (const float*)d_in[10];
  const float* cn_w2 = (const float*)d_in[11];
  const float* cn_b2 = (const float*)d_in[12];
  const float* cn_cw1 = (const float*)d_in[13];
  const float* cn_cb1 = (const float*)d_in[14];
  const float* cn_cw2 = (const float*)d_in[15];
  const float* cn_cb2 = (const float*)d_in[16];
  const float* ce_w1 = (const float*)d_in[17];
  const float* ce_b1 = (const float*)d_in[18];
  const float* ce_w2 = (const float*)d_in[19];
  const float* ce_b2 = (const float*)d_in[20];
  const float* ce_cw1 = (const float*)d_in[21];
  const float* ce_cb1 = (const float*)d_in[22];
  const float* ce_cw2 = (const float*)d_in[23];
  const float* ce_cb2 = (const float*)d_in[24];
  const float* ln_comb_g = (const float*)d_in[25];
  const float* ln_comb_b = (const float*)d_in[26];
  const float* Wq = (const float*)d_in[27];
  const float* bq = (const float*)d_in[28];
  const float* Wk = (const float*)d_in[29];
  const float* bk = (const float*)d_in[30];
  const float* Wv = (const float*)d_in[31];
  const float* bv = (const float*)d_in[32];
  const float* Wskip = (const float*)d_in[33];
  const float* bskip = (const float*)d_in[34];
  const float* ln_tc_g = (const float*)d_in[35];
  const float* ln_tc_b = (const float*)d_in[36];
  const float* Wpn = (const float*)d_in[37];
  const float* bpn = (const float*)d_in[38];
  const float* Wpe = (const float*)d_in[39];
  const float* bpe = (const float*)d_in[40];
  const float* Wg = (const float*)d_in[41];
  const float* bg = (const float*)d_in[42];
  const float* Wc1 = (const float*)d_in[43];
  const float* bc1 = (const float*)d_in[44];
  const float* Wc2 = (const float*)d_in[45];
  const float* bc2 = (const float*)d_in[46];
  float* out = (float*)d_out;

  const int N = in_sizes[0] / 6;   // 50000
  const int E = in_sizes[2] / 2;   // 100000
  const int E2 = 2 * E;

  // ---- workspace carve (~215 MB peak) ----
  char* p = (char*)d_ws;
  auto carve = [&](size_t bytes) -> void* {
    void* r = (void*)p;
    p += (bytes + 255) & ~(size_t)255;
    return r;
  };
  unsigned short* qo = (unsigned short*)carve((size_t)N * 256 * 2);    // Q bf16
  unsigned short* skipb = (unsigned short*)carve((size_t)N * 256 * 2); // skip bf16 | P(fp32) aliases here
  unsigned short* kvb = (unsigned short*)carve((size_t)N * 512 * 2);   // K|V bf16
  unsigned short* aob = (unsigned short*)carve((size_t)N * 256 * 2);   // attn out bf16 -> AB f32
  float* ef = (float*)carve((size_t)E2 * 64 * 4);
  float* nf = (float*)carve((size_t)N * 64 * 4);
  unsigned short* comb = (unsigned short*)carve((size_t)N * 128 * 2);
  unsigned short* W1t = (unsigned short*)carve((size_t)3 * 1024 * 128 * 2);
  float* bias1 = (float*)carve((size_t)3 * 1024 * 4);
  unsigned short* B2t = (unsigned short*)carve((size_t)3 * 256 * 256 * 2);
  float* bias2 = (float*)carve((size_t)3 * 256 * 4);
  unsigned short* Wg1t = (unsigned short*)carve((size_t)3 * 64 * 64 * 2);
  unsigned short* Wc1t = (unsigned short*)carve((size_t)2 * 64 * 64 * 2);
  int* cnt = (int*)carve((size_t)N * 4);
  int* cur = (int*)carve((size_t)N * 4);
  int* off = (int*)carve((size_t)(N + 1) * 4);
  int* elist = (int*)carve((size_t)E2 * 4);
  int* slist = (int*)carve((size_t)E2 * 4);
  int* bsum = (int*)carve((size_t)256 * 4);
  int* boff = (int*)carve((size_t)256 * 4);
  float* pm = (float*)carve((size_t)PBLK * 64 * 4);
  float* ps = (float*)carve((size_t)PBLK * 64 * 4);
  float* cwv = (float*)carve(64 * 4);
  float* spmax = (float*)carve((size_t)E2 * 4);
  float* spmean = (float*)carve((size_t)E2 * 4);
  float* sconv = (float*)carve((size_t)E2 * 4);
  size_t need = (size_t)(p - (char*)d_ws);

  // P [N,256] fp32 (51.2MB) aliases skipb(25.6) + first half of kvb(25.6):
  // both dead after k_attn; P consumed by gate kernels before next iter's
  // QKVS GEMM rewrites skipb/kvb. (Proven safe in rounds 7-8.)
  float* P = (float*)skipb;
  float* ABt = (float*)aob;
  float* ABb = (float*)aob + (size_t)N * 64;

  auto cdiv = [](int a, int b) { return (a + b - 1) / b; };

  if (ws_size < need) {
    k_sentinel<<<cdiv(E, 256), 256, 0, stream>>>(out, E);
    return;
  }

  // ---- CSR by dst (multi-block scan) ----
  k_zero2<<<cdiv(N, 256), 256, 0, stream>>>(cnt, cur, N);
  k_hist<<<cdiv(E2, 256), 256, 0, stream>>>(ei, cnt, E);
  const int nblk = cdiv(N, 1024);
  k_scan1<<<nblk, 256, 0, stream>>>(cnt, off, bsum, N);
  k_scan2<<<1, 64, 0, stream>>>(bsum, boff, off, N, nblk);
  k_scan3<<<cdiv(N, 256), 256, 0, stream>>>(off, boff, N);
  k_scatter<<<cdiv(E2, 256), 256, 0, stream>>>(ei, off, cur, elist, slist, E);

  // ---- pack weights (bf16 transposed) ----
  const int PACK = 3 * 1024 * 128 + 3 * 1024 + 3 * 256 * 256 + 3 * 256 + 3 * 64 * 64 + 2 * 64 * 64;
  k_packW<<<cdiv(PACK, 256), 256, 0, stream>>>(Wq, Wk, Wv, Wskip, bq, bk, bv, bskip,
                                               Wpn, Wpe, bpn, bpe, Wg, Wc1,
                                               W1t, bias1, B2t, bias2, Wg1t, Wc1t);

  // ---- embeddings ----
  k_node_embed<<<cdiv(N, 4), 256, 0, stream>>>(x, zk, z_table, W_node, b_node, nf, N);
  k_edge_embed<<<cdiv(E2, 4), 256, 0, stream>>>(x, edge_attr, ei, W_edge, b_edge, ef, E);

  // ---- CBAM on nodes then edges ----
  auto run_cbam = [&](float* buf, int rows, const float* w1, const float* b1, const float* w2,
                      const float* b2, const float* cw1, const float* cb1, const float* cw2,
                      const float* cb2) {
    k_pool_partial<<<PBLK, 256, 0, stream>>>(buf, rows, pm, ps);
    k_pool_final<<<1, 256, 0, stream>>>(pm, ps, rows, PBLK, w1, b1, w2, b2, cwv);
    k_chan_sp<<<cdiv(rows, 16), 256, 0, stream>>>(buf, rows, cwv, spmax, spmean);
    k_conv<<<cdiv(rows, 256), 256, 0, stream>>>(spmax, spmean, rows, cw1, cb1, cw2, cb2, sconv);
    k_row_scale<<<cdiv(rows * 16, 256), 256, 0, stream>>>(buf, rows, sconv);
  };
  run_cbam(nf, N, cn_w1, cn_b1, cn_w2, cn_b2, cn_cw1, cn_cb1, cn_cw2, cn_cb2);
  run_cbam(ef, E2, ce_w1, ce_b1, ce_w2, ce_b2, ce_cw1, ce_cb1, ce_cw2, ce_cb2);

  // ---- T = 3 message-passing iterations ----
  dim3 gqkvs(cdiv(N, 128), 8);
  dim3 gp(cdiv(N, 128), 2);
  for (int i = 0; i < 3; ++i) {
    k_aggcomb<<<cdiv(N, 4), 256, 0, stream>>>(ef, nf, off, elist, comb,
                                              ln_comb_g + (size_t)i * 128, ln_comb_b + (size_t)i * 128, N);
    gemm_mfma<0><<<gqkvs, 256, 0, stream>>>(comb, N, 128, W1t + (size_t)i * 131072,
                                            bias1 + (size_t)i * 1024, nullptr, qo, kvb, skipb);
    k_attn<<<cdiv(N, 4), 256, 0, stream>>>(qo, kvb, skipb, off, slist, aob,
                                           ln_tc_g + (size_t)i * 256, ln_tc_b + (size_t)i * 256, N);
    gemm_mfma<1><<<gp, 256, 0, stream>>>(aob, N, 256, B2t + (size_t)i * 65536,
                                         bias2 + (size_t)i * 256, P, nullptr, nullptr, nullptr);
    gemm_gate<1><<<cdiv(N, 128), 256, 0, stream>>>(nf, N, Wg1t + (size_t)i * 4096, P,
                                                   bg + (size_t)i * 64, nullptr, nf);
    gemm_gate<2><<<cdiv(E2, 128), 256, 0, stream>>>(ef, E2, Wg1t + (size_t)i * 4096, P,
                                                    bg + (size_t)i * 64, ei, ef);
  }

  // ---- classifier ----
  gemm_gate<0><<<cdiv(N, 128), 256, 0, stream>>>(nf, N, Wc1t, nullptr, nullptr, nullptr, ABt);
  gemm_gate<0><<<cdiv(N, 128), 256, 0, stream>>>(nf, N, Wc1t + 4096, nullptr, nullptr, nullptr, ABb);
  k_clf_pair<<<cdiv(E, 4), 256, 0, stream>>>(ABt, ABb, ei, bc1, Wc2, bc2, out, E);
  (void)out_size;
  (void)n_in;
}

// Round 10
// 802.113 us; speedup vs baseline: 1.3220x; 1.0830x over previous
//
#include <hip/hip_runtime.h>

// ============================================================================
// New_LinkNet GNN forward — MFMA bf16 GEMMs + fused gate updates.
// Round-10 changes vs round 9 (869us; k_attn 50us latency-bound on serial
// per-edge gather chain; gate_edge/aggcomb stream ef as fp32):
//  - k_attn: 2-edge unrolled loop — both K/V gathers issue before the
//    reductions; interleaved shfl chains; sequential softmax updates.
//  - ef stored bf16 end-to-end: edge_embed, templated CBAM (pool/chan/scale),
//    aggcomb bf16 gather, gemm_gate<2> direct-bf16 A staging + bf16 update.
// ============================================================================

#define LN_EPS 1e-5f
#define PBLK 512

typedef __attribute__((ext_vector_type(8))) short bf16x8;
typedef __attribute__((ext_vector_type(4))) float f32x4;

static __device__ __forceinline__ float wsum(float v) {
#pragma unroll
  for (int d = 32; d > 0; d >>= 1) v += __shfl_xor(v, d);
  return v;
}
static __device__ __forceinline__ float sigm(float x) { return 1.0f / (1.0f + __expf(-x)); }
static __device__ __forceinline__ unsigned short f2bf(float f) {
  unsigned int u = __float_as_uint(f);
  u += 0x7FFFu + ((u >> 16) & 1u);
  return (unsigned short)(u >> 16);
}
static __device__ __forceinline__ float bf2f(unsigned short b) {
  return __uint_as_float(((unsigned int)b) << 16);
}
// typed 4-element load/store (fp32 or bf16) as float4
static __device__ __forceinline__ float4 ld4v(const float* p) { return *(const float4*)p; }
static __device__ __forceinline__ float4 ld4v(const unsigned short* p) {
  union { uint2 u; unsigned short h[4]; } t;
  t.u = *(const uint2*)p;
  return make_float4(bf2f(t.h[0]), bf2f(t.h[1]), bf2f(t.h[2]), bf2f(t.h[3]));
}
static __device__ __forceinline__ void st4v(float* p, float4 v) { *(float4*)p = v; }
static __device__ __forceinline__ void st4v(unsigned short* p, float4 v) {
  union { uint2 u; unsigned short h[4]; } t;
  t.h[0] = f2bf(v.x); t.h[1] = f2bf(v.y); t.h[2] = f2bf(v.z); t.h[3] = f2bf(v.w);
  *(uint2*)p = t.u;
}

// ---------------- util ----------------
__global__ __launch_bounds__(256) void k_zero2(int* __restrict__ a, int* __restrict__ b, int n) {
  int i = blockIdx.x * 256 + threadIdx.x;
  if (i < n) { a[i] = 0; b[i] = 0; }
}

__global__ __launch_bounds__(256) void k_sentinel(float* __restrict__ out, int n) {
  int i = blockIdx.x * 256 + threadIdx.x;
  if (i < n) out[i] = 1.0e6f;
}

// ---------------- CSR build (by dst) ----------------
__global__ __launch_bounds__(256) void k_hist(const int* __restrict__ ei, int* __restrict__ cnt, int E) {
  int e = blockIdx.x * 256 + threadIdx.x;
  if (e >= 2 * E) return;
  int d = (e < E) ? ei[E + e] : ei[e - E];
  atomicAdd(&cnt[d], 1);
}

__global__ __launch_bounds__(256) void k_scan1(const int* __restrict__ cnt, int* __restrict__ off,
                                               int* __restrict__ bsum, int n) {
  const int t = threadIdx.x;
  const int lane = t & 63, w = t >> 6;
  const int i0 = blockIdx.x * 1024 + t * 4;
  int v0 = (i0 + 0 < n) ? cnt[i0 + 0] : 0;
  int v1 = (i0 + 1 < n) ? cnt[i0 + 1] : 0;
  int v2 = (i0 + 2 < n) ? cnt[i0 + 2] : 0;
  int v3 = (i0 + 3 < n) ? cnt[i0 + 3] : 0;
  int s = v0 + v1 + v2 + v3;
  int sc = s;
#pragma unroll
  for (int d = 1; d < 64; d <<= 1) {
    int tv = __shfl_up(sc, d);
    if (lane >= d) sc += tv;
  }
  __shared__ int wsums[4];
  if (lane == 63) wsums[w] = sc;
  __syncthreads();
  int wbase = 0;
#pragma unroll
  for (int k = 0; k < 4; ++k)
    if (k < w) wbase += wsums[k];
  int run = wbase + sc - s;
  if (i0 + 0 < n) off[i0 + 0] = run; run += v0;
  if (i0 + 1 < n) off[i0 + 1] = run; run += v1;
  if (i0 + 2 < n) off[i0 + 2] = run; run += v2;
  if (i0 + 3 < n) off[i0 + 3] = run;
  if (t == 255) bsum[blockIdx.x] = wbase + sc;
}

__global__ __launch_bounds__(64) void k_scan2(const int* __restrict__ bsum, int* __restrict__ boff,
                                              int* __restrict__ off, int n, int nblk) {
  const int lane = threadIdx.x;
  int carry = 0;
  for (int base = 0; base < nblk; base += 64) {
    int i = base + lane;
    int v = (i < nblk) ? bsum[i] : 0;
    int sc = v;
#pragma unroll
    for (int d = 1; d < 64; d <<= 1) {
      int tv = __shfl_up(sc, d);
      if (lane >= d) sc += tv;
    }
    if (i < nblk) boff[i] = carry + sc - v;
    carry += __shfl(sc, 63);
  }
  if (lane == 0) off[n] = carry;
}

__global__ __launch_bounds__(256) void k_scan3(int* __restrict__ off, const int* __restrict__ boff, int n) {
  int i = blockIdx.x * 256 + threadIdx.x;
  if (i < n) off[i] += boff[i >> 10];
}

__global__ __launch_bounds__(256) void k_scatter(const int* __restrict__ ei, const int* __restrict__ off,
                                                 int* __restrict__ cur, int* __restrict__ elist,
                                                 int* __restrict__ slist, int E) {
  int e = blockIdx.x * 256 + threadIdx.x;
  if (e >= 2 * E) return;
  int d = (e < E) ? ei[E + e] : ei[e - E];
  int pos = atomicAdd(&cur[d], 1);
  int base = off[d] + pos;
  elist[base] = e;
  slist[base] = ei[e];
}

// ---------------- pack all transposed bf16 weights ----------------
__global__ __launch_bounds__(256) void k_packW(
    const float* __restrict__ Wq, const float* __restrict__ Wk, const float* __restrict__ Wv,
    const float* __restrict__ Ws, const float* __restrict__ bq, const float* __restrict__ bk,
    const float* __restrict__ bv, const float* __restrict__ bs,
    const float* __restrict__ Wpn, const float* __restrict__ Wpe,
    const float* __restrict__ bpn, const float* __restrict__ bpe,
    const float* __restrict__ Wg, const float* __restrict__ Wc1,
    unsigned short* __restrict__ W1t, float* __restrict__ bias1,
    unsigned short* __restrict__ B2t, float* __restrict__ bias2,
    unsigned short* __restrict__ Wg1t, unsigned short* __restrict__ Wc1t) {
  const int S1 = 3 * 1024 * 128, S2 = 3 * 1024, S3 = 3 * 256 * 256, S4 = 3 * 256;
  const int S5 = 3 * 64 * 64, S6 = 2 * 64 * 64;
  int idx = blockIdx.x * 256 + threadIdx.x;
  if (idx < S1) {
    int i = idx / 131072, r = idx % 131072;
    int col = r >> 7, k = r & 127;
    int m = col >> 8, cc = col & 255;
    const float* W = (m == 0) ? Wq : (m == 1) ? Wk : (m == 2) ? Wv : Ws;
    W1t[idx] = f2bf(W[i * 32768 + k * 256 + cc]);
  } else if (idx < S1 + S2) {
    int j = idx - S1;
    int i = j >> 10, col = j & 1023;
    int m = col >> 8, cc = col & 255;
    const float* bsrc = (m == 0) ? bq : (m == 1) ? bk : (m == 2) ? bv : bs;
    bias1[j] = bsrc[i * 256 + cc];
  } else if (idx < S1 + S2 + S3) {
    int j = idx - S1 - S2;
    int i = j / 65536, r = j % 65536;
    int col = r >> 8, k = r & 255;
    float v;
    if (col < 64) v = Wpn[i * 16384 + k * 64 + col];
    else if (col < 128) v = Wpe[i * 16384 + k * 64 + (col - 64)];
    else {
      const float* Wsrc = (col < 192) ? Wpn : Wpe;
      int cc = col & 63;
      float acc = 0.f;
      for (int jj = 0; jj < 64; ++jj)
        acc = fmaf(Wsrc[i * 16384 + k * 64 + jj], Wg[i * 8192 + (64 + jj) * 64 + cc], acc);
      v = acc;
    }
    B2t[j] = f2bf(v);
  } else if (idx < S1 + S2 + S3 + S4) {
    int j = idx - S1 - S2 - S3;
    int i = j >> 8, col = j & 255;
    float v;
    if (col < 64) v = bpn[i * 64 + col];
    else if (col < 128) v = bpe[i * 64 + col - 64];
    else {
      const float* bsrc = (col < 192) ? bpn : bpe;
      int cc = col & 63;
      float acc = 0.f;
      for (int jj = 0; jj < 64; ++jj)
        acc = fmaf(bsrc[i * 64 + jj], Wg[i * 8192 + (64 + jj) * 64 + cc], acc);
      v = acc;
    }
    bias2[j] = v;
  } else if (idx < S1 + S2 + S3 + S4 + S5) {
    int j = idx - S1 - S2 - S3 - S4;
    int i = j / 4096, r = j % 4096;
    int col = r >> 6, k = r & 63;
    Wg1t[j] = f2bf(Wg[i * 8192 + k * 64 + col]);
  } else if (idx < S1 + S2 + S3 + S4 + S5 + S6) {
    int j = idx - S1 - S2 - S3 - S4 - S5;
    int h = j / 4096, r = j % 4096;
    int col = r >> 6, k = r & 63;
    Wc1t[j] = f2bf(Wc1[(h * 64 + k) * 64 + col]);
  }
}

// ---------------- embeddings ----------------
__global__ __launch_bounds__(256) void k_node_embed(
    const float* __restrict__ x, const int* __restrict__ zk, const float* __restrict__ zt,
    const float* __restrict__ Wn, const float* __restrict__ bn, float* __restrict__ nf, int N) {
  int n = blockIdx.x * 4 + (threadIdx.x >> 6);
  int lane = threadIdx.x & 63;
  if (n >= N) return;
  const float* xr = x + (size_t)n * 6;
  float acc = bn[lane];
#pragma unroll
  for (int d = 0; d < 6; ++d) acc = fmaf(xr[d], Wn[d * 64 + lane], acc);
  int zi = __float2int_rn(xr[2]);
  int idx = 0;
#pragma unroll
  for (int t = 5; t >= 0; --t)
    if (zi == zk[t]) idx = t;
  nf[(size_t)n * 64 + lane] = fmaxf(acc, 0.0f) + zt[idx * 64 + lane];
}

__global__ __launch_bounds__(256) void k_edge_embed(
    const float* __restrict__ x, const float* __restrict__ ea, const int* __restrict__ ei,
    const float* __restrict__ We, const float* __restrict__ be,
    unsigned short* __restrict__ ef, int E) {
  int e = blockIdx.x * 4 + (threadIdx.x >> 6);
  int lane = threadIdx.x & 63;
  if (e >= 2 * E) return;
  int e0 = (e < E) ? e : e - E;
  int s = ei[e];
  int d = (e < E) ? ei[E + e] : ei[e - E];
  const float* ar = ea + (size_t)e0 * 4;
  const float* xs = x + (size_t)s * 6;
  const float* xd = x + (size_t)d * 6;
  float in[7];
  in[0] = ar[0]; in[1] = ar[1]; in[2] = ar[2]; in[3] = ar[3];
  in[4] = xs[0] - xd[0]; in[5] = xs[1] - xd[1]; in[6] = xs[2] - xd[2];
  float acc = be[lane];
#pragma unroll
  for (int dd = 0; dd < 7; ++dd) acc = fmaf(in[dd], We[dd * 64 + lane], acc);
  ef[(size_t)e * 64 + lane] = f2bf(fmaxf(acc, 0.0f));
}

// ---------------- CBAM (vectorized, fp32 or bf16 buffer) ----------------
template <typename T>
__global__ __launch_bounds__(256) void k_pool_partial(const T* __restrict__ buf, int n,
                                                      float* __restrict__ pm, float* __restrict__ ps) {
  const int w = threadIdx.x >> 6, l = threadIdx.x & 63;
  const int rsub = l >> 4, c4 = (l & 15) << 2;
  float4 mx = make_float4(-INFINITY, -INFINITY, -INFINITY, -INFINITY);
  float4 sm = make_float4(0.f, 0.f, 0.f, 0.f);
  for (int r = blockIdx.x * 16 + w * 4 + rsub; r < n; r += gridDim.x * 16) {
    float4 v = ld4v(buf + (size_t)r * 64 + c4);
    mx.x = fmaxf(mx.x, v.x); mx.y = fmaxf(mx.y, v.y);
    mx.z = fmaxf(mx.z, v.z); mx.w = fmaxf(mx.w, v.w);
    sm.x += v.x; sm.y += v.y; sm.z += v.z; sm.w += v.w;
  }
#pragma unroll
  for (int d = 16; d < 64; d <<= 1) {
    mx.x = fmaxf(mx.x, __shfl_xor(mx.x, d)); mx.y = fmaxf(mx.y, __shfl_xor(mx.y, d));
    mx.z = fmaxf(mx.z, __shfl_xor(mx.z, d)); mx.w = fmaxf(mx.w, __shfl_xor(mx.w, d));
    sm.x += __shfl_xor(sm.x, d); sm.y += __shfl_xor(sm.y, d);
    sm.z += __shfl_xor(sm.z, d); sm.w += __shfl_xor(sm.w, d);
  }
  __shared__ float smx[4][64], ssm[4][64];
  if (l < 16) {
    *(float4*)&smx[w][c4] = mx;
    *(float4*)&ssm[w][c4] = sm;
  }
  __syncthreads();
  if (threadIdx.x < 64) {
    int t = threadIdx.x;
    float m2 = fmaxf(fmaxf(smx[0][t], smx[1][t]), fmaxf(smx[2][t], smx[3][t]));
    float s2 = ssm[0][t] + ssm[1][t] + ssm[2][t] + ssm[3][t];
    pm[blockIdx.x * 64 + t] = m2;
    ps[blockIdx.x * 64 + t] = s2;
  }
}

__global__ __launch_bounds__(256) void k_pool_final(
    const float* __restrict__ pm, const float* __restrict__ ps, int n, int nblk,
    const float* __restrict__ w1, const float* __restrict__ b1,
    const float* __restrict__ w2, const float* __restrict__ b2, float* __restrict__ cw) {
  __shared__ float redm[4][64], reds[4][64];
  __shared__ float cat[128];
  __shared__ float hid[4];
  int t = threadIdx.x;
  int g = t >> 6, col = t & 63;
  float mx = -INFINITY, sm = 0.0f;
  for (int p = g; p < nblk; p += 4) {
    mx = fmaxf(mx, pm[p * 64 + col]);
    sm += ps[p * 64 + col];
  }
  redm[g][col] = mx;
  reds[g][col] = sm;
  __syncthreads();
  if (t < 64) {
    float m2 = fmaxf(fmaxf(redm[0][t], redm[1][t]), fmaxf(redm[2][t], redm[3][t]));
    float s2 = reds[0][t] + reds[1][t] + reds[2][t] + reds[3][t];
    cat[t] = m2;
    cat[64 + t] = s2 / (float)n;
  }
  __syncthreads();
  if (t < 4) {
    float a = b1[t];
    for (int k = 0; k < 128; ++k) a = fmaf(cat[k], w1[k * 4 + t], a);
    hid[t] = fmaxf(a, 0.0f);
  }
  __syncthreads();
  if (t < 64) {
    float a = b2[t];
#pragma unroll
    for (int h = 0; h < 4; ++h) a = fmaf(hid[h], w2[h * 64 + t], a);
    cw[t] = sigm(a);
  }
}

template <typename T>
__global__ __launch_bounds__(256) void k_chan_sp(T* __restrict__ buf, int n,
                                                 const float* __restrict__ cw,
                                                 float* __restrict__ spmax, float* __restrict__ spmean) {
  const int w = threadIdx.x >> 6, l = threadIdx.x & 63;
  const int rsub = l >> 4, c4 = (l & 15) << 2;
  int r = blockIdx.x * 16 + w * 4 + rsub;
  if (r >= n) return;
  float4 cwv = *(const float4*)(cw + c4);
  float4 v = ld4v(buf + (size_t)r * 64 + c4);
  v.x *= cwv.x; v.y *= cwv.y; v.z *= cwv.z; v.w *= cwv.w;
  st4v(buf + (size_t)r * 64 + c4, v);
  float mx = fmaxf(fmaxf(v.x, v.y), fmaxf(v.z, v.w));
  float sm = v.x + v.y + v.z + v.w;
#pragma unroll
  for (int d = 1; d < 16; d <<= 1) {
    mx = fmaxf(mx, __shfl_xor(mx, d));
    sm += __shfl_xor(sm, d);
  }
  if ((l & 15) == 0) {
    spmax[r] = mx;
    spmean[r] = sm * (1.0f / 64.0f);
  }
}

__global__ __launch_bounds__(256) void k_conv(const float* __restrict__ spmax, const float* __restrict__ spmean,
                                              int n, const float* __restrict__ w1, const float* __restrict__ b1,
                                              const float* __restrict__ w2, const float* __restrict__ b2,
                                              float* __restrict__ s) {
  __shared__ float tl[258];
  int base = blockIdx.x * 256;
  for (int q = threadIdx.x; q < 258; q += 256) {
    int p = base - 1 + q;
    float t = 0.0f;
    if (p >= 0 && p < n) {
      float a = b1[0];
#pragma unroll
      for (int h = 0; h < 5; ++h) {
        int pp = p + h - 2;
        if (pp >= 0 && pp < n) a += spmax[pp] * w1[h] + spmean[pp] * w1[5 + h];
      }
      t = fmaxf(a, 0.0f);
    }
    tl[q] = t;
  }
  __syncthreads();
  int o = base + threadIdx.x;
  if (o < n) {
    float a = b2[0] + tl[threadIdx.x] * w2[0] + tl[threadIdx.x + 1] * w2[1] + tl[threadIdx.x + 2] * w2[2];
    s[o] = sigm(a);
  }
}

template <typename T>
__global__ __launch_bounds__(256) void k_row_scale(T* __restrict__ buf, int n, const float* __restrict__ s) {
  int i4 = blockIdx.x * 256 + threadIdx.x;
  if (i4 >= n * 16) return;
  int r = i4 >> 4;
  float sc = s[r];
  float4 v = ld4v(buf + (size_t)i4 * 4);
  v.x *= sc; v.y *= sc; v.z *= sc; v.w *= sc;
  st4v(buf + (size_t)i4 * 4, v);
}

// ---------------- agg + concat-LN (bf16 ef in, bf16 out) ----------------
__global__ __launch_bounds__(256) void k_aggcomb(const unsigned short* __restrict__ ef,
                                                 const float* __restrict__ nf,
                                                 const int* __restrict__ off, const int* __restrict__ elist,
                                                 unsigned short* __restrict__ comb, const float* __restrict__ g,
                                                 const float* __restrict__ b, int N) {
  int n = blockIdx.x * 4 + (threadIdx.x >> 6);
  int lane = threadIdx.x & 63;
  if (n >= N) return;
  float agg = 0.0f;
  int i0 = off[n], i1 = off[n + 1];
  for (int idx = i0; idx < i1; ++idx) agg += bf2f(ef[(size_t)elist[idx] * 64 + lane]);
  float y0 = nf[(size_t)n * 64 + lane];
  float y1 = agg - y0;
  float s1 = wsum(y0 + y1);
  float s2 = wsum(y0 * y0 + y1 * y1);
  float mu = s1 * (1.0f / 128.0f);
  float var = s2 * (1.0f / 128.0f) - mu * mu;
  float rs = rsqrtf(fmaxf(var, 0.0f) + LN_EPS);
  comb[(size_t)n * 128 + lane] = f2bf((y0 - mu) * rs * g[lane] + b[lane]);
  comb[(size_t)n * 128 + 64 + lane] = f2bf((y1 - mu) * rs * g[64 + lane] + b[64 + lane]);
}

// ---------------- MFMA GEMM: C[M,NC] = A[M,K](bf16) @ Bt[NC,K](bf16) -------
template <int MODE>
__global__ __launch_bounds__(256) void gemm_mfma(
    const unsigned short* __restrict__ A, int M, int K,
    const unsigned short* __restrict__ Bt, const float* __restrict__ bias,
    float* __restrict__ outF, unsigned short* __restrict__ outQ,
    unsigned short* __restrict__ outK, unsigned short* __restrict__ outS) {
  constexpr int SHN = (MODE == 0) ? (128 * 136) : (128 * 64 * 2);
  __shared__ unsigned short shmem[SHN];
  unsigned short* As = shmem;
  unsigned short* Bs = shmem + 128 * 64;
  const int tid = threadIdx.x;
  const int bm = blockIdx.x * 128;
  const int bn = blockIdx.y * 128;
  const int wid = tid >> 6, lane = tid & 63;
  const int wr = (wid >> 1) * 64, wc = (wid & 1) * 64;
  const int lrow = lane & 15, lkb = (lane >> 4) * 8;
  f32x4 acc[4][4];
#pragma unroll
  for (int m = 0; m < 4; ++m)
#pragma unroll
    for (int n = 0; n < 4; ++n) acc[m][n] = (f32x4){0.f, 0.f, 0.f, 0.f};

  for (int k0 = 0; k0 < K; k0 += 64) {
#pragma unroll
    for (int l = 0; l < 4; ++l) {
      int c = tid + l * 256;
      int row = c >> 3, kc = (c & 7) * 8;
      int sw = row * 64 + (kc ^ ((row & 7) << 3));
      int grow = bm + row;
      bf16x8 v = {0, 0, 0, 0, 0, 0, 0, 0};
      if (grow < M) v = *(const bf16x8*)(A + (size_t)grow * K + k0 + kc);
      *(bf16x8*)&As[sw] = v;
      int gcol = bn + row;
      *(bf16x8*)&Bs[sw] = *(const bf16x8*)(Bt + (size_t)gcol * K + k0 + kc);
    }
    __syncthreads();
#pragma unroll
    for (int ks = 0; ks < 2; ++ks) {
      const int ke = ks * 32 + lkb;
      bf16x8 af[4], bfr[4];
#pragma unroll
      for (int m = 0; m < 4; ++m) {
        int row = wr + m * 16 + lrow;
        af[m] = *(const bf16x8*)&As[row * 64 + (ke ^ ((row & 7) << 3))];
      }
#pragma unroll
      for (int n = 0; n < 4; ++n) {
        int col = wc + n * 16 + lrow;
        bfr[n] = *(const bf16x8*)&Bs[col * 64 + (ke ^ ((col & 7) << 3))];
      }
#pragma unroll
      for (int m = 0; m < 4; ++m)
#pragma unroll
        for (int n = 0; n < 4; ++n)
          acc[m][n] = __builtin_amdgcn_mfma_f32_16x16x32_bf16(af[m], bfr[n], acc[m][n], 0, 0, 0);
    }
    __syncthreads();
  }

  const int colw = lane & 15, rq = (lane >> 4) * 4;
  if (MODE == 1) {
#pragma unroll
    for (int m = 0; m < 4; ++m) {
#pragma unroll
      for (int n = 0; n < 4; ++n) {
        int gcol = bn + wc + n * 16 + colw;
        float bv = bias[gcol];
#pragma unroll
        for (int r = 0; r < 4; ++r) {
          int grow = bm + wr + m * 16 + rq + r;
          if (grow >= M) continue;
          outF[(size_t)grow * 256 + gcol] = acc[m][n][r] + bv;
        }
      }
    }
  } else {
    unsigned short* Cs = shmem;
#pragma unroll
    for (int m = 0; m < 4; ++m) {
#pragma unroll
      for (int n = 0; n < 4; ++n) {
        int col = wc + n * 16 + colw;
        float bv = bias[bn + col];
#pragma unroll
        for (int r = 0; r < 4; ++r) {
          int row = wr + m * 16 + rq + r;
          Cs[row * 136 + col] = f2bf(acc[m][n][r] + bv);
        }
      }
    }
    __syncthreads();
    const int proj = bn >> 8;
    const int cbase = bn & 255;
    const int rsub = tid >> 4, c8 = (tid & 15) * 8;
#pragma unroll
    for (int i = 0; i < 8; ++i) {
      int row = i * 16 + rsub;
      int grow = bm + row;
      if (grow >= M) continue;
      uint4 v = *(const uint4*)&Cs[row * 136 + c8];
      int cc = cbase + c8;
      if (proj == 0) *(uint4*)(outQ + (size_t)grow * 256 + cc) = v;
      else if (proj == 1) *(uint4*)(outK + (size_t)grow * 512 + cc) = v;
      else if (proj == 2) *(uint4*)(outK + (size_t)grow * 512 + 256 + cc) = v;
      else *(uint4*)(outS + (size_t)grow * 256 + cc) = v;
    }
  }
}

// ------ MFMA [M,64]@[64,64] with fused epilogue ------
// UPD 0: fp32 A, store fp32 C. UPD 1: fp32 A (nf), fp32 gate update.
// UPD 2: bf16 A (ef), bf16 gate update.
template <int UPD>
__global__ __launch_bounds__(256) void gemm_gate(
    const void* __restrict__ Av, int M, const unsigned short* __restrict__ Wt,
    const float* __restrict__ P, const float* __restrict__ bgv,
    const int* __restrict__ ei, void* __restrict__ updv) {
  __shared__ unsigned short As[128 * 64];
  __shared__ unsigned short Ws[64 * 64];
  const int tid = threadIdx.x;
  const int bm = blockIdx.x * 128;
  if (UPD == 2) {
    const unsigned short* Ab = (const unsigned short*)Av;
#pragma unroll
    for (int l = 0; l < 4; ++l) {
      int u = tid + l * 256;
      int row = u >> 3, kc = (u & 7) * 8;
      int grow = bm + row;
      bf16x8 v = {0, 0, 0, 0, 0, 0, 0, 0};
      if (grow < M) v = *(const bf16x8*)(Ab + (size_t)grow * 64 + kc);
      *(bf16x8*)&As[row * 64 + (kc ^ ((row & 7) << 3))] = v;
    }
  } else {
    const float* Af = (const float*)Av;
#pragma unroll
    for (int l = 0; l < 8; ++l) {
      int u = tid + l * 256;
      int row = u >> 4, k4 = (u & 15) << 2;
      int grow = bm + row;
      float4 v = make_float4(0.f, 0.f, 0.f, 0.f);
      if (grow < M) v = *(const float4*)(Af + (size_t)grow * 64 + k4);
      union { unsigned short h[4]; uint2 q; } pk;
      pk.h[0] = f2bf(v.x); pk.h[1] = f2bf(v.y); pk.h[2] = f2bf(v.z); pk.h[3] = f2bf(v.w);
      *(uint2*)&As[row * 64 + (k4 ^ ((row & 7) << 3))] = pk.q;
    }
  }
#pragma unroll
  for (int l = 0; l < 2; ++l) {
    int u = tid + l * 256;
    int row = u >> 3, kc = (u & 7) * 8;
    *(bf16x8*)&Ws[row * 64 + (kc ^ ((row & 7) << 3))] = *(const bf16x8*)(Wt + row * 64 + kc);
  }
  __syncthreads();
  const int wid = tid >> 6, lane = tid & 63;
  const int wr = wid * 32;
  const int lrow = lane & 15, lkb = (lane >> 4) * 8;
  f32x4 acc[2][4];
#pragma unroll
  for (int m = 0; m < 2; ++m)
#pragma unroll
    for (int n = 0; n < 4; ++n) acc[m][n] = (f32x4){0.f, 0.f, 0.f, 0.f};
#pragma unroll
  for (int ks = 0; ks < 2; ++ks) {
    const int ke = ks * 32 + lkb;
    bf16x8 af[2], wf[4];
#pragma unroll
    for (int m = 0; m < 2; ++m) {
      int row = wr + m * 16 + lrow;
      af[m] = *(const bf16x8*)&As[row * 64 + (ke ^ ((row & 7) << 3))];
    }
#pragma unroll
    for (int n = 0; n < 4; ++n) {
      int col = n * 16 + lrow;
      wf[n] = *(const bf16x8*)&Ws[col * 64 + (ke ^ ((col & 7) << 3))];
    }
#pragma unroll
    for (int m = 0; m < 2; ++m)
#pragma unroll
      for (int n = 0; n < 4; ++n)
        acc[m][n] = __builtin_amdgcn_mfma_f32_16x16x32_bf16(af[m], wf[n], acc[m][n], 0, 0, 0);
  }
  const int colw = lane & 15, rq = (lane >> 4) * 4;
#pragma unroll
  for (int m = 0; m < 2; ++m) {
#pragma unroll
    for (int r = 0; r < 4; ++r) {
      int e = bm + wr + m * 16 + rq + r;
      if (e >= M) continue;
      if (UPD == 0) {
        float* upd = (float*)updv;
#pragma unroll
        for (int n = 0; n < 4; ++n) upd[(size_t)e * 64 + n * 16 + colw] = acc[m][n][r];
      } else if (UPD == 1) {
        float* upd = (float*)updv;
        const float* Pr = P + (size_t)e * 256;
#pragma unroll
        for (int n = 0; n < 4; ++n) {
          int c = n * 16 + colw;
          float g = sigm(acc[m][n][r] + Pr[128 + c] + bgv[c]);
          size_t oi = (size_t)e * 64 + c;
          upd[oi] = upd[oi] * g + Pr[c] * (1.0f - g);
        }
      } else {
        unsigned short* upd = (unsigned short*)updv;
        int s = ei[e];
        const float* Pr = P + (size_t)s * 256;
#pragma unroll
        for (int n = 0; n < 4; ++n) {
          int c = n * 16 + colw;
          float g = sigm(acc[m][n][r] + Pr[192 + c] + bgv[c]);
          size_t oi = (size_t)e * 64 + c;
          float vA = bf2f(upd[oi]);
          upd[oi] = f2bf(vA * g + Pr[64 + c] * (1.0f - g));
        }
      }
    }
  }
}

// ---------------- attention: 2-edge unrolled, lane = (head, 4 cols) -------
__global__ __launch_bounds__(256) void k_attn(const unsigned short* __restrict__ qo,
                                              const unsigned short* __restrict__ kv,
                                              const unsigned short* __restrict__ skipb, const int* __restrict__ off,
                                              const int* __restrict__ slist,
                                              unsigned short* __restrict__ aob,
                                              const float* __restrict__ g, const float* __restrict__ b, int N) {
  int n = blockIdx.x * 4 + (threadIdx.x >> 6);
  int lane = threadIdx.x & 63;
  if (n >= N) return;
  union { uint2 u; unsigned short h[4]; } qq;
  qq.u = *(const uint2*)(qo + (size_t)n * 256 + 4 * lane);
  float q0 = bf2f(qq.h[0]), q1 = bf2f(qq.h[1]), q2 = bf2f(qq.h[2]), q3 = bf2f(qq.h[3]);
  float m = -INFINITY, lsum = 0.f;
  float a0 = 0.f, a1 = 0.f, a2 = 0.f, a3 = 0.f;
  int i0 = off[n], i1 = off[n + 1];
  int idx = i0;
  for (; idx + 2 <= i1; idx += 2) {
    int sA = slist[idx], sB = slist[idx + 1];
    const unsigned short* kbA = kv + (size_t)sA * 512;
    const unsigned short* kbB = kv + (size_t)sB * 512;
    union { uint2 u; unsigned short h[4]; } kkA, vvA, kkB, vvB;
    kkA.u = *(const uint2*)(kbA + 4 * lane);
    vvA.u = *(const uint2*)(kbA + 256 + 4 * lane);
    kkB.u = *(const uint2*)(kbB + 4 * lane);
    vvB.u = *(const uint2*)(kbB + 256 + 4 * lane);
    float dA = q0 * bf2f(kkA.h[0]) + q1 * bf2f(kkA.h[1]) + q2 * bf2f(kkA.h[2]) + q3 * bf2f(kkA.h[3]);
    float dB = q0 * bf2f(kkB.h[0]) + q1 * bf2f(kkB.h[1]) + q2 * bf2f(kkB.h[2]) + q3 * bf2f(kkB.h[3]);
#pragma unroll
    for (int dd = 1; dd < 16; dd <<= 1) {
      dA += __shfl_xor(dA, dd);
      dB += __shfl_xor(dB, dd);
    }
    dA *= 0.125f;
    dB *= 0.125f;
    float nm, sc, p;
    nm = fmaxf(m, dA); sc = __expf(m - nm); p = __expf(dA - nm);
    lsum = lsum * sc + p;
    a0 = fmaf(p, bf2f(vvA.h[0]), a0 * sc);
    a1 = fmaf(p, bf2f(vvA.h[1]), a1 * sc);
    a2 = fmaf(p, bf2f(vvA.h[2]), a2 * sc);
    a3 = fmaf(p, bf2f(vvA.h[3]), a3 * sc);
    m = nm;
    nm = fmaxf(m, dB); sc = __expf(m - nm); p = __expf(dB - nm);
    lsum = lsum * sc + p;
    a0 = fmaf(p, bf2f(vvB.h[0]), a0 * sc);
    a1 = fmaf(p, bf2f(vvB.h[1]), a1 * sc);
    a2 = fmaf(p, bf2f(vvB.h[2]), a2 * sc);
    a3 = fmaf(p, bf2f(vvB.h[3]), a3 * sc);
    m = nm;
  }
  if (idx < i1) {
    int s = slist[idx];
    const unsigned short* kb = kv + (size_t)s * 512;
    union { uint2 u; unsigned short h[4]; } kk, vv;
    kk.u = *(const uint2*)(kb + 4 * lane);
    vv.u = *(const uint2*)(kb + 256 + 4 * lane);
    float d = q0 * bf2f(kk.h[0]) + q1 * bf2f(kk.h[1]) + q2 * bf2f(kk.h[2]) + q3 * bf2f(kk.h[3]);
#pragma unroll
    for (int dd = 1; dd < 16; dd <<= 1) d += __shfl_xor(d, dd);
    d *= 0.125f;
    float nm = fmaxf(m, d);
    float sc = __expf(m - nm);
    float p = __expf(d - nm);
    lsum = lsum * sc + p;
    a0 = fmaf(p, bf2f(vv.h[0]), a0 * sc);
    a1 = fmaf(p, bf2f(vv.h[1]), a1 * sc);
    a2 = fmaf(p, bf2f(vv.h[2]), a2 * sc);
    a3 = fmaf(p, bf2f(vv.h[3]), a3 * sc);
    m = nm;
  }
  union { uint2 u; unsigned short h[4]; } sb;
  sb.u = *(const uint2*)(skipb + (size_t)n * 256 + 4 * lane);
  float inv = (lsum > 0.f) ? 1.0f / lsum : 0.f;
  float v0 = bf2f(sb.h[0]) + a0 * inv;
  float v1 = bf2f(sb.h[1]) + a1 * inv;
  float v2 = bf2f(sb.h[2]) + a2 * inv;
  float v3 = bf2f(sb.h[3]) + a3 * inv;
  float s1 = wsum(v0 + v1 + v2 + v3);
  float s2 = wsum(v0 * v0 + v1 * v1 + v2 * v2 + v3 * v3);
  float mu = s1 * (1.0f / 256.0f);
  float var = s2 * (1.0f / 256.0f) - mu * mu;
  float rs = rsqrtf(fmaxf(var, 0.0f) + LN_EPS);
  float4 g4 = *(const float4*)(g + 4 * lane);
  float4 b4 = *(const float4*)(b + 4 * lane);
  union { uint2 u; unsigned short h[4]; } ob;
  ob.h[0] = f2bf((v0 - mu) * rs * g4.x + b4.x);
  ob.h[1] = f2bf((v1 - mu) * rs * g4.y + b4.y);
  ob.h[2] = f2bf((v2 - mu) * rs * g4.z + b4.z);
  ob.h[3] = f2bf((v3 - mu) * rs * g4.w + b4.w);
  *(uint2*)(aob + (size_t)n * 256 + 4 * lane) = ob.u;
}

// ---------------- classifier pair kernel ----------------
__global__ __launch_bounds__(256) void k_clf_pair(const float* __restrict__ ABt, const float* __restrict__ ABb,
                                                  const int* __restrict__ ei, const float* __restrict__ bc1,
                                                  const float* __restrict__ Wc2, const float* __restrict__ bc2,
                                                  float* __restrict__ out, int E) {
  int e = blockIdx.x * 4 + (threadIdx.x >> 6);
  int lane = threadIdx.x & 63;
  if (e >= E) return;
  int s = ei[e], t = ei[E + e];
  float h = fmaxf(ABt[(size_t)s * 64 + lane] + ABb[(size_t)t * 64 + lane] + bc1[lane], 0.0f);
  float r = wsum(h * Wc2[lane]);
  if (lane == 0) out[e] = r + bc2[0];
}

// ============================================================================
extern "C" void kernel_launch(void* const* d_in, const int* in_sizes, int n_in,
                              void* d_out, int out_size, void* d_ws, size_t ws_size,
                              hipStream_t stream) {
  const float* x = (const float*)d_in[0];
  const float* edge_attr = (const float*)d_in[1];
  const int* ei = (const int*)d_in[2];
  const int* zk = (const int*)d_in[3];
  const float* z_table = (const float*)d_in[4];
  const float* W_node = (const float*)d_in[5];
  const float* b_node = (const float*)d_in[6];
  const float* W_edge = (const float*)d_in[7];
  const float* b_edge = (const float*)d_in[8];
  const float* cn_w1 = (const float*)d_in[9];
  const float* cn_b1 = (const float*)d_in[10];
  const float* cn_w2 = (const float*)d_in[11];
  const float* cn_b2 = (const float*)d_in[12];
  const float* cn_cw1 = (const float*)d_in[13];
  const float* cn_cb1 = (const float*)d_in[14];
  const float* cn_cw2 = (const float*)d_in[15];
  const float* cn_cb2 = (const float*)d_in[16];
  const float* ce_w1 = (const float*)d_in[17];
  const float* ce_b1 = (const float*)d_in[18];
  const float* ce_w2 = (const float*)d_in[19];
  const float* ce_b2 = (const float*)d_in[20];
  const float* ce_cw1 = (const float*)d_in[21];
  const float* ce_cb1 = (const float*)d_in[22];
  const float* ce_cw2 = (const float*)d_in[23];
  const float* ce_cb2 = (const float*)d_in[24];
  const float* ln_comb_g = (const float*)d_in[25];
  const float* ln_comb_b = (const float*)d_in[26];
  const float* Wq = (const float*)d_in[27];
  const float* bq = (const float*)d_in[28];
  const float* Wk = (const float*)d_in[29];
  const float* bk = (const float*)d_in[30];
  const float* Wv = (const float*)d_in[31];
  const float* bv = (const float*)d_in[32];
  const float* Wskip = (const float*)d_in[33];
  const float* bskip = (const float*)d_in[34];
  const float* ln_tc_g = (const float*)d_in[35];
  const float* ln_tc_b = (const float*)d_in[36];
  const float* Wpn = (const float*)d_in[37];
  const float* bpn = (const float*)d_in[38];
  const float* Wpe = (const float*)d_in[39];
  const float* bpe = (const float*)d_in[40];
  const float* Wg = (const float*)d_in[41];
  const float* bg = (const float*)d_in[42];
  const float* Wc1 = (const float*)d_in[43];
  const float* bc1 = (const float*)d_in[44];
  const float* Wc2 = (const float*)d_in[45];
  const float* bc2 = (const float*)d_in[46];
  float* out = (float*)d_out;

  const int N = in_sizes[0] / 6;   // 50000
  const int E = in_sizes[2] / 2;   // 100000
  const int E2 = 2 * E;

  // ---- workspace carve (~190 MB peak) ----
  char* p = (char*)d_ws;
  auto carve = [&](size_t bytes) -> void* {
    void* r = (void*)p;
    p += (bytes + 255) & ~(size_t)255;
    return r;
  };
  unsigned short* qo = (unsigned short*)carve((size_t)N * 256 * 2);    // Q bf16
  unsigned short* skipb = (unsigned short*)carve((size_t)N * 256 * 2); // skip bf16 | P(fp32) aliases
  unsigned short* kvb = (unsigned short*)carve((size_t)N * 512 * 2);   // K|V bf16
  unsigned short* aob = (unsigned short*)carve((size_t)N * 256 * 2);   // attn out bf16 -> AB f32
  unsigned short* efb = (unsigned short*)carve((size_t)E2 * 64 * 2);   // edge features bf16
  float* nf = (float*)carve((size_t)N * 64 * 4);
  unsigned short* comb = (unsigned short*)carve((size_t)N * 128 * 2);
  unsigned short* W1t = (unsigned short*)carve((size_t)3 * 1024 * 128 * 2);
  float* bias1 = (float*)carve((size_t)3 * 1024 * 4);
  unsigned short* B2t = (unsigned short*)carve((size_t)3 * 256 * 256 * 2);
  float* bias2 = (float*)carve((size_t)3 * 256 * 4);
  unsigned short* Wg1t = (unsigned short*)carve((size_t)3 * 64 * 64 * 2);
  unsigned short* Wc1t = (unsigned short*)carve((size_t)2 * 64 * 64 * 2);
  int* cnt = (int*)carve((size_t)N * 4);
  int* cur = (int*)carve((size_t)N * 4);
  int* off = (int*)carve((size_t)(N + 1) * 4);
  int* elist = (int*)carve((size_t)E2 * 4);
  int* slist = (int*)carve((size_t)E2 * 4);
  int* bsum = (int*)carve((size_t)256 * 4);
  int* boff = (int*)carve((size_t)256 * 4);
  float* pm = (float*)carve((size_t)PBLK * 64 * 4);
  float* ps = (float*)carve((size_t)PBLK * 64 * 4);
  float* cwv = (float*)carve(64 * 4);
  float* spmax = (float*)carve((size_t)E2 * 4);
  float* spmean = (float*)carve((size_t)E2 * 4);
  float* sconv = (float*)carve((size_t)E2 * 4);
  size_t need = (size_t)(p - (char*)d_ws);

  // P [N,256] fp32 aliases skipb+kvb-front (dead after k_attn; proven r7-r9)
  float* P = (float*)skipb;
  float* ABt = (float*)aob;
  float* ABb = (float*)aob + (size_t)N * 64;

  auto cdiv = [](int a, int b) { return (a + b - 1) / b; };

  if (ws_size < need) {
    k_sentinel<<<cdiv(E, 256), 256, 0, stream>>>(out, E);
    return;
  }

  // ---- CSR by dst (multi-block scan) ----
  k_zero2<<<cdiv(N, 256), 256, 0, stream>>>(cnt, cur, N);
  k_hist<<<cdiv(E2, 256), 256, 0, stream>>>(ei, cnt, E);
  const int nblk = cdiv(N, 1024);
  k_scan1<<<nblk, 256, 0, stream>>>(cnt, off, bsum, N);
  k_scan2<<<1, 64, 0, stream>>>(bsum, boff, off, N, nblk);
  k_scan3<<<cdiv(N, 256), 256, 0, stream>>>(off, boff, N);
  k_scatter<<<cdiv(E2, 256), 256, 0, stream>>>(ei, off, cur, elist, slist, E);

  // ---- pack weights (bf16 transposed) ----
  const int PACK = 3 * 1024 * 128 + 3 * 1024 + 3 * 256 * 256 + 3 * 256 + 3 * 64 * 64 + 2 * 64 * 64;
  k_packW<<<cdiv(PACK, 256), 256, 0, stream>>>(Wq, Wk, Wv, Wskip, bq, bk, bv, bskip,
                                               Wpn, Wpe, bpn, bpe, Wg, Wc1,
                                               W1t, bias1, B2t, bias2, Wg1t, Wc1t);

  // ---- embeddings ----
  k_node_embed<<<cdiv(N, 4), 256, 0, stream>>>(x, zk, z_table, W_node, b_node, nf, N);
  k_edge_embed<<<cdiv(E2, 4), 256, 0, stream>>>(x, edge_attr, ei, W_edge, b_edge, efb, E);

  // ---- CBAM: nodes (fp32) then edges (bf16) ----
  k_pool_partial<float><<<PBLK, 256, 0, stream>>>(nf, N, pm, ps);
  k_pool_final<<<1, 256, 0, stream>>>(pm, ps, N, PBLK, cn_w1, cn_b1, cn_w2, cn_b2, cwv);
  k_chan_sp<float><<<cdiv(N, 16), 256, 0, stream>>>(nf, N, cwv, spmax, spmean);
  k_conv<<<cdiv(N, 256), 256, 0, stream>>>(spmax, spmean, N, cn_cw1, cn_cb1, cn_cw2, cn_cb2, sconv);
  k_row_scale<float><<<cdiv(N * 16, 256), 256, 0, stream>>>(nf, N, sconv);

  k_pool_partial<unsigned short><<<PBLK, 256, 0, stream>>>(efb, E2, pm, ps);
  k_pool_final<<<1, 256, 0, stream>>>(pm, ps, E2, PBLK, ce_w1, ce_b1, ce_w2, ce_b2, cwv);
  k_chan_sp<unsigned short><<<cdiv(E2, 16), 256, 0, stream>>>(efb, E2, cwv, spmax, spmean);
  k_conv<<<cdiv(E2, 256), 256, 0, stream>>>(spmax, spmean, E2, ce_cw1, ce_cb1, ce_cw2, ce_cb2, sconv);
  k_row_scale<unsigned short><<<cdiv(E2 * 16, 256), 256, 0, stream>>>(efb, E2, sconv);

  // ---- T = 3 message-passing iterations ----
  dim3 gqkvs(cdiv(N, 128), 8);
  dim3 gp(cdiv(N, 128), 2);
  for (int i = 0; i < 3; ++i) {
    k_aggcomb<<<cdiv(N, 4), 256, 0, stream>>>(efb, nf, off, elist, comb,
                                              ln_comb_g + (size_t)i * 128, ln_comb_b + (size_t)i * 128, N);
    gemm_mfma<0><<<gqkvs, 256, 0, stream>>>(comb, N, 128, W1t + (size_t)i * 131072,
                                            bias1 + (size_t)i * 1024, nullptr, qo, kvb, skipb);
    k_attn<<<cdiv(N, 4), 256, 0, stream>>>(qo, kvb, skipb, off, slist, aob,
                                           ln_tc_g + (size_t)i * 256, ln_tc_b + (size_t)i * 256, N);
    gemm_mfma<1><<<gp, 256, 0, stream>>>(aob, N, 256, B2t + (size_t)i * 65536,
                                         bias2 + (size_t)i * 256, P, nullptr, nullptr, nullptr);
    gemm_gate<1><<<cdiv(N, 128), 256, 0, stream>>>(nf, N, Wg1t + (size_t)i * 4096, P,
                                                   bg + (size_t)i * 64, nullptr, nf);
    gemm_gate<2><<<cdiv(E2, 128), 256, 0, stream>>>(efb, E2, Wg1t + (size_t)i * 4096, P,
                                                    bg + (size_t)i * 64, ei, efb);
  }

  // ---- classifier ----
  gemm_gate<0><<<cdiv(N, 128), 256, 0, stream>>>(nf, N, Wc1t, nullptr, nullptr, nullptr, ABt);
  gemm_gate<0><<<cdiv(N, 128), 256, 0, stream>>>(nf, N, Wc1t + 4096, nullptr, nullptr, nullptr, ABb);
  k_clf_pair<<<cdiv(E, 4), 256, 0, stream>>>(ABt, ABb, ei, bc1, Wc2, bc2, out, E);
  (void)out_size;
  (void)n_in;
}

// Round 11
// 744.257 us; speedup vs baseline: 1.4248x; 1.0777x over previous
//
#include <hip/hip_runtime.h>

// ============================================================================
// New_LinkNet GNN forward — MFMA bf16 GEMMs + fused gate updates.
// Round-11 changes vs round 10 (802us; gemm_mfma<0> 48us with 37MB avoidable
// A-refetch across XCDs; P pipeline fp32 = 150MB/iter):
//  - gemm_mfma<0>: XCD-aware 1D-grid swizzle (8 col-blocks of one A row-tile
//    -> same XCD L2 chunk; bijective, nwg%8==0).
//  - P stored bf16: gemm_mfma<1> LDS-staged bf16 epilogue; gates bf2f-read P.
//    P aliases skipb exactly (both [N,256] bf16).
// ============================================================================

#define LN_EPS 1e-5f
#define PBLK 512

typedef __attribute__((ext_vector_type(8))) short bf16x8;
typedef __attribute__((ext_vector_type(4))) float f32x4;

static __device__ __forceinline__ float wsum(float v) {
#pragma unroll
  for (int d = 32; d > 0; d >>= 1) v += __shfl_xor(v, d);
  return v;
}
static __device__ __forceinline__ float sigm(float x) { return 1.0f / (1.0f + __expf(-x)); }
static __device__ __forceinline__ unsigned short f2bf(float f) {
  unsigned int u = __float_as_uint(f);
  u += 0x7FFFu + ((u >> 16) & 1u);
  return (unsigned short)(u >> 16);
}
static __device__ __forceinline__ float bf2f(unsigned short b) {
  return __uint_as_float(((unsigned int)b) << 16);
}
static __device__ __forceinline__ float4 ld4v(const float* p) { return *(const float4*)p; }
static __device__ __forceinline__ float4 ld4v(const unsigned short* p) {
  union { uint2 u; unsigned short h[4]; } t;
  t.u = *(const uint2*)p;
  return make_float4(bf2f(t.h[0]), bf2f(t.h[1]), bf2f(t.h[2]), bf2f(t.h[3]));
}
static __device__ __forceinline__ void st4v(float* p, float4 v) { *(float4*)p = v; }
static __device__ __forceinline__ void st4v(unsigned short* p, float4 v) {
  union { uint2 u; unsigned short h[4]; } t;
  t.h[0] = f2bf(v.x); t.h[1] = f2bf(v.y); t.h[2] = f2bf(v.z); t.h[3] = f2bf(v.w);
  *(uint2*)p = t.u;
}

// ---------------- util ----------------
__global__ __launch_bounds__(256) void k_zero2(int* __restrict__ a, int* __restrict__ b, int n) {
  int i = blockIdx.x * 256 + threadIdx.x;
  if (i < n) { a[i] = 0; b[i] = 0; }
}

__global__ __launch_bounds__(256) void k_sentinel(float* __restrict__ out, int n) {
  int i = blockIdx.x * 256 + threadIdx.x;
  if (i < n) out[i] = 1.0e6f;
}

// ---------------- CSR build (by dst) ----------------
__global__ __launch_bounds__(256) void k_hist(const int* __restrict__ ei, int* __restrict__ cnt, int E) {
  int e = blockIdx.x * 256 + threadIdx.x;
  if (e >= 2 * E) return;
  int d = (e < E) ? ei[E + e] : ei[e - E];
  atomicAdd(&cnt[d], 1);
}

__global__ __launch_bounds__(256) void k_scan1(const int* __restrict__ cnt, int* __restrict__ off,
                                               int* __restrict__ bsum, int n) {
  const int t = threadIdx.x;
  const int lane = t & 63, w = t >> 6;
  const int i0 = blockIdx.x * 1024 + t * 4;
  int v0 = (i0 + 0 < n) ? cnt[i0 + 0] : 0;
  int v1 = (i0 + 1 < n) ? cnt[i0 + 1] : 0;
  int v2 = (i0 + 2 < n) ? cnt[i0 + 2] : 0;
  int v3 = (i0 + 3 < n) ? cnt[i0 + 3] : 0;
  int s = v0 + v1 + v2 + v3;
  int sc = s;
#pragma unroll
  for (int d = 1; d < 64; d <<= 1) {
    int tv = __shfl_up(sc, d);
    if (lane >= d) sc += tv;
  }
  __shared__ int wsums[4];
  if (lane == 63) wsums[w] = sc;
  __syncthreads();
  int wbase = 0;
#pragma unroll
  for (int k = 0; k < 4; ++k)
    if (k < w) wbase += wsums[k];
  int run = wbase + sc - s;
  if (i0 + 0 < n) off[i0 + 0] = run; run += v0;
  if (i0 + 1 < n) off[i0 + 1] = run; run += v1;
  if (i0 + 2 < n) off[i0 + 2] = run; run += v2;
  if (i0 + 3 < n) off[i0 + 3] = run;
  if (t == 255) bsum[blockIdx.x] = wbase + sc;
}

__global__ __launch_bounds__(64) void k_scan2(const int* __restrict__ bsum, int* __restrict__ boff,
                                              int* __restrict__ off, int n, int nblk) {
  const int lane = threadIdx.x;
  int carry = 0;
  for (int base = 0; base < nblk; base += 64) {
    int i = base + lane;
    int v = (i < nblk) ? bsum[i] : 0;
    int sc = v;
#pragma unroll
    for (int d = 1; d < 64; d <<= 1) {
      int tv = __shfl_up(sc, d);
      if (lane >= d) sc += tv;
    }
    if (i < nblk) boff[i] = carry + sc - v;
    carry += __shfl(sc, 63);
  }
  if (lane == 0) off[n] = carry;
}

__global__ __launch_bounds__(256) void k_scan3(int* __restrict__ off, const int* __restrict__ boff, int n) {
  int i = blockIdx.x * 256 + threadIdx.x;
  if (i < n) off[i] += boff[i >> 10];
}

__global__ __launch_bounds__(256) void k_scatter(const int* __restrict__ ei, const int* __restrict__ off,
                                                 int* __restrict__ cur, int* __restrict__ elist,
                                                 int* __restrict__ slist, int E) {
  int e = blockIdx.x * 256 + threadIdx.x;
  if (e >= 2 * E) return;
  int d = (e < E) ? ei[E + e] : ei[e - E];
  int pos = atomicAdd(&cur[d], 1);
  int base = off[d] + pos;
  elist[base] = e;
  slist[base] = ei[e];
}

// ---------------- pack all transposed bf16 weights ----------------
__global__ __launch_bounds__(256) void k_packW(
    const float* __restrict__ Wq, const float* __restrict__ Wk, const float* __restrict__ Wv,
    const float* __restrict__ Ws, const float* __restrict__ bq, const float* __restrict__ bk,
    const float* __restrict__ bv, const float* __restrict__ bs,
    const float* __restrict__ Wpn, const float* __restrict__ Wpe,
    const float* __restrict__ bpn, const float* __restrict__ bpe,
    const float* __restrict__ Wg, const float* __restrict__ Wc1,
    unsigned short* __restrict__ W1t, float* __restrict__ bias1,
    unsigned short* __restrict__ B2t, float* __restrict__ bias2,
    unsigned short* __restrict__ Wg1t, unsigned short* __restrict__ Wc1t) {
  const int S1 = 3 * 1024 * 128, S2 = 3 * 1024, S3 = 3 * 256 * 256, S4 = 3 * 256;
  const int S5 = 3 * 64 * 64, S6 = 2 * 64 * 64;
  int idx = blockIdx.x * 256 + threadIdx.x;
  if (idx < S1) {
    int i = idx / 131072, r = idx % 131072;
    int col = r >> 7, k = r & 127;
    int m = col >> 8, cc = col & 255;
    const float* W = (m == 0) ? Wq : (m == 1) ? Wk : (m == 2) ? Wv : Ws;
    W1t[idx] = f2bf(W[i * 32768 + k * 256 + cc]);
  } else if (idx < S1 + S2) {
    int j = idx - S1;
    int i = j >> 10, col = j & 1023;
    int m = col >> 8, cc = col & 255;
    const float* bsrc = (m == 0) ? bq : (m == 1) ? bk : (m == 2) ? bv : bs;
    bias1[j] = bsrc[i * 256 + cc];
  } else if (idx < S1 + S2 + S3) {
    int j = idx - S1 - S2;
    int i = j / 65536, r = j % 65536;
    int col = r >> 8, k = r & 255;
    float v;
    if (col < 64) v = Wpn[i * 16384 + k * 64 + col];
    else if (col < 128) v = Wpe[i * 16384 + k * 64 + (col - 64)];
    else {
      const float* Wsrc = (col < 192) ? Wpn : Wpe;
      int cc = col & 63;
      float acc = 0.f;
      for (int jj = 0; jj < 64; ++jj)
        acc = fmaf(Wsrc[i * 16384 + k * 64 + jj], Wg[i * 8192 + (64 + jj) * 64 + cc], acc);
      v = acc;
    }
    B2t[j] = f2bf(v);
  } else if (idx < S1 + S2 + S3 + S4) {
    int j = idx - S1 - S2 - S3;
    int i = j >> 8, col = j & 255;
    float v;
    if (col < 64) v = bpn[i * 64 + col];
    else if (col < 128) v = bpe[i * 64 + col - 64];
    else {
      const float* bsrc = (col < 192) ? bpn : bpe;
      int cc = col & 63;
      float acc = 0.f;
      for (int jj = 0; jj < 64; ++jj)
        acc = fmaf(bsrc[i * 64 + jj], Wg[i * 8192 + (64 + jj) * 64 + cc], acc);
      v = acc;
    }
    bias2[j] = v;
  } else if (idx < S1 + S2 + S3 + S4 + S5) {
    int j = idx - S1 - S2 - S3 - S4;
    int i = j / 4096, r = j % 4096;
    int col = r >> 6, k = r & 63;
    Wg1t[j] = f2bf(Wg[i * 8192 + k * 64 + col]);
  } else if (idx < S1 + S2 + S3 + S4 + S5 + S6) {
    int j = idx - S1 - S2 - S3 - S4 - S5;
    int h = j / 4096, r = j % 4096;
    int col = r >> 6, k = r & 63;
    Wc1t[j] = f2bf(Wc1[(h * 64 + k) * 64 + col]);
  }
}

// ---------------- embeddings ----------------
__global__ __launch_bounds__(256) void k_node_embed(
    const float* __restrict__ x, const int* __restrict__ zk, const float* __restrict__ zt,
    const float* __restrict__ Wn, const float* __restrict__ bn, float* __restrict__ nf, int N) {
  int n = blockIdx.x * 4 + (threadIdx.x >> 6);
  int lane = threadIdx.x & 63;
  if (n >= N) return;
  const float* xr = x + (size_t)n * 6;
  float acc = bn[lane];
#pragma unroll
  for (int d = 0; d < 6; ++d) acc = fmaf(xr[d], Wn[d * 64 + lane], acc);
  int zi = __float2int_rn(xr[2]);
  int idx = 0;
#pragma unroll
  for (int t = 5; t >= 0; --t)
    if (zi == zk[t]) idx = t;
  nf[(size_t)n * 64 + lane] = fmaxf(acc, 0.0f) + zt[idx * 64 + lane];
}

__global__ __launch_bounds__(256) void k_edge_embed(
    const float* __restrict__ x, const float* __restrict__ ea, const int* __restrict__ ei,
    const float* __restrict__ We, const float* __restrict__ be,
    unsigned short* __restrict__ ef, int E) {
  int e = blockIdx.x * 4 + (threadIdx.x >> 6);
  int lane = threadIdx.x & 63;
  if (e >= 2 * E) return;
  int e0 = (e < E) ? e : e - E;
  int s = ei[e];
  int d = (e < E) ? ei[E + e] : ei[e - E];
  const float* ar = ea + (size_t)e0 * 4;
  const float* xs = x + (size_t)s * 6;
  const float* xd = x + (size_t)d * 6;
  float in[7];
  in[0] = ar[0]; in[1] = ar[1]; in[2] = ar[2]; in[3] = ar[3];
  in[4] = xs[0] - xd[0]; in[5] = xs[1] - xd[1]; in[6] = xs[2] - xd[2];
  float acc = be[lane];
#pragma unroll
  for (int dd = 0; dd < 7; ++dd) acc = fmaf(in[dd], We[dd * 64 + lane], acc);
  ef[(size_t)e * 64 + lane] = f2bf(fmaxf(acc, 0.0f));
}

// ---------------- CBAM (vectorized, fp32 or bf16 buffer) ----------------
template <typename T>
__global__ __launch_bounds__(256) void k_pool_partial(const T* __restrict__ buf, int n,
                                                      float* __restrict__ pm, float* __restrict__ ps) {
  const int w = threadIdx.x >> 6, l = threadIdx.x & 63;
  const int rsub = l >> 4, c4 = (l & 15) << 2;
  float4 mx = make_float4(-INFINITY, -INFINITY, -INFINITY, -INFINITY);
  float4 sm = make_float4(0.f, 0.f, 0.f, 0.f);
  for (int r = blockIdx.x * 16 + w * 4 + rsub; r < n; r += gridDim.x * 16) {
    float4 v = ld4v(buf + (size_t)r * 64 + c4);
    mx.x = fmaxf(mx.x, v.x); mx.y = fmaxf(mx.y, v.y);
    mx.z = fmaxf(mx.z, v.z); mx.w = fmaxf(mx.w, v.w);
    sm.x += v.x; sm.y += v.y; sm.z += v.z; sm.w += v.w;
  }
#pragma unroll
  for (int d = 16; d < 64; d <<= 1) {
    mx.x = fmaxf(mx.x, __shfl_xor(mx.x, d)); mx.y = fmaxf(mx.y, __shfl_xor(mx.y, d));
    mx.z = fmaxf(mx.z, __shfl_xor(mx.z, d)); mx.w = fmaxf(mx.w, __shfl_xor(mx.w, d));
    sm.x += __shfl_xor(sm.x, d); sm.y += __shfl_xor(sm.y, d);
    sm.z += __shfl_xor(sm.z, d); sm.w += __shfl_xor(sm.w, d);
  }
  __shared__ float smx[4][64], ssm[4][64];
  if (l < 16) {
    *(float4*)&smx[w][c4] = mx;
    *(float4*)&ssm[w][c4] = sm;
  }
  __syncthreads();
  if (threadIdx.x < 64) {
    int t = threadIdx.x;
    float m2 = fmaxf(fmaxf(smx[0][t], smx[1][t]), fmaxf(smx[2][t], smx[3][t]));
    float s2 = ssm[0][t] + ssm[1][t] + ssm[2][t] + ssm[3][t];
    pm[blockIdx.x * 64 + t] = m2;
    ps[blockIdx.x * 64 + t] = s2;
  }
}

__global__ __launch_bounds__(256) void k_pool_final(
    const float* __restrict__ pm, const float* __restrict__ ps, int n, int nblk,
    const float* __restrict__ w1, const float* __restrict__ b1,
    const float* __restrict__ w2, const float* __restrict__ b2, float* __restrict__ cw) {
  __shared__ float redm[4][64], reds[4][64];
  __shared__ float cat[128];
  __shared__ float hid[4];
  int t = threadIdx.x;
  int g = t >> 6, col = t & 63;
  float mx = -INFINITY, sm = 0.0f;
  for (int p = g; p < nblk; p += 4) {
    mx = fmaxf(mx, pm[p * 64 + col]);
    sm += ps[p * 64 + col];
  }
  redm[g][col] = mx;
  reds[g][col] = sm;
  __syncthreads();
  if (t < 64) {
    float m2 = fmaxf(fmaxf(redm[0][t], redm[1][t]), fmaxf(redm[2][t], redm[3][t]));
    float s2 = reds[0][t] + reds[1][t] + reds[2][t] + reds[3][t];
    cat[t] = m2;
    cat[64 + t] = s2 / (float)n;
  }
  __syncthreads();
  if (t < 4) {
    float a = b1[t];
    for (int k = 0; k < 128; ++k) a = fmaf(cat[k], w1[k * 4 + t], a);
    hid[t] = fmaxf(a, 0.0f);
  }
  __syncthreads();
  if (t < 64) {
    float a = b2[t];
#pragma unroll
    for (int h = 0; h < 4; ++h) a = fmaf(hid[h], w2[h * 64 + t], a);
    cw[t] = sigm(a);
  }
}

template <typename T>
__global__ __launch_bounds__(256) void k_chan_sp(T* __restrict__ buf, int n,
                                                 const float* __restrict__ cw,
                                                 float* __restrict__ spmax, float* __restrict__ spmean) {
  const int w = threadIdx.x >> 6, l = threadIdx.x & 63;
  const int rsub = l >> 4, c4 = (l & 15) << 2;
  int r = blockIdx.x * 16 + w * 4 + rsub;
  if (r >= n) return;
  float4 cwv = *(const float4*)(cw + c4);
  float4 v = ld4v(buf + (size_t)r * 64 + c4);
  v.x *= cwv.x; v.y *= cwv.y; v.z *= cwv.z; v.w *= cwv.w;
  st4v(buf + (size_t)r * 64 + c4, v);
  float mx = fmaxf(fmaxf(v.x, v.y), fmaxf(v.z, v.w));
  float sm = v.x + v.y + v.z + v.w;
#pragma unroll
  for (int d = 1; d < 16; d <<= 1) {
    mx = fmaxf(mx, __shfl_xor(mx, d));
    sm += __shfl_xor(sm, d);
  }
  if ((l & 15) == 0) {
    spmax[r] = mx;
    spmean[r] = sm * (1.0f / 64.0f);
  }
}

__global__ __launch_bounds__(256) void k_conv(const float* __restrict__ spmax, const float* __restrict__ spmean,
                                              int n, const float* __restrict__ w1, const float* __restrict__ b1,
                                              const float* __restrict__ w2, const float* __restrict__ b2,
                                              float* __restrict__ s) {
  __shared__ float tl[258];
  int base = blockIdx.x * 256;
  for (int q = threadIdx.x; q < 258; q += 256) {
    int p = base - 1 + q;
    float t = 0.0f;
    if (p >= 0 && p < n) {
      float a = b1[0];
#pragma unroll
      for (int h = 0; h < 5; ++h) {
        int pp = p + h - 2;
        if (pp >= 0 && pp < n) a += spmax[pp] * w1[h] + spmean[pp] * w1[5 + h];
      }
      t = fmaxf(a, 0.0f);
    }
    tl[q] = t;
  }
  __syncthreads();
  int o = base + threadIdx.x;
  if (o < n) {
    float a = b2[0] + tl[threadIdx.x] * w2[0] + tl[threadIdx.x + 1] * w2[1] + tl[threadIdx.x + 2] * w2[2];
    s[o] = sigm(a);
  }
}

template <typename T>
__global__ __launch_bounds__(256) void k_row_scale(T* __restrict__ buf, int n, const float* __restrict__ s) {
  int i4 = blockIdx.x * 256 + threadIdx.x;
  if (i4 >= n * 16) return;
  int r = i4 >> 4;
  float sc = s[r];
  float4 v = ld4v(buf + (size_t)i4 * 4);
  v.x *= sc; v.y *= sc; v.z *= sc; v.w *= sc;
  st4v(buf + (size_t)i4 * 4, v);
}

// ---------------- agg + concat-LN (bf16 ef in, bf16 out) ----------------
__global__ __launch_bounds__(256) void k_aggcomb(const unsigned short* __restrict__ ef,
                                                 const float* __restrict__ nf,
                                                 const int* __restrict__ off, const int* __restrict__ elist,
                                                 unsigned short* __restrict__ comb, const float* __restrict__ g,
                                                 const float* __restrict__ b, int N) {
  int n = blockIdx.x * 4 + (threadIdx.x >> 6);
  int lane = threadIdx.x & 63;
  if (n >= N) return;
  float agg = 0.0f;
  int i0 = off[n], i1 = off[n + 1];
  for (int idx = i0; idx < i1; ++idx) agg += bf2f(ef[(size_t)elist[idx] * 64 + lane]);
  float y0 = nf[(size_t)n * 64 + lane];
  float y1 = agg - y0;
  float s1 = wsum(y0 + y1);
  float s2 = wsum(y0 * y0 + y1 * y1);
  float mu = s1 * (1.0f / 128.0f);
  float var = s2 * (1.0f / 128.0f) - mu * mu;
  float rs = rsqrtf(fmaxf(var, 0.0f) + LN_EPS);
  comb[(size_t)n * 128 + lane] = f2bf((y0 - mu) * rs * g[lane] + b[lane]);
  comb[(size_t)n * 128 + 64 + lane] = f2bf((y1 - mu) * rs * g[64 + lane] + b[64 + lane]);
}

// ---------------- MFMA GEMM: C[M,NC] = A[M,K](bf16) @ Bt[NC,K](bf16) -------
// 64-wide K chunks, 0-conflict swizzle, LDS-staged bf16 epilogue (uint4).
// MODE 0: NC=1024 Q|K|V|S split; XCD-swizzled 1D grid (nwg = gx*8, gx=M/128).
// MODE 1: NC=256 single bf16 out (ld 256); 2D grid.
template <int MODE>
__global__ __launch_bounds__(256) void gemm_mfma(
    const unsigned short* __restrict__ A, int M, int K,
    const unsigned short* __restrict__ Bt, const float* __restrict__ bias,
    unsigned short* __restrict__ outQ, unsigned short* __restrict__ outK,
    unsigned short* __restrict__ outS) {
  __shared__ unsigned short shmem[128 * 136];
  unsigned short* As = shmem;
  unsigned short* Bs = shmem + 128 * 64;
  const int tid = threadIdx.x;
  int bm, bn;
  if (MODE == 0) {
    // XCD swizzle: consecutive hw blocks round-robin XCDs; remap so each
    // XCD gets a contiguous tile chunk => 8 col-tiles of one row-tile share L2.
    int cpx = gridDim.x >> 3;                                 // nwg/8
    int wgid = (blockIdx.x & 7) * cpx + (blockIdx.x >> 3);    // bijective
    bm = (wgid >> 3) * 128;
    bn = (wgid & 7) * 128;
  } else {
    bm = blockIdx.x * 128;
    bn = blockIdx.y * 128;
  }
  const int wid = tid >> 6, lane = tid & 63;
  const int wr = (wid >> 1) * 64, wc = (wid & 1) * 64;
  const int lrow = lane & 15, lkb = (lane >> 4) * 8;
  f32x4 acc[4][4];
#pragma unroll
  for (int m = 0; m < 4; ++m)
#pragma unroll
    for (int n = 0; n < 4; ++n) acc[m][n] = (f32x4){0.f, 0.f, 0.f, 0.f};

  for (int k0 = 0; k0 < K; k0 += 64) {
#pragma unroll
    for (int l = 0; l < 4; ++l) {
      int c = tid + l * 256;
      int row = c >> 3, kc = (c & 7) * 8;
      int sw = row * 64 + (kc ^ ((row & 7) << 3));
      int grow = bm + row;
      bf16x8 v = {0, 0, 0, 0, 0, 0, 0, 0};
      if (grow < M) v = *(const bf16x8*)(A + (size_t)grow * K + k0 + kc);
      *(bf16x8*)&As[sw] = v;
      int gcol = bn + row;
      *(bf16x8*)&Bs[sw] = *(const bf16x8*)(Bt + (size_t)gcol * K + k0 + kc);
    }
    __syncthreads();
#pragma unroll
    for (int ks = 0; ks < 2; ++ks) {
      const int ke = ks * 32 + lkb;
      bf16x8 af[4], bfr[4];
#pragma unroll
      for (int m = 0; m < 4; ++m) {
        int row = wr + m * 16 + lrow;
        af[m] = *(const bf16x8*)&As[row * 64 + (ke ^ ((row & 7) << 3))];
      }
#pragma unroll
      for (int n = 0; n < 4; ++n) {
        int col = wc + n * 16 + lrow;
        bfr[n] = *(const bf16x8*)&Bs[col * 64 + (ke ^ ((col & 7) << 3))];
      }
#pragma unroll
      for (int m = 0; m < 4; ++m)
#pragma unroll
        for (int n = 0; n < 4; ++n)
          acc[m][n] = __builtin_amdgcn_mfma_f32_16x16x32_bf16(af[m], bfr[n], acc[m][n], 0, 0, 0);
    }
    __syncthreads();
  }

  // LDS-staged bf16 epilogue: [128][136] rows (272B, 16B-aligned)
  const int colw = lane & 15, rq = (lane >> 4) * 4;
  unsigned short* Cs = shmem;
#pragma unroll
  for (int m = 0; m < 4; ++m) {
#pragma unroll
    for (int n = 0; n < 4; ++n) {
      int col = wc + n * 16 + colw;
      float bv = bias[bn + col];
#pragma unroll
      for (int r = 0; r < 4; ++r) {
        int row = wr + m * 16 + rq + r;
        Cs[row * 136 + col] = f2bf(acc[m][n][r] + bv);
      }
    }
  }
  __syncthreads();
  const int rsub = tid >> 4, c8 = (tid & 15) * 8;
#pragma unroll
  for (int i = 0; i < 8; ++i) {
    int row = i * 16 + rsub;
    int grow = bm + row;
    if (grow >= M) continue;
    uint4 v = *(const uint4*)&Cs[row * 136 + c8];
    if (MODE == 1) {
      *(uint4*)(outQ + (size_t)grow * 256 + bn + c8) = v;
    } else {
      const int proj = bn >> 8;
      int cc = (bn & 255) + c8;
      if (proj == 0) *(uint4*)(outQ + (size_t)grow * 256 + cc) = v;
      else if (proj == 1) *(uint4*)(outK + (size_t)grow * 512 + cc) = v;
      else if (proj == 2) *(uint4*)(outK + (size_t)grow * 512 + 256 + cc) = v;
      else *(uint4*)(outS + (size_t)grow * 256 + cc) = v;
    }
  }
}

// ------ MFMA [M,64]@[64,64] with fused epilogue ------
// UPD 0: fp32 A, store fp32 C. UPD 1: fp32 A (nf), fp32 gate update.
// UPD 2: bf16 A (ef), bf16 gate update. P is bf16 [N,256].
template <int UPD>
__global__ __launch_bounds__(256) void gemm_gate(
    const void* __restrict__ Av, int M, const unsigned short* __restrict__ Wt,
    const unsigned short* __restrict__ P, const float* __restrict__ bgv,
    const int* __restrict__ ei, void* __restrict__ updv) {
  __shared__ unsigned short As[128 * 64];
  __shared__ unsigned short Ws[64 * 64];
  const int tid = threadIdx.x;
  const int bm = blockIdx.x * 128;
  if (UPD == 2) {
    const unsigned short* Ab = (const unsigned short*)Av;
#pragma unroll
    for (int l = 0; l < 4; ++l) {
      int u = tid + l * 256;
      int row = u >> 3, kc = (u & 7) * 8;
      int grow = bm + row;
      bf16x8 v = {0, 0, 0, 0, 0, 0, 0, 0};
      if (grow < M) v = *(const bf16x8*)(Ab + (size_t)grow * 64 + kc);
      *(bf16x8*)&As[row * 64 + (kc ^ ((row & 7) << 3))] = v;
    }
  } else {
    const float* Af = (const float*)Av;
#pragma unroll
    for (int l = 0; l < 8; ++l) {
      int u = tid + l * 256;
      int row = u >> 4, k4 = (u & 15) << 2;
      int grow = bm + row;
      float4 v = make_float4(0.f, 0.f, 0.f, 0.f);
      if (grow < M) v = *(const float4*)(Af + (size_t)grow * 64 + k4);
      union { unsigned short h[4]; uint2 q; } pk;
      pk.h[0] = f2bf(v.x); pk.h[1] = f2bf(v.y); pk.h[2] = f2bf(v.z); pk.h[3] = f2bf(v.w);
      *(uint2*)&As[row * 64 + (k4 ^ ((row & 7) << 3))] = pk.q;
    }
  }
#pragma unroll
  for (int l = 0; l < 2; ++l) {
    int u = tid + l * 256;
    int row = u >> 3, kc = (u & 7) * 8;
    *(bf16x8*)&Ws[row * 64 + (kc ^ ((row & 7) << 3))] = *(const bf16x8*)(Wt + row * 64 + kc);
  }
  __syncthreads();
  const int wid = tid >> 6, lane = tid & 63;
  const int wr = wid * 32;
  const int lrow = lane & 15, lkb = (lane >> 4) * 8;
  f32x4 acc[2][4];
#pragma unroll
  for (int m = 0; m < 2; ++m)
#pragma unroll
    for (int n = 0; n < 4; ++n) acc[m][n] = (f32x4){0.f, 0.f, 0.f, 0.f};
#pragma unroll
  for (int ks = 0; ks < 2; ++ks) {
    const int ke = ks * 32 + lkb;
    bf16x8 af[2], wf[4];
#pragma unroll
    for (int m = 0; m < 2; ++m) {
      int row = wr + m * 16 + lrow;
      af[m] = *(const bf16x8*)&As[row * 64 + (ke ^ ((row & 7) << 3))];
    }
#pragma unroll
    for (int n = 0; n < 4; ++n) {
      int col = n * 16 + lrow;
      wf[n] = *(const bf16x8*)&Ws[col * 64 + (ke ^ ((col & 7) << 3))];
    }
#pragma unroll
    for (int m = 0; m < 2; ++m)
#pragma unroll
      for (int n = 0; n < 4; ++n)
        acc[m][n] = __builtin_amdgcn_mfma_f32_16x16x32_bf16(af[m], wf[n], acc[m][n], 0, 0, 0);
  }
  const int colw = lane & 15, rq = (lane >> 4) * 4;
#pragma unroll
  for (int m = 0; m < 2; ++m) {
#pragma unroll
    for (int r = 0; r < 4; ++r) {
      int e = bm + wr + m * 16 + rq + r;
      if (e >= M) continue;
      if (UPD == 0) {
        float* upd = (float*)updv;
#pragma unroll
        for (int n = 0; n < 4; ++n) upd[(size_t)e * 64 + n * 16 + colw] = acc[m][n][r];
      } else if (UPD == 1) {
        float* upd = (float*)updv;
        const unsigned short* Pr = P + (size_t)e * 256;
#pragma unroll
        for (int n = 0; n < 4; ++n) {
          int c = n * 16 + colw;
          float g = sigm(acc[m][n][r] + bf2f(Pr[128 + c]) + bgv[c]);
          size_t oi = (size_t)e * 64 + c;
          upd[oi] = upd[oi] * g + bf2f(Pr[c]) * (1.0f - g);
        }
      } else {
        unsigned short* upd = (unsigned short*)updv;
        int s = ei[e];
        const unsigned short* Pr = P + (size_t)s * 256;
#pragma unroll
        for (int n = 0; n < 4; ++n) {
          int c = n * 16 + colw;
          float g = sigm(acc[m][n][r] + bf2f(Pr[192 + c]) + bgv[c]);
          size_t oi = (size_t)e * 64 + c;
          float vA = bf2f(upd[oi]);
          upd[oi] = f2bf(vA * g + bf2f(Pr[64 + c]) * (1.0f - g));
        }
      }
    }
  }
}

// ---------------- attention: 2-edge unrolled, lane = (head, 4 cols) -------
__global__ __launch_bounds__(256) void k_attn(const unsigned short* __restrict__ qo,
                                              const unsigned short* __restrict__ kv,
                                              const unsigned short* __restrict__ skipb, const int* __restrict__ off,
                                              const int* __restrict__ slist,
                                              unsigned short* __restrict__ aob,
                                              const float* __restrict__ g, const float* __restrict__ b, int N) {
  int n = blockIdx.x * 4 + (threadIdx.x >> 6);
  int lane = threadIdx.x & 63;
  if (n >= N) return;
  union { uint2 u; unsigned short h[4]; } qq;
  qq.u = *(const uint2*)(qo + (size_t)n * 256 + 4 * lane);
  float q0 = bf2f(qq.h[0]), q1 = bf2f(qq.h[1]), q2 = bf2f(qq.h[2]), q3 = bf2f(qq.h[3]);
  float m = -INFINITY, lsum = 0.f;
  float a0 = 0.f, a1 = 0.f, a2 = 0.f, a3 = 0.f;
  int i0 = off[n], i1 = off[n + 1];
  int idx = i0;
  for (; idx + 2 <= i1; idx += 2) {
    int sA = slist[idx], sB = slist[idx + 1];
    const unsigned short* kbA = kv + (size_t)sA * 512;
    const unsigned short* kbB = kv + (size_t)sB * 512;
    union { uint2 u; unsigned short h[4]; } kkA, vvA, kkB, vvB;
    kkA.u = *(const uint2*)(kbA + 4 * lane);
    vvA.u = *(const uint2*)(kbA + 256 + 4 * lane);
    kkB.u = *(const uint2*)(kbB + 4 * lane);
    vvB.u = *(const uint2*)(kbB + 256 + 4 * lane);
    float dA = q0 * bf2f(kkA.h[0]) + q1 * bf2f(kkA.h[1]) + q2 * bf2f(kkA.h[2]) + q3 * bf2f(kkA.h[3]);
    float dB = q0 * bf2f(kkB.h[0]) + q1 * bf2f(kkB.h[1]) + q2 * bf2f(kkB.h[2]) + q3 * bf2f(kkB.h[3]);
#pragma unroll
    for (int dd = 1; dd < 16; dd <<= 1) {
      dA += __shfl_xor(dA, dd);
      dB += __shfl_xor(dB, dd);
    }
    dA *= 0.125f;
    dB *= 0.125f;
    float nm, sc, p;
    nm = fmaxf(m, dA); sc = __expf(m - nm); p = __expf(dA - nm);
    lsum = lsum * sc + p;
    a0 = fmaf(p, bf2f(vvA.h[0]), a0 * sc);
    a1 = fmaf(p, bf2f(vvA.h[1]), a1 * sc);
    a2 = fmaf(p, bf2f(vvA.h[2]), a2 * sc);
    a3 = fmaf(p, bf2f(vvA.h[3]), a3 * sc);
    m = nm;
    nm = fmaxf(m, dB); sc = __expf(m - nm); p = __expf(dB - nm);
    lsum = lsum * sc + p;
    a0 = fmaf(p, bf2f(vvB.h[0]), a0 * sc);
    a1 = fmaf(p, bf2f(vvB.h[1]), a1 * sc);
    a2 = fmaf(p, bf2f(vvB.h[2]), a2 * sc);
    a3 = fmaf(p, bf2f(vvB.h[3]), a3 * sc);
    m = nm;
  }
  if (idx < i1) {
    int s = slist[idx];
    const unsigned short* kb = kv + (size_t)s * 512;
    union { uint2 u; unsigned short h[4]; } kk, vv;
    kk.u = *(const uint2*)(kb + 4 * lane);
    vv.u = *(const uint2*)(kb + 256 + 4 * lane);
    float d = q0 * bf2f(kk.h[0]) + q1 * bf2f(kk.h[1]) + q2 * bf2f(kk.h[2]) + q3 * bf2f(kk.h[3]);
#pragma unroll
    for (int dd = 1; dd < 16; dd <<= 1) d += __shfl_xor(d, dd);
    d *= 0.125f;
    float nm = fmaxf(m, d);
    float sc = __expf(m - nm);
    float p = __expf(d - nm);
    lsum = lsum * sc + p;
    a0 = fmaf(p, bf2f(vv.h[0]), a0 * sc);
    a1 = fmaf(p, bf2f(vv.h[1]), a1 * sc);
    a2 = fmaf(p, bf2f(vv.h[2]), a2 * sc);
    a3 = fmaf(p, bf2f(vv.h[3]), a3 * sc);
    m = nm;
  }
  union { uint2 u; unsigned short h[4]; } sb;
  sb.u = *(const uint2*)(skipb + (size_t)n * 256 + 4 * lane);
  float inv = (lsum > 0.f) ? 1.0f / lsum : 0.f;
  float v0 = bf2f(sb.h[0]) + a0 * inv;
  float v1 = bf2f(sb.h[1]) + a1 * inv;
  float v2 = bf2f(sb.h[2]) + a2 * inv;
  float v3 = bf2f(sb.h[3]) + a3 * inv;
  float s1 = wsum(v0 + v1 + v2 + v3);
  float s2 = wsum(v0 * v0 + v1 * v1 + v2 * v2 + v3 * v3);
  float mu = s1 * (1.0f / 256.0f);
  float var = s2 * (1.0f / 256.0f) - mu * mu;
  float rs = rsqrtf(fmaxf(var, 0.0f) + LN_EPS);
  float4 g4 = *(const float4*)(g + 4 * lane);
  float4 b4 = *(const float4*)(b + 4 * lane);
  union { uint2 u; unsigned short h[4]; } ob;
  ob.h[0] = f2bf((v0 - mu) * rs * g4.x + b4.x);
  ob.h[1] = f2bf((v1 - mu) * rs * g4.y + b4.y);
  ob.h[2] = f2bf((v2 - mu) * rs * g4.z + b4.z);
  ob.h[3] = f2bf((v3 - mu) * rs * g4.w + b4.w);
  *(uint2*)(aob + (size_t)n * 256 + 4 * lane) = ob.u;
}

// ---------------- classifier pair kernel ----------------
__global__ __launch_bounds__(256) void k_clf_pair(const float* __restrict__ ABt, const float* __restrict__ ABb,
                                                  const int* __restrict__ ei, const float* __restrict__ bc1,
                                                  const float* __restrict__ Wc2, const float* __restrict__ bc2,
                                                  float* __restrict__ out, int E) {
  int e = blockIdx.x * 4 + (threadIdx.x >> 6);
  int lane = threadIdx.x & 63;
  if (e >= E) return;
  int s = ei[e], t = ei[E + e];
  float h = fmaxf(ABt[(size_t)s * 64 + lane] + ABb[(size_t)t * 64 + lane] + bc1[lane], 0.0f);
  float r = wsum(h * Wc2[lane]);
  if (lane == 0) out[e] = r + bc2[0];
}

// ============================================================================
extern "C" void kernel_launch(void* const* d_in, const int* in_sizes, int n_in,
                              void* d_out, int out_size, void* d_ws, size_t ws_size,
                              hipStream_t stream) {
  const float* x = (const float*)d_in[0];
  const float* edge_attr = (const float*)d_in[1];
  const int* ei = (const int*)d_in[2];
  const int* zk = (const int*)d_in[3];
  const float* z_table = (const float*)d_in[4];
  const float* W_node = (const float*)d_in[5];
  const float* b_node = (const float*)d_in[6];
  const float* W_edge = (const float*)d_in[7];
  const float* b_edge = (const float*)d_in[8];
  const float* cn_w1 = (const float*)d_in[9];
  const float* cn_b1 = (const float*)d_in[10];
  const float* cn_w2 = (const float*)d_in[11];
  const float* cn_b2 = (const float*)d_in[12];
  const float* cn_cw1 = (const float*)d_in[13];
  const float* cn_cb1 = (const float*)d_in[14];
  const float* cn_cw2 = (const float*)d_in[15];
  const float* cn_cb2 = (const float*)d_in[16];
  const float* ce_w1 = (const float*)d_in[17];
  const float* ce_b1 = (const float*)d_in[18];
  const float* ce_w2 = (const float*)d_in[19];
  const float* ce_b2 = (const float*)d_in[20];
  const float* ce_cw1 = (const float*)d_in[21];
  const float* ce_cb1 = (const float*)d_in[22];
  const float* ce_cw2 = (const float*)d_in[23];
  const float* ce_cb2 = (const float*)d_in[24];
  const float* ln_comb_g = (const float*)d_in[25];
  const float* ln_comb_b = (const float*)d_in[26];
  const float* Wq = (const float*)d_in[27];
  const float* bq = (const float*)d_in[28];
  const float* Wk = (const float*)d_in[29];
  const float* bk = (const float*)d_in[30];
  const float* Wv = (const float*)d_in[31];
  const float* bv = (const float*)d_in[32];
  const float* Wskip = (const float*)d_in[33];
  const float* bskip = (const float*)d_in[34];
  const float* ln_tc_g = (const float*)d_in[35];
  const float* ln_tc_b = (const float*)d_in[36];
  const float* Wpn = (const float*)d_in[37];
  const float* bpn = (const float*)d_in[38];
  const float* Wpe = (const float*)d_in[39];
  const float* bpe = (const float*)d_in[40];
  const float* Wg = (const float*)d_in[41];
  const float* bg = (const float*)d_in[42];
  const float* Wc1 = (const float*)d_in[43];
  const float* bc1 = (const float*)d_in[44];
  const float* Wc2 = (const float*)d_in[45];
  const float* bc2 = (const float*)d_in[46];
  float* out = (float*)d_out;

  const int N = in_sizes[0] / 6;   // 50000
  const int E = in_sizes[2] / 2;   // 100000
  const int E2 = 2 * E;

  // ---- workspace carve (~190 MB peak) ----
  char* p = (char*)d_ws;
  auto carve = [&](size_t bytes) -> void* {
    void* r = (void*)p;
    p += (bytes + 255) & ~(size_t)255;
    return r;
  };
  unsigned short* qo = (unsigned short*)carve((size_t)N * 256 * 2);    // Q bf16
  unsigned short* skipb = (unsigned short*)carve((size_t)N * 256 * 2); // skip bf16 -> P bf16 (exact alias)
  unsigned short* kvb = (unsigned short*)carve((size_t)N * 512 * 2);   // K|V bf16
  unsigned short* aob = (unsigned short*)carve((size_t)N * 256 * 2);   // attn out bf16 -> AB f32
  unsigned short* efb = (unsigned short*)carve((size_t)E2 * 64 * 2);   // edge features bf16
  float* nf = (float*)carve((size_t)N * 64 * 4);
  unsigned short* comb = (unsigned short*)carve((size_t)N * 128 * 2);
  unsigned short* W1t = (unsigned short*)carve((size_t)3 * 1024 * 128 * 2);
  float* bias1 = (float*)carve((size_t)3 * 1024 * 4);
  unsigned short* B2t = (unsigned short*)carve((size_t)3 * 256 * 256 * 2);
  float* bias2 = (float*)carve((size_t)3 * 256 * 4);
  unsigned short* Wg1t = (unsigned short*)carve((size_t)3 * 64 * 64 * 2);
  unsigned short* Wc1t = (unsigned short*)carve((size_t)2 * 64 * 64 * 2);
  int* cnt = (int*)carve((size_t)N * 4);
  int* cur = (int*)carve((size_t)N * 4);
  int* off = (int*)carve((size_t)(N + 1) * 4);
  int* elist = (int*)carve((size_t)E2 * 4);
  int* slist = (int*)carve((size_t)E2 * 4);
  int* bsum = (int*)carve((size_t)256 * 4);
  int* boff = (int*)carve((size_t)256 * 4);
  float* pm = (float*)carve((size_t)PBLK * 64 * 4);
  float* ps = (float*)carve((size_t)PBLK * 64 * 4);
  float* cwv = (float*)carve(64 * 4);
  float* spmax = (float*)carve((size_t)E2 * 4);
  float* spmean = (float*)carve((size_t)E2 * 4);
  float* sconv = (float*)carve((size_t)E2 * 4);
  size_t need = (size_t)(p - (char*)d_ws);

  // P [N,256] bf16 aliases skipb exactly (skip dead after k_attn; P written
  // by gemm_mfma<1>, consumed by gate kernels before next iter's QKVS GEMM).
  unsigned short* Pb = skipb;
  float* ABt = (float*)aob;
  float* ABb = (float*)aob + (size_t)N * 64;

  auto cdiv = [](int a, int b) { return (a + b - 1) / b; };

  if (ws_size < need) {
    k_sentinel<<<cdiv(E, 256), 256, 0, stream>>>(out, E);
    return;
  }

  // ---- CSR by dst (multi-block scan) ----
  k_zero2<<<cdiv(N, 256), 256, 0, stream>>>(cnt, cur, N);
  k_hist<<<cdiv(E2, 256), 256, 0, stream>>>(ei, cnt, E);
  const int nblk = cdiv(N, 1024);
  k_scan1<<<nblk, 256, 0, stream>>>(cnt, off, bsum, N);
  k_scan2<<<1, 64, 0, stream>>>(bsum, boff, off, N, nblk);
  k_scan3<<<cdiv(N, 256), 256, 0, stream>>>(off, boff, N);
  k_scatter<<<cdiv(E2, 256), 256, 0, stream>>>(ei, off, cur, elist, slist, E);

  // ---- pack weights (bf16 transposed) ----
  const int PACK = 3 * 1024 * 128 + 3 * 1024 + 3 * 256 * 256 + 3 * 256 + 3 * 64 * 64 + 2 * 64 * 64;
  k_packW<<<cdiv(PACK, 256), 256, 0, stream>>>(Wq, Wk, Wv, Wskip, bq, bk, bv, bskip,
                                               Wpn, Wpe, bpn, bpe, Wg, Wc1,
                                               W1t, bias1, B2t, bias2, Wg1t, Wc1t);

  // ---- embeddings ----
  k_node_embed<<<cdiv(N, 4), 256, 0, stream>>>(x, zk, z_table, W_node, b_node, nf, N);
  k_edge_embed<<<cdiv(E2, 4), 256, 0, stream>>>(x, edge_attr, ei, W_edge, b_edge, efb, E);

  // ---- CBAM: nodes (fp32) then edges (bf16) ----
  k_pool_partial<float><<<PBLK, 256, 0, stream>>>(nf, N, pm, ps);
  k_pool_final<<<1, 256, 0, stream>>>(pm, ps, N, PBLK, cn_w1, cn_b1, cn_w2, cn_b2, cwv);
  k_chan_sp<float><<<cdiv(N, 16), 256, 0, stream>>>(nf, N, cwv, spmax, spmean);
  k_conv<<<cdiv(N, 256), 256, 0, stream>>>(spmax, spmean, N, cn_cw1, cn_cb1, cn_cw2, cn_cb2, sconv);
  k_row_scale<float><<<cdiv(N * 16, 256), 256, 0, stream>>>(nf, N, sconv);

  k_pool_partial<unsigned short><<<PBLK, 256, 0, stream>>>(efb, E2, pm, ps);
  k_pool_final<<<1, 256, 0, stream>>>(pm, ps, E2, PBLK, ce_w1, ce_b1, ce_w2, ce_b2, cwv);
  k_chan_sp<unsigned short><<<cdiv(E2, 16), 256, 0, stream>>>(efb, E2, cwv, spmax, spmean);
  k_conv<<<cdiv(E2, 256), 256, 0, stream>>>(spmax, spmean, E2, ce_cw1, ce_cb1, ce_cw2, ce_cb2, sconv);
  k_row_scale<unsigned short><<<cdiv(E2 * 16, 256), 256, 0, stream>>>(efb, E2, sconv);

  // ---- T = 3 message-passing iterations ----
  const int gqkvs = cdiv(N, 128) * 8;  // 1D, XCD-swizzled in-kernel
  dim3 gp(cdiv(N, 128), 2);
  for (int i = 0; i < 3; ++i) {
    k_aggcomb<<<cdiv(N, 4), 256, 0, stream>>>(efb, nf, off, elist, comb,
                                              ln_comb_g + (size_t)i * 128, ln_comb_b + (size_t)i * 128, N);
    gemm_mfma<0><<<gqkvs, 256, 0, stream>>>(comb, N, 128, W1t + (size_t)i * 131072,
                                            bias1 + (size_t)i * 1024, qo, kvb, skipb);
    k_attn<<<cdiv(N, 4), 256, 0, stream>>>(qo, kvb, skipb, off, slist, aob,
                                           ln_tc_g + (size_t)i * 256, ln_tc_b + (size_t)i * 256, N);
    gemm_mfma<1><<<gp, 256, 0, stream>>>(aob, N, 256, B2t + (size_t)i * 65536,
                                         bias2 + (size_t)i * 256, Pb, nullptr, nullptr);
    gemm_gate<1><<<cdiv(N, 128), 256, 0, stream>>>(nf, N, Wg1t + (size_t)i * 4096, Pb,
                                                   bg + (size_t)i * 64, nullptr, nf);
    gemm_gate<2><<<cdiv(E2, 128), 256, 0, stream>>>(efb, E2, Wg1t + (size_t)i * 4096, Pb,
                                                    bg + (size_t)i * 64, ei, efb);
  }

  // ---- classifier ----
  gemm_gate<0><<<cdiv(N, 128), 256, 0, stream>>>(nf, N, Wc1t, nullptr, nullptr, nullptr, ABt);
  gemm_gate<0><<<cdiv(N, 128), 256, 0, stream>>>(nf, N, Wc1t + 4096, nullptr, nullptr, nullptr, ABb);
  k_clf_pair<<<cdiv(E, 4), 256, 0, stream>>>(ABt, ABb, ei, bc1, Wc2, bc2, out, E);
  (void)out_size;
  (void)n_in;
}

// Round 12
// 714.747 us; speedup vs baseline: 1.4836x; 1.0413x over previous
//
#include <hip/hip_runtime.h>

// ============================================================================
// New_LinkNet GNN forward — MFMA bf16 GEMMs + fused gate updates.
// Round-12 changes vs round 11 (744us; k_attn 43.6us latency on 2-deep gather
// chain; aggcomb random 128B-row elist gather):
//  - ef kept in CSR(dst) order after CBAM: k_scatter emits pinv; edge
//    k_row_scale scatters to efc[pinv[e]]; k_aggcomb streams contiguous rows
//    (elist removed); gemm_gate<2> reads src from slist.
//  - k_attn: 4-edge unroll (8 gathers in flight, interleaved shfl chains,
//    sequential softmax updates) + 2/1-edge tails.
// ============================================================================

#define LN_EPS 1e-5f
#define PBLK 512

typedef __attribute__((ext_vector_type(8))) short bf16x8;
typedef __attribute__((ext_vector_type(4))) float f32x4;

static __device__ __forceinline__ float wsum(float v) {
#pragma unroll
  for (int d = 32; d > 0; d >>= 1) v += __shfl_xor(v, d);
  return v;
}
static __device__ __forceinline__ float sigm(float x) { return 1.0f / (1.0f + __expf(-x)); }
static __device__ __forceinline__ unsigned short f2bf(float f) {
  unsigned int u = __float_as_uint(f);
  u += 0x7FFFu + ((u >> 16) & 1u);
  return (unsigned short)(u >> 16);
}
static __device__ __forceinline__ float bf2f(unsigned short b) {
  return __uint_as_float(((unsigned int)b) << 16);
}
static __device__ __forceinline__ float4 ld4v(const float* p) { return *(const float4*)p; }
static __device__ __forceinline__ float4 ld4v(const unsigned short* p) {
  union { uint2 u; unsigned short h[4]; } t;
  t.u = *(const uint2*)p;
  return make_float4(bf2f(t.h[0]), bf2f(t.h[1]), bf2f(t.h[2]), bf2f(t.h[3]));
}
static __device__ __forceinline__ void st4v(float* p, float4 v) { *(float4*)p = v; }
static __device__ __forceinline__ void st4v(unsigned short* p, float4 v) {
  union { uint2 u; unsigned short h[4]; } t;
  t.h[0] = f2bf(v.x); t.h[1] = f2bf(v.y); t.h[2] = f2bf(v.z); t.h[3] = f2bf(v.w);
  *(uint2*)p = t.u;
}

// ---------------- util ----------------
__global__ __launch_bounds__(256) void k_zero2(int* __restrict__ a, int* __restrict__ b, int n) {
  int i = blockIdx.x * 256 + threadIdx.x;
  if (i < n) { a[i] = 0; b[i] = 0; }
}

__global__ __launch_bounds__(256) void k_sentinel(float* __restrict__ out, int n) {
  int i = blockIdx.x * 256 + threadIdx.x;
  if (i < n) out[i] = 1.0e6f;
}

// ---------------- CSR build (by dst) ----------------
__global__ __launch_bounds__(256) void k_hist(const int* __restrict__ ei, int* __restrict__ cnt, int E) {
  int e = blockIdx.x * 256 + threadIdx.x;
  if (e >= 2 * E) return;
  int d = (e < E) ? ei[E + e] : ei[e - E];
  atomicAdd(&cnt[d], 1);
}

__global__ __launch_bounds__(256) void k_scan1(const int* __restrict__ cnt, int* __restrict__ off,
                                               int* __restrict__ bsum, int n) {
  const int t = threadIdx.x;
  const int lane = t & 63, w = t >> 6;
  const int i0 = blockIdx.x * 1024 + t * 4;
  int v0 = (i0 + 0 < n) ? cnt[i0 + 0] : 0;
  int v1 = (i0 + 1 < n) ? cnt[i0 + 1] : 0;
  int v2 = (i0 + 2 < n) ? cnt[i0 + 2] : 0;
  int v3 = (i0 + 3 < n) ? cnt[i0 + 3] : 0;
  int s = v0 + v1 + v2 + v3;
  int sc = s;
#pragma unroll
  for (int d = 1; d < 64; d <<= 1) {
    int tv = __shfl_up(sc, d);
    if (lane >= d) sc += tv;
  }
  __shared__ int wsums[4];
  if (lane == 63) wsums[w] = sc;
  __syncthreads();
  int wbase = 0;
#pragma unroll
  for (int k = 0; k < 4; ++k)
    if (k < w) wbase += wsums[k];
  int run = wbase + sc - s;
  if (i0 + 0 < n) off[i0 + 0] = run; run += v0;
  if (i0 + 1 < n) off[i0 + 1] = run; run += v1;
  if (i0 + 2 < n) off[i0 + 2] = run; run += v2;
  if (i0 + 3 < n) off[i0 + 3] = run;
  if (t == 255) bsum[blockIdx.x] = wbase + sc;
}

__global__ __launch_bounds__(64) void k_scan2(const int* __restrict__ bsum, int* __restrict__ boff,
                                              int* __restrict__ off, int n, int nblk) {
  const int lane = threadIdx.x;
  int carry = 0;
  for (int base = 0; base < nblk; base += 64) {
    int i = base + lane;
    int v = (i < nblk) ? bsum[i] : 0;
    int sc = v;
#pragma unroll
    for (int d = 1; d < 64; d <<= 1) {
      int tv = __shfl_up(sc, d);
      if (lane >= d) sc += tv;
    }
    if (i < nblk) boff[i] = carry + sc - v;
    carry += __shfl(sc, 63);
  }
  if (lane == 0) off[n] = carry;
}

__global__ __launch_bounds__(256) void k_scan3(int* __restrict__ off, const int* __restrict__ boff, int n) {
  int i = blockIdx.x * 256 + threadIdx.x;
  if (i < n) off[i] += boff[i >> 10];
}

// emits pinv (edge-id -> CSR position) and slist (CSR position -> src node)
__global__ __launch_bounds__(256) void k_scatter(const int* __restrict__ ei, const int* __restrict__ off,
                                                 int* __restrict__ cur, int* __restrict__ pinv,
                                                 int* __restrict__ slist, int E) {
  int e = blockIdx.x * 256 + threadIdx.x;
  if (e >= 2 * E) return;
  int d = (e < E) ? ei[E + e] : ei[e - E];
  int pos = atomicAdd(&cur[d], 1);
  int base = off[d] + pos;
  pinv[e] = base;
  slist[base] = ei[e];
}

// ---------------- pack all transposed bf16 weights ----------------
__global__ __launch_bounds__(256) void k_packW(
    const float* __restrict__ Wq, const float* __restrict__ Wk, const float* __restrict__ Wv,
    const float* __restrict__ Ws, const float* __restrict__ bq, const float* __restrict__ bk,
    const float* __restrict__ bv, const float* __restrict__ bs,
    const float* __restrict__ Wpn, const float* __restrict__ Wpe,
    const float* __restrict__ bpn, const float* __restrict__ bpe,
    const float* __restrict__ Wg, const float* __restrict__ Wc1,
    unsigned short* __restrict__ W1t, float* __restrict__ bias1,
    unsigned short* __restrict__ B2t, float* __restrict__ bias2,
    unsigned short* __restrict__ Wg1t, unsigned short* __restrict__ Wc1t) {
  const int S1 = 3 * 1024 * 128, S2 = 3 * 1024, S3 = 3 * 256 * 256, S4 = 3 * 256;
  const int S5 = 3 * 64 * 64, S6 = 2 * 64 * 64;
  int idx = blockIdx.x * 256 + threadIdx.x;
  if (idx < S1) {
    int i = idx / 131072, r = idx % 131072;
    int col = r >> 7, k = r & 127;
    int m = col >> 8, cc = col & 255;
    const float* W = (m == 0) ? Wq : (m == 1) ? Wk : (m == 2) ? Wv : Ws;
    W1t[idx] = f2bf(W[i * 32768 + k * 256 + cc]);
  } else if (idx < S1 + S2) {
    int j = idx - S1;
    int i = j >> 10, col = j & 1023;
    int m = col >> 8, cc = col & 255;
    const float* bsrc = (m == 0) ? bq : (m == 1) ? bk : (m == 2) ? bv : bs;
    bias1[j] = bsrc[i * 256 + cc];
  } else if (idx < S1 + S2 + S3) {
    int j = idx - S1 - S2;
    int i = j / 65536, r = j % 65536;
    int col = r >> 8, k = r & 255;
    float v;
    if (col < 64) v = Wpn[i * 16384 + k * 64 + col];
    else if (col < 128) v = Wpe[i * 16384 + k * 64 + (col - 64)];
    else {
      const float* Wsrc = (col < 192) ? Wpn : Wpe;
      int cc = col & 63;
      float acc = 0.f;
      for (int jj = 0; jj < 64; ++jj)
        acc = fmaf(Wsrc[i * 16384 + k * 64 + jj], Wg[i * 8192 + (64 + jj) * 64 + cc], acc);
      v = acc;
    }
    B2t[j] = f2bf(v);
  } else if (idx < S1 + S2 + S3 + S4) {
    int j = idx - S1 - S2 - S3;
    int i = j >> 8, col = j & 255;
    float v;
    if (col < 64) v = bpn[i * 64 + col];
    else if (col < 128) v = bpe[i * 64 + col - 64];
    else {
      const float* bsrc = (col < 192) ? bpn : bpe;
      int cc = col & 63;
      float acc = 0.f;
      for (int jj = 0; jj < 64; ++jj)
        acc = fmaf(bsrc[i * 64 + jj], Wg[i * 8192 + (64 + jj) * 64 + cc], acc);
      v = acc;
    }
    bias2[j] = v;
  } else if (idx < S1 + S2 + S3 + S4 + S5) {
    int j = idx - S1 - S2 - S3 - S4;
    int i = j / 4096, r = j % 4096;
    int col = r >> 6, k = r & 63;
    Wg1t[j] = f2bf(Wg[i * 8192 + k * 64 + col]);
  } else if (idx < S1 + S2 + S3 + S4 + S5 + S6) {
    int j = idx - S1 - S2 - S3 - S4 - S5;
    int h = j / 4096, r = j % 4096;
    int col = r >> 6, k = r & 63;
    Wc1t[j] = f2bf(Wc1[(h * 64 + k) * 64 + col]);
  }
}

// ---------------- embeddings ----------------
__global__ __launch_bounds__(256) void k_node_embed(
    const float* __restrict__ x, const int* __restrict__ zk, const float* __restrict__ zt,
    const float* __restrict__ Wn, const float* __restrict__ bn, float* __restrict__ nf, int N) {
  int n = blockIdx.x * 4 + (threadIdx.x >> 6);
  int lane = threadIdx.x & 63;
  if (n >= N) return;
  const float* xr = x + (size_t)n * 6;
  float acc = bn[lane];
#pragma unroll
  for (int d = 0; d < 6; ++d) acc = fmaf(xr[d], Wn[d * 64 + lane], acc);
  int zi = __float2int_rn(xr[2]);
  int idx = 0;
#pragma unroll
  for (int t = 5; t >= 0; --t)
    if (zi == zk[t]) idx = t;
  nf[(size_t)n * 64 + lane] = fmaxf(acc, 0.0f) + zt[idx * 64 + lane];
}

__global__ __launch_bounds__(256) void k_edge_embed(
    const float* __restrict__ x, const float* __restrict__ ea, const int* __restrict__ ei,
    const float* __restrict__ We, const float* __restrict__ be,
    unsigned short* __restrict__ ef, int E) {
  int e = blockIdx.x * 4 + (threadIdx.x >> 6);
  int lane = threadIdx.x & 63;
  if (e >= 2 * E) return;
  int e0 = (e < E) ? e : e - E;
  int s = ei[e];
  int d = (e < E) ? ei[E + e] : ei[e - E];
  const float* ar = ea + (size_t)e0 * 4;
  const float* xs = x + (size_t)s * 6;
  const float* xd = x + (size_t)d * 6;
  float in[7];
  in[0] = ar[0]; in[1] = ar[1]; in[2] = ar[2]; in[3] = ar[3];
  in[4] = xs[0] - xd[0]; in[5] = xs[1] - xd[1]; in[6] = xs[2] - xd[2];
  float acc = be[lane];
#pragma unroll
  for (int dd = 0; dd < 7; ++dd) acc = fmaf(in[dd], We[dd * 64 + lane], acc);
  ef[(size_t)e * 64 + lane] = f2bf(fmaxf(acc, 0.0f));
}

// ---------------- CBAM (vectorized, fp32 or bf16 buffer) ----------------
template <typename T>
__global__ __launch_bounds__(256) void k_pool_partial(const T* __restrict__ buf, int n,
                                                      float* __restrict__ pm, float* __restrict__ ps) {
  const int w = threadIdx.x >> 6, l = threadIdx.x & 63;
  const int rsub = l >> 4, c4 = (l & 15) << 2;
  float4 mx = make_float4(-INFINITY, -INFINITY, -INFINITY, -INFINITY);
  float4 sm = make_float4(0.f, 0.f, 0.f, 0.f);
  for (int r = blockIdx.x * 16 + w * 4 + rsub; r < n; r += gridDim.x * 16) {
    float4 v = ld4v(buf + (size_t)r * 64 + c4);
    mx.x = fmaxf(mx.x, v.x); mx.y = fmaxf(mx.y, v.y);
    mx.z = fmaxf(mx.z, v.z); mx.w = fmaxf(mx.w, v.w);
    sm.x += v.x; sm.y += v.y; sm.z += v.z; sm.w += v.w;
  }
#pragma unroll
  for (int d = 16; d < 64; d <<= 1) {
    mx.x = fmaxf(mx.x, __shfl_xor(mx.x, d)); mx.y = fmaxf(mx.y, __shfl_xor(mx.y, d));
    mx.z = fmaxf(mx.z, __shfl_xor(mx.z, d)); mx.w = fmaxf(mx.w, __shfl_xor(mx.w, d));
    sm.x += __shfl_xor(sm.x, d); sm.y += __shfl_xor(sm.y, d);
    sm.z += __shfl_xor(sm.z, d); sm.w += __shfl_xor(sm.w, d);
  }
  __shared__ float smx[4][64], ssm[4][64];
  if (l < 16) {
    *(float4*)&smx[w][c4] = mx;
    *(float4*)&ssm[w][c4] = sm;
  }
  __syncthreads();
  if (threadIdx.x < 64) {
    int t = threadIdx.x;
    float m2 = fmaxf(fmaxf(smx[0][t], smx[1][t]), fmaxf(smx[2][t], smx[3][t]));
    float s2 = ssm[0][t] + ssm[1][t] + ssm[2][t] + ssm[3][t];
    pm[blockIdx.x * 64 + t] = m2;
    ps[blockIdx.x * 64 + t] = s2;
  }
}

__global__ __launch_bounds__(256) void k_pool_final(
    const float* __restrict__ pm, const float* __restrict__ ps, int n, int nblk,
    const float* __restrict__ w1, const float* __restrict__ b1,
    const float* __restrict__ w2, const float* __restrict__ b2, float* __restrict__ cw) {
  __shared__ float redm[4][64], reds[4][64];
  __shared__ float cat[128];
  __shared__ float hid[4];
  int t = threadIdx.x;
  int g = t >> 6, col = t & 63;
  float mx = -INFINITY, sm = 0.0f;
  for (int p = g; p < nblk; p += 4) {
    mx = fmaxf(mx, pm[p * 64 + col]);
    sm += ps[p * 64 + col];
  }
  redm[g][col] = mx;
  reds[g][col] = sm;
  __syncthreads();
  if (t < 64) {
    float m2 = fmaxf(fmaxf(redm[0][t], redm[1][t]), fmaxf(redm[2][t], redm[3][t]));
    float s2 = reds[0][t] + reds[1][t] + reds[2][t] + reds[3][t];
    cat[t] = m2;
    cat[64 + t] = s2 / (float)n;
  }
  __syncthreads();
  if (t < 4) {
    float a = b1[t];
    for (int k = 0; k < 128; ++k) a = fmaf(cat[k], w1[k * 4 + t], a);
    hid[t] = fmaxf(a, 0.0f);
  }
  __syncthreads();
  if (t < 64) {
    float a = b2[t];
#pragma unroll
    for (int h = 0; h < 4; ++h) a = fmaf(hid[h], w2[h * 64 + t], a);
    cw[t] = sigm(a);
  }
}

template <typename T>
__global__ __launch_bounds__(256) void k_chan_sp(T* __restrict__ buf, int n,
                                                 const float* __restrict__ cw,
                                                 float* __restrict__ spmax, float* __restrict__ spmean) {
  const int w = threadIdx.x >> 6, l = threadIdx.x & 63;
  const int rsub = l >> 4, c4 = (l & 15) << 2;
  int r = blockIdx.x * 16 + w * 4 + rsub;
  if (r >= n) return;
  float4 cwv = *(const float4*)(cw + c4);
  float4 v = ld4v(buf + (size_t)r * 64 + c4);
  v.x *= cwv.x; v.y *= cwv.y; v.z *= cwv.z; v.w *= cwv.w;
  st4v(buf + (size_t)r * 64 + c4, v);
  float mx = fmaxf(fmaxf(v.x, v.y), fmaxf(v.z, v.w));
  float sm = v.x + v.y + v.z + v.w;
#pragma unroll
  for (int d = 1; d < 16; d <<= 1) {
    mx = fmaxf(mx, __shfl_xor(mx, d));
    sm += __shfl_xor(sm, d);
  }
  if ((l & 15) == 0) {
    spmax[r] = mx;
    spmean[r] = sm * (1.0f / 64.0f);
  }
}

__global__ __launch_bounds__(256) void k_conv(const float* __restrict__ spmax, const float* __restrict__ spmean,
                                              int n, const float* __restrict__ w1, const float* __restrict__ b1,
                                              const float* __restrict__ w2, const float* __restrict__ b2,
                                              float* __restrict__ s) {
  __shared__ float tl[258];
  int base = blockIdx.x * 256;
  for (int q = threadIdx.x; q < 258; q += 256) {
    int p = base - 1 + q;
    float t = 0.0f;
    if (p >= 0 && p < n) {
      float a = b1[0];
#pragma unroll
      for (int h = 0; h < 5; ++h) {
        int pp = p + h - 2;
        if (pp >= 0 && pp < n) a += spmax[pp] * w1[h] + spmean[pp] * w1[5 + h];
      }
      t = fmaxf(a, 0.0f);
    }
    tl[q] = t;
  }
  __syncthreads();
  int o = base + threadIdx.x;
  if (o < n) {
    float a = b2[0] + tl[threadIdx.x] * w2[0] + tl[threadIdx.x + 1] * w2[1] + tl[threadIdx.x + 2] * w2[2];
    s[o] = sigm(a);
  }
}

__global__ __launch_bounds__(256) void k_row_scale(float* __restrict__ buf, int n, const float* __restrict__ s) {
  int i4 = blockIdx.x * 256 + threadIdx.x;
  if (i4 >= n * 16) return;
  int r = i4 >> 4;
  float sc = s[r];
  float4 v = ld4v(buf + (size_t)i4 * 4);
  v.x *= sc; v.y *= sc; v.z *= sc; v.w *= sc;
  st4v(buf + (size_t)i4 * 4, v);
}

// bf16 row scale + scatter to CSR position (efc[pinv[r]] = efb[r] * s[r])
__global__ __launch_bounds__(256) void k_row_scale_perm(const unsigned short* __restrict__ src, int n,
                                                        const float* __restrict__ s,
                                                        const int* __restrict__ pinv,
                                                        unsigned short* __restrict__ dst) {
  int i4 = blockIdx.x * 256 + threadIdx.x;
  if (i4 >= n * 16) return;
  int r = i4 >> 4, c4 = (i4 & 15) * 4;
  float sc = s[r];
  float4 v = ld4v(src + (size_t)r * 64 + c4);
  v.x *= sc; v.y *= sc; v.z *= sc; v.w *= sc;
  st4v(dst + (size_t)pinv[r] * 64 + c4, v);
}

// ---------------- agg + concat-LN (CSR-ordered bf16 ef, streaming) --------
__global__ __launch_bounds__(256) void k_aggcomb(const unsigned short* __restrict__ efc,
                                                 const float* __restrict__ nf,
                                                 const int* __restrict__ off,
                                                 unsigned short* __restrict__ comb, const float* __restrict__ g,
                                                 const float* __restrict__ b, int N) {
  int n = blockIdx.x * 4 + (threadIdx.x >> 6);
  int lane = threadIdx.x & 63;
  if (n >= N) return;
  float agg = 0.0f;
  int i0 = off[n], i1 = off[n + 1];
  for (int idx = i0; idx < i1; ++idx) agg += bf2f(efc[(size_t)idx * 64 + lane]);
  float y0 = nf[(size_t)n * 64 + lane];
  float y1 = agg - y0;
  float s1 = wsum(y0 + y1);
  float s2 = wsum(y0 * y0 + y1 * y1);
  float mu = s1 * (1.0f / 128.0f);
  float var = s2 * (1.0f / 128.0f) - mu * mu;
  float rs = rsqrtf(fmaxf(var, 0.0f) + LN_EPS);
  comb[(size_t)n * 128 + lane] = f2bf((y0 - mu) * rs * g[lane] + b[lane]);
  comb[(size_t)n * 128 + 64 + lane] = f2bf((y1 - mu) * rs * g[64 + lane] + b[64 + lane]);
}

// ---------------- MFMA GEMM: C[M,NC] = A[M,K](bf16) @ Bt[NC,K](bf16) -------
template <int MODE>
__global__ __launch_bounds__(256) void gemm_mfma(
    const unsigned short* __restrict__ A, int M, int K,
    const unsigned short* __restrict__ Bt, const float* __restrict__ bias,
    unsigned short* __restrict__ outQ, unsigned short* __restrict__ outK,
    unsigned short* __restrict__ outS) {
  __shared__ unsigned short shmem[128 * 136];
  unsigned short* As = shmem;
  unsigned short* Bs = shmem + 128 * 64;
  const int tid = threadIdx.x;
  int bm, bn;
  if (MODE == 0) {
    int cpx = gridDim.x >> 3;
    int wgid = (blockIdx.x & 7) * cpx + (blockIdx.x >> 3);
    bm = (wgid >> 3) * 128;
    bn = (wgid & 7) * 128;
  } else {
    bm = blockIdx.x * 128;
    bn = blockIdx.y * 128;
  }
  const int wid = tid >> 6, lane = tid & 63;
  const int wr = (wid >> 1) * 64, wc = (wid & 1) * 64;
  const int lrow = lane & 15, lkb = (lane >> 4) * 8;
  f32x4 acc[4][4];
#pragma unroll
  for (int m = 0; m < 4; ++m)
#pragma unroll
    for (int n = 0; n < 4; ++n) acc[m][n] = (f32x4){0.f, 0.f, 0.f, 0.f};

  for (int k0 = 0; k0 < K; k0 += 64) {
#pragma unroll
    for (int l = 0; l < 4; ++l) {
      int c = tid + l * 256;
      int row = c >> 3, kc = (c & 7) * 8;
      int sw = row * 64 + (kc ^ ((row & 7) << 3));
      int grow = bm + row;
      bf16x8 v = {0, 0, 0, 0, 0, 0, 0, 0};
      if (grow < M) v = *(const bf16x8*)(A + (size_t)grow * K + k0 + kc);
      *(bf16x8*)&As[sw] = v;
      int gcol = bn + row;
      *(bf16x8*)&Bs[sw] = *(const bf16x8*)(Bt + (size_t)gcol * K + k0 + kc);
    }
    __syncthreads();
#pragma unroll
    for (int ks = 0; ks < 2; ++ks) {
      const int ke = ks * 32 + lkb;
      bf16x8 af[4], bfr[4];
#pragma unroll
      for (int m = 0; m < 4; ++m) {
        int row = wr + m * 16 + lrow;
        af[m] = *(const bf16x8*)&As[row * 64 + (ke ^ ((row & 7) << 3))];
      }
#pragma unroll
      for (int n = 0; n < 4; ++n) {
        int col = wc + n * 16 + lrow;
        bfr[n] = *(const bf16x8*)&Bs[col * 64 + (ke ^ ((col & 7) << 3))];
      }
#pragma unroll
      for (int m = 0; m < 4; ++m)
#pragma unroll
        for (int n = 0; n < 4; ++n)
          acc[m][n] = __builtin_amdgcn_mfma_f32_16x16x32_bf16(af[m], bfr[n], acc[m][n], 0, 0, 0);
    }
    __syncthreads();
  }

  const int colw = lane & 15, rq = (lane >> 4) * 4;
  unsigned short* Cs = shmem;
#pragma unroll
  for (int m = 0; m < 4; ++m) {
#pragma unroll
    for (int n = 0; n < 4; ++n) {
      int col = wc + n * 16 + colw;
      float bv = bias[bn + col];
#pragma unroll
      for (int r = 0; r < 4; ++r) {
        int row = wr + m * 16 + rq + r;
        Cs[row * 136 + col] = f2bf(acc[m][n][r] + bv);
      }
    }
  }
  __syncthreads();
  const int rsub = tid >> 4, c8 = (tid & 15) * 8;
#pragma unroll
  for (int i = 0; i < 8; ++i) {
    int row = i * 16 + rsub;
    int grow = bm + row;
    if (grow >= M) continue;
    uint4 v = *(const uint4*)&Cs[row * 136 + c8];
    if (MODE == 1) {
      *(uint4*)(outQ + (size_t)grow * 256 + bn + c8) = v;
    } else {
      const int proj = bn >> 8;
      int cc = (bn & 255) + c8;
      if (proj == 0) *(uint4*)(outQ + (size_t)grow * 256 + cc) = v;
      else if (proj == 1) *(uint4*)(outK + (size_t)grow * 512 + cc) = v;
      else if (proj == 2) *(uint4*)(outK + (size_t)grow * 512 + 256 + cc) = v;
      else *(uint4*)(outS + (size_t)grow * 256 + cc) = v;
    }
  }
}

// ------ MFMA [M,64]@[64,64] with fused epilogue ------
// UPD 0: fp32 A, store fp32 C. UPD 1: fp32 A (nf), fp32 gate update.
// UPD 2: bf16 A (efc, CSR order), bf16 gate update; src from srcl (slist).
template <int UPD>
__global__ __launch_bounds__(256) void gemm_gate(
    const void* __restrict__ Av, int M, const unsigned short* __restrict__ Wt,
    const unsigned short* __restrict__ P, const float* __restrict__ bgv,
    const int* __restrict__ srcl, void* __restrict__ updv) {
  __shared__ unsigned short As[128 * 64];
  __shared__ unsigned short Ws[64 * 64];
  const int tid = threadIdx.x;
  const int bm = blockIdx.x * 128;
  if (UPD == 2) {
    const unsigned short* Ab = (const unsigned short*)Av;
#pragma unroll
    for (int l = 0; l < 4; ++l) {
      int u = tid + l * 256;
      int row = u >> 3, kc = (u & 7) * 8;
      int grow = bm + row;
      bf16x8 v = {0, 0, 0, 0, 0, 0, 0, 0};
      if (grow < M) v = *(const bf16x8*)(Ab + (size_t)grow * 64 + kc);
      *(bf16x8*)&As[row * 64 + (kc ^ ((row & 7) << 3))] = v;
    }
  } else {
    const float* Af = (const float*)Av;
#pragma unroll
    for (int l = 0; l < 8; ++l) {
      int u = tid + l * 256;
      int row = u >> 4, k4 = (u & 15) << 2;
      int grow = bm + row;
      float4 v = make_float4(0.f, 0.f, 0.f, 0.f);
      if (grow < M) v = *(const float4*)(Af + (size_t)grow * 64 + k4);
      union { unsigned short h[4]; uint2 q; } pk;
      pk.h[0] = f2bf(v.x); pk.h[1] = f2bf(v.y); pk.h[2] = f2bf(v.z); pk.h[3] = f2bf(v.w);
      *(uint2*)&As[row * 64 + (k4 ^ ((row & 7) << 3))] = pk.q;
    }
  }
#pragma unroll
  for (int l = 0; l < 2; ++l) {
    int u = tid + l * 256;
    int row = u >> 3, kc = (u & 7) * 8;
    *(bf16x8*)&Ws[row * 64 + (kc ^ ((row & 7) << 3))] = *(const bf16x8*)(Wt + row * 64 + kc);
  }
  __syncthreads();
  const int wid = tid >> 6, lane = tid & 63;
  const int wr = wid * 32;
  const int lrow = lane & 15, lkb = (lane >> 4) * 8;
  f32x4 acc[2][4];
#pragma unroll
  for (int m = 0; m < 2; ++m)
#pragma unroll
    for (int n = 0; n < 4; ++n) acc[m][n] = (f32x4){0.f, 0.f, 0.f, 0.f};
#pragma unroll
  for (int ks = 0; ks < 2; ++ks) {
    const int ke = ks * 32 + lkb;
    bf16x8 af[2], wf[4];
#pragma unroll
    for (int m = 0; m < 2; ++m) {
      int row = wr + m * 16 + lrow;
      af[m] = *(const bf16x8*)&As[row * 64 + (ke ^ ((row & 7) << 3))];
    }
#pragma unroll
    for (int n = 0; n < 4; ++n) {
      int col = n * 16 + lrow;
      wf[n] = *(const bf16x8*)&Ws[col * 64 + (ke ^ ((col & 7) << 3))];
    }
#pragma unroll
    for (int m = 0; m < 2; ++m)
#pragma unroll
      for (int n = 0; n < 4; ++n)
        acc[m][n] = __builtin_amdgcn_mfma_f32_16x16x32_bf16(af[m], wf[n], acc[m][n], 0, 0, 0);
  }
  const int colw = lane & 15, rq = (lane >> 4) * 4;
#pragma unroll
  for (int m = 0; m < 2; ++m) {
#pragma unroll
    for (int r = 0; r < 4; ++r) {
      int e = bm + wr + m * 16 + rq + r;
      if (e >= M) continue;
      if (UPD == 0) {
        float* upd = (float*)updv;
#pragma unroll
        for (int n = 0; n < 4; ++n) upd[(size_t)e * 64 + n * 16 + colw] = acc[m][n][r];
      } else if (UPD == 1) {
        float* upd = (float*)updv;
        const unsigned short* Pr = P + (size_t)e * 256;
#pragma unroll
        for (int n = 0; n < 4; ++n) {
          int c = n * 16 + colw;
          float g = sigm(acc[m][n][r] + bf2f(Pr[128 + c]) + bgv[c]);
          size_t oi = (size_t)e * 64 + c;
          upd[oi] = upd[oi] * g + bf2f(Pr[c]) * (1.0f - g);
        }
      } else {
        unsigned short* upd = (unsigned short*)updv;
        int s = srcl[e];
        const unsigned short* Pr = P + (size_t)s * 256;
#pragma unroll
        for (int n = 0; n < 4; ++n) {
          int c = n * 16 + colw;
          float g = sigm(acc[m][n][r] + bf2f(Pr[192 + c]) + bgv[c]);
          size_t oi = (size_t)e * 64 + c;
          float vA = bf2f(upd[oi]);
          upd[oi] = f2bf(vA * g + bf2f(Pr[64 + c]) * (1.0f - g));
        }
      }
    }
  }
}

// ---------------- attention: 4-edge unrolled, lane = (head, 4 cols) -------
__global__ __launch_bounds__(256) void k_attn(const unsigned short* __restrict__ qo,
                                              const unsigned short* __restrict__ kv,
                                              const unsigned short* __restrict__ skipb, const int* __restrict__ off,
                                              const int* __restrict__ slist,
                                              unsigned short* __restrict__ aob,
                                              const float* __restrict__ g, const float* __restrict__ b, int N) {
  int n = blockIdx.x * 4 + (threadIdx.x >> 6);
  int lane = threadIdx.x & 63;
  if (n >= N) return;
  union { uint2 u; unsigned short h[4]; } qq;
  qq.u = *(const uint2*)(qo + (size_t)n * 256 + 4 * lane);
  float q0 = bf2f(qq.h[0]), q1 = bf2f(qq.h[1]), q2 = bf2f(qq.h[2]), q3 = bf2f(qq.h[3]);
  float m = -INFINITY, lsum = 0.f;
  float a0 = 0.f, a1 = 0.f, a2 = 0.f, a3 = 0.f;
  int i0 = off[n], i1 = off[n + 1];
  int idx = i0;
  for (; idx + 4 <= i1; idx += 4) {
    int s0 = slist[idx], s1 = slist[idx + 1], s2 = slist[idx + 2], s3 = slist[idx + 3];
    const unsigned short* kb0 = kv + (size_t)s0 * 512;
    const unsigned short* kb1 = kv + (size_t)s1 * 512;
    const unsigned short* kb2 = kv + (size_t)s2 * 512;
    const unsigned short* kb3 = kv + (size_t)s3 * 512;
    union { uint2 u; unsigned short h[4]; } kk0, vv0, kk1, vv1, kk2, vv2, kk3, vv3;
    kk0.u = *(const uint2*)(kb0 + 4 * lane); vv0.u = *(const uint2*)(kb0 + 256 + 4 * lane);
    kk1.u = *(const uint2*)(kb1 + 4 * lane); vv1.u = *(const uint2*)(kb1 + 256 + 4 * lane);
    kk2.u = *(const uint2*)(kb2 + 4 * lane); vv2.u = *(const uint2*)(kb2 + 256 + 4 * lane);
    kk3.u = *(const uint2*)(kb3 + 4 * lane); vv3.u = *(const uint2*)(kb3 + 256 + 4 * lane);
    float d0 = q0 * bf2f(kk0.h[0]) + q1 * bf2f(kk0.h[1]) + q2 * bf2f(kk0.h[2]) + q3 * bf2f(kk0.h[3]);
    float d1 = q0 * bf2f(kk1.h[0]) + q1 * bf2f(kk1.h[1]) + q2 * bf2f(kk1.h[2]) + q3 * bf2f(kk1.h[3]);
    float d2 = q0 * bf2f(kk2.h[0]) + q1 * bf2f(kk2.h[1]) + q2 * bf2f(kk2.h[2]) + q3 * bf2f(kk2.h[3]);
    float d3 = q0 * bf2f(kk3.h[0]) + q1 * bf2f(kk3.h[1]) + q2 * bf2f(kk3.h[2]) + q3 * bf2f(kk3.h[3]);
#pragma unroll
    for (int dd = 1; dd < 16; dd <<= 1) {
      d0 += __shfl_xor(d0, dd);
      d1 += __shfl_xor(d1, dd);
      d2 += __shfl_xor(d2, dd);
      d3 += __shfl_xor(d3, dd);
    }
    d0 *= 0.125f; d1 *= 0.125f; d2 *= 0.125f; d3 *= 0.125f;
    float nm, sc, p;
    nm = fmaxf(m, d0); sc = __expf(m - nm); p = __expf(d0 - nm);
    lsum = lsum * sc + p;
    a0 = fmaf(p, bf2f(vv0.h[0]), a0 * sc); a1 = fmaf(p, bf2f(vv0.h[1]), a1 * sc);
    a2 = fmaf(p, bf2f(vv0.h[2]), a2 * sc); a3 = fmaf(p, bf2f(vv0.h[3]), a3 * sc);
    m = nm;
    nm = fmaxf(m, d1); sc = __expf(m - nm); p = __expf(d1 - nm);
    lsum = lsum * sc + p;
    a0 = fmaf(p, bf2f(vv1.h[0]), a0 * sc); a1 = fmaf(p, bf2f(vv1.h[1]), a1 * sc);
    a2 = fmaf(p, bf2f(vv1.h[2]), a2 * sc); a3 = fmaf(p, bf2f(vv1.h[3]), a3 * sc);
    m = nm;
    nm = fmaxf(m, d2); sc = __expf(m - nm); p = __expf(d2 - nm);
    lsum = lsum * sc + p;
    a0 = fmaf(p, bf2f(vv2.h[0]), a0 * sc); a1 = fmaf(p, bf2f(vv2.h[1]), a1 * sc);
    a2 = fmaf(p, bf2f(vv2.h[2]), a2 * sc); a3 = fmaf(p, bf2f(vv2.h[3]), a3 * sc);
    m = nm;
    nm = fmaxf(m, d3); sc = __expf(m - nm); p = __expf(d3 - nm);
    lsum = lsum * sc + p;
    a0 = fmaf(p, bf2f(vv3.h[0]), a0 * sc); a1 = fmaf(p, bf2f(vv3.h[1]), a1 * sc);
    a2 = fmaf(p, bf2f(vv3.h[2]), a2 * sc); a3 = fmaf(p, bf2f(vv3.h[3]), a3 * sc);
    m = nm;
  }
  for (; idx + 2 <= i1; idx += 2) {
    int sA = slist[idx], sB = slist[idx + 1];
    const unsigned short* kbA = kv + (size_t)sA * 512;
    const unsigned short* kbB = kv + (size_t)sB * 512;
    union { uint2 u; unsigned short h[4]; } kkA, vvA, kkB, vvB;
    kkA.u = *(const uint2*)(kbA + 4 * lane); vvA.u = *(const uint2*)(kbA + 256 + 4 * lane);
    kkB.u = *(const uint2*)(kbB + 4 * lane); vvB.u = *(const uint2*)(kbB + 256 + 4 * lane);
    float dA = q0 * bf2f(kkA.h[0]) + q1 * bf2f(kkA.h[1]) + q2 * bf2f(kkA.h[2]) + q3 * bf2f(kkA.h[3]);
    float dB = q0 * bf2f(kkB.h[0]) + q1 * bf2f(kkB.h[1]) + q2 * bf2f(kkB.h[2]) + q3 * bf2f(kkB.h[3]);
#pragma unroll
    for (int dd = 1; dd < 16; dd <<= 1) {
      dA += __shfl_xor(dA, dd);
      dB += __shfl_xor(dB, dd);
    }
    dA *= 0.125f; dB *= 0.125f;
    float nm, sc, p;
    nm = fmaxf(m, dA); sc = __expf(m - nm); p = __expf(dA - nm);
    lsum = lsum * sc + p;
    a0 = fmaf(p, bf2f(vvA.h[0]), a0 * sc); a1 = fmaf(p, bf2f(vvA.h[1]), a1 * sc);
    a2 = fmaf(p, bf2f(vvA.h[2]), a2 * sc); a3 = fmaf(p, bf2f(vvA.h[3]), a3 * sc);
    m = nm;
    nm = fmaxf(m, dB); sc = __expf(m - nm); p = __expf(dB - nm);
    lsum = lsum * sc + p;
    a0 = fmaf(p, bf2f(vvB.h[0]), a0 * sc); a1 = fmaf(p, bf2f(vvB.h[1]), a1 * sc);
    a2 = fmaf(p, bf2f(vvB.h[2]), a2 * sc); a3 = fmaf(p, bf2f(vvB.h[3]), a3 * sc);
    m = nm;
  }
  if (idx < i1) {
    int s = slist[idx];
    const unsigned short* kb = kv + (size_t)s * 512;
    union { uint2 u; unsigned short h[4]; } kk, vv;
    kk.u = *(const uint2*)(kb + 4 * lane);
    vv.u = *(const uint2*)(kb + 256 + 4 * lane);
    float d = q0 * bf2f(kk.h[0]) + q1 * bf2f(kk.h[1]) + q2 * bf2f(kk.h[2]) + q3 * bf2f(kk.h[3]);
#pragma unroll
    for (int dd = 1; dd < 16; dd <<= 1) d += __shfl_xor(d, dd);
    d *= 0.125f;
    float nm = fmaxf(m, d);
    float sc = __expf(m - nm);
    float p = __expf(d - nm);
    lsum = lsum * sc + p;
    a0 = fmaf(p, bf2f(vv.h[0]), a0 * sc);
    a1 = fmaf(p, bf2f(vv.h[1]), a1 * sc);
    a2 = fmaf(p, bf2f(vv.h[2]), a2 * sc);
    a3 = fmaf(p, bf2f(vv.h[3]), a3 * sc);
    m = nm;
  }
  union { uint2 u; unsigned short h[4]; } sb;
  sb.u = *(const uint2*)(skipb + (size_t)n * 256 + 4 * lane);
  float inv = (lsum > 0.f) ? 1.0f / lsum : 0.f;
  float v0 = bf2f(sb.h[0]) + a0 * inv;
  float v1 = bf2f(sb.h[1]) + a1 * inv;
  float v2 = bf2f(sb.h[2]) + a2 * inv;
  float v3 = bf2f(sb.h[3]) + a3 * inv;
  float s1 = wsum(v0 + v1 + v2 + v3);
  float s2 = wsum(v0 * v0 + v1 * v1 + v2 * v2 + v3 * v3);
  float mu = s1 * (1.0f / 256.0f);
  float var = s2 * (1.0f / 256.0f) - mu * mu;
  float rs = rsqrtf(fmaxf(var, 0.0f) + LN_EPS);
  float4 g4 = *(const float4*)(g + 4 * lane);
  float4 b4 = *(const float4*)(b + 4 * lane);
  union { uint2 u; unsigned short h[4]; } ob;
  ob.h[0] = f2bf((v0 - mu) * rs * g4.x + b4.x);
  ob.h[1] = f2bf((v1 - mu) * rs * g4.y + b4.y);
  ob.h[2] = f2bf((v2 - mu) * rs * g4.z + b4.z);
  ob.h[3] = f2bf((v3 - mu) * rs * g4.w + b4.w);
  *(uint2*)(aob + (size_t)n * 256 + 4 * lane) = ob.u;
}

// ---------------- classifier pair kernel ----------------
__global__ __launch_bounds__(256) void k_clf_pair(const float* __restrict__ ABt, const float* __restrict__ ABb,
                                                  const int* __restrict__ ei, const float* __restrict__ bc1,
                                                  const float* __restrict__ Wc2, const float* __restrict__ bc2,
                                                  float* __restrict__ out, int E) {
  int e = blockIdx.x * 4 + (threadIdx.x >> 6);
  int lane = threadIdx.x & 63;
  if (e >= E) return;
  int s = ei[e], t = ei[E + e];
  float h = fmaxf(ABt[(size_t)s * 64 + lane] + ABb[(size_t)t * 64 + lane] + bc1[lane], 0.0f);
  float r = wsum(h * Wc2[lane]);
  if (lane == 0) out[e] = r + bc2[0];
}

// ============================================================================
extern "C" void kernel_launch(void* const* d_in, const int* in_sizes, int n_in,
                              void* d_out, int out_size, void* d_ws, size_t ws_size,
                              hipStream_t stream) {
  const float* x = (const float*)d_in[0];
  const float* edge_attr = (const float*)d_in[1];
  const int* ei = (const int*)d_in[2];
  const int* zk = (const int*)d_in[3];
  const float* z_table = (const float*)d_in[4];
  const float* W_node = (const float*)d_in[5];
  const float* b_node = (const float*)d_in[6];
  const float* W_edge = (const float*)d_in[7];
  const float* b_edge = (const float*)d_in[8];
  const float* cn_w1 = (const float*)d_in[9];
  const float* cn_b1 = (const float*)d_in[10];
  const float* cn_w2 = (const float*)d_in[11];
  const float* cn_b2 = (const float*)d_in[12];
  const float* cn_cw1 = (const float*)d_in[13];
  const float* cn_cb1 = (const float*)d_in[14];
  const float* cn_cw2 = (const float*)d_in[15];
  const float* cn_cb2 = (const float*)d_in[16];
  const float* ce_w1 = (const float*)d_in[17];
  const float* ce_b1 = (const float*)d_in[18];
  const float* ce_w2 = (const float*)d_in[19];
  const float* ce_b2 = (const float*)d_in[20];
  const float* ce_cw1 = (const float*)d_in[21];
  const float* ce_cb1 = (const float*)d_in[22];
  const float* ce_cw2 = (const float*)d_in[23];
  const float* ce_cb2 = (const float*)d_in[24];
  const float* ln_comb_g = (const float*)d_in[25];
  const float* ln_comb_b = (const float*)d_in[26];
  const float* Wq = (const float*)d_in[27];
  const float* bq = (const float*)d_in[28];
  const float* Wk = (const float*)d_in[29];
  const float* bk = (const float*)d_in[30];
  const float* Wv = (const float*)d_in[31];
  const float* bv = (const float*)d_in[32];
  const float* Wskip = (const float*)d_in[33];
  const float* bskip = (const float*)d_in[34];
  const float* ln_tc_g = (const float*)d_in[35];
  const float* ln_tc_b = (const float*)d_in[36];
  const float* Wpn = (const float*)d_in[37];
  const float* bpn = (const float*)d_in[38];
  const float* Wpe = (const float*)d_in[39];
  const float* bpe = (const float*)d_in[40];
  const float* Wg = (const float*)d_in[41];
  const float* bg = (const float*)d_in[42];
  const float* Wc1 = (const float*)d_in[43];
  const float* bc1 = (const float*)d_in[44];
  const float* Wc2 = (const float*)d_in[45];
  const float* bc2 = (const float*)d_in[46];
  float* out = (float*)d_out;

  const int N = in_sizes[0] / 6;   // 50000
  const int E = in_sizes[2] / 2;   // 100000
  const int E2 = 2 * E;

  // ---- workspace carve (~216 MB peak) ----
  char* p = (char*)d_ws;
  auto carve = [&](size_t bytes) -> void* {
    void* r = (void*)p;
    p += (bytes + 255) & ~(size_t)255;
    return r;
  };
  unsigned short* qo = (unsigned short*)carve((size_t)N * 256 * 2);    // Q bf16
  unsigned short* skipb = (unsigned short*)carve((size_t)N * 256 * 2); // skip bf16 -> P bf16 (exact alias)
  unsigned short* kvb = (unsigned short*)carve((size_t)N * 512 * 2);   // K|V bf16
  unsigned short* aob = (unsigned short*)carve((size_t)N * 256 * 2);   // attn out bf16 -> AB f32
  unsigned short* efb = (unsigned short*)carve((size_t)E2 * 64 * 2);   // edge feats bf16 (edge-id order, pre-loop)
  unsigned short* efc = (unsigned short*)carve((size_t)E2 * 64 * 2);   // edge feats bf16 (CSR order)
  float* nf = (float*)carve((size_t)N * 64 * 4);
  unsigned short* comb = (unsigned short*)carve((size_t)N * 128 * 2);
  unsigned short* W1t = (unsigned short*)carve((size_t)3 * 1024 * 128 * 2);
  float* bias1 = (float*)carve((size_t)3 * 1024 * 4);
  unsigned short* B2t = (unsigned short*)carve((size_t)3 * 256 * 256 * 2);
  float* bias2 = (float*)carve((size_t)3 * 256 * 4);
  unsigned short* Wg1t = (unsigned short*)carve((size_t)3 * 64 * 64 * 2);
  unsigned short* Wc1t = (unsigned short*)carve((size_t)2 * 64 * 64 * 2);
  int* cnt = (int*)carve((size_t)N * 4);
  int* cur = (int*)carve((size_t)N * 4);
  int* off = (int*)carve((size_t)(N + 1) * 4);
  int* pinv = (int*)carve((size_t)E2 * 4);
  int* slist = (int*)carve((size_t)E2 * 4);
  int* bsum = (int*)carve((size_t)256 * 4);
  int* boff = (int*)carve((size_t)256 * 4);
  float* pm = (float*)carve((size_t)PBLK * 64 * 4);
  float* ps = (float*)carve((size_t)PBLK * 64 * 4);
  float* cwv = (float*)carve(64 * 4);
  float* spmax = (float*)carve((size_t)E2 * 4);
  float* spmean = (float*)carve((size_t)E2 * 4);
  float* sconv = (float*)carve((size_t)E2 * 4);
  size_t need = (size_t)(p - (char*)d_ws);

  unsigned short* Pb = skipb;       // P bf16 aliases skipb (dead after k_attn)
  float* ABt = (float*)aob;
  float* ABb = (float*)aob + (size_t)N * 64;

  auto cdiv = [](int a, int b) { return (a + b - 1) / b; };

  if (ws_size < need) {
    k_sentinel<<<cdiv(E, 256), 256, 0, stream>>>(out, E);
    return;
  }

  // ---- CSR by dst (multi-block scan) ----
  k_zero2<<<cdiv(N, 256), 256, 0, stream>>>(cnt, cur, N);
  k_hist<<<cdiv(E2, 256), 256, 0, stream>>>(ei, cnt, E);
  const int nblk = cdiv(N, 1024);
  k_scan1<<<nblk, 256, 0, stream>>>(cnt, off, bsum, N);
  k_scan2<<<1, 64, 0, stream>>>(bsum, boff, off, N, nblk);
  k_scan3<<<cdiv(N, 256), 256, 0, stream>>>(off, boff, N);
  k_scatter<<<cdiv(E2, 256), 256, 0, stream>>>(ei, off, cur, pinv, slist, E);

  // ---- pack weights (bf16 transposed) ----
  const int PACK = 3 * 1024 * 128 + 3 * 1024 + 3 * 256 * 256 + 3 * 256 + 3 * 64 * 64 + 2 * 64 * 64;
  k_packW<<<cdiv(PACK, 256), 256, 0, stream>>>(Wq, Wk, Wv, Wskip, bq, bk, bv, bskip,
                                               Wpn, Wpe, bpn, bpe, Wg, Wc1,
                                               W1t, bias1, B2t, bias2, Wg1t, Wc1t);

  // ---- embeddings ----
  k_node_embed<<<cdiv(N, 4), 256, 0, stream>>>(x, zk, z_table, W_node, b_node, nf, N);
  k_edge_embed<<<cdiv(E2, 4), 256, 0, stream>>>(x, edge_attr, ei, W_edge, b_edge, efb, E);

  // ---- CBAM: nodes (fp32, in place) then edges (bf16, scatter to CSR) ----
  k_pool_partial<float><<<PBLK, 256, 0, stream>>>(nf, N, pm, ps);
  k_pool_final<<<1, 256, 0, stream>>>(pm, ps, N, PBLK, cn_w1, cn_b1, cn_w2, cn_b2, cwv);
  k_chan_sp<float><<<cdiv(N, 16), 256, 0, stream>>>(nf, N, cwv, spmax, spmean);
  k_conv<<<cdiv(N, 256), 256, 0, stream>>>(spmax, spmean, N, cn_cw1, cn_cb1, cn_cw2, cn_cb2, sconv);
  k_row_scale<<<cdiv(N * 16, 256), 256, 0, stream>>>(nf, N, sconv);

  k_pool_partial<unsigned short><<<PBLK, 256, 0, stream>>>(efb, E2, pm, ps);
  k_pool_final<<<1, 256, 0, stream>>>(pm, ps, E2, PBLK, ce_w1, ce_b1, ce_w2, ce_b2, cwv);
  k_chan_sp<unsigned short><<<cdiv(E2, 16), 256, 0, stream>>>(efb, E2, cwv, spmax, spmean);
  k_conv<<<cdiv(E2, 256), 256, 0, stream>>>(spmax, spmean, E2, ce_cw1, ce_cb1, ce_cw2, ce_cb2, sconv);
  k_row_scale_perm<<<cdiv(E2 * 16, 256), 256, 0, stream>>>(efb, E2, sconv, pinv, efc);

  // ---- T = 3 message-passing iterations ----
  const int gqkvs = cdiv(N, 128) * 8;  // 1D, XCD-swizzled in-kernel
  dim3 gp(cdiv(N, 128), 2);
  for (int i = 0; i < 3; ++i) {
    k_aggcomb<<<cdiv(N, 4), 256, 0, stream>>>(efc, nf, off, comb,
                                              ln_comb_g + (size_t)i * 128, ln_comb_b + (size_t)i * 128, N);
    gemm_mfma<0><<<gqkvs, 256, 0, stream>>>(comb, N, 128, W1t + (size_t)i * 131072,
                                            bias1 + (size_t)i * 1024, qo, kvb, skipb);
    k_attn<<<cdiv(N, 4), 256, 0, stream>>>(qo, kvb, skipb, off, slist, aob,
                                           ln_tc_g + (size_t)i * 256, ln_tc_b + (size_t)i * 256, N);
    gemm_mfma<1><<<gp, 256, 0, stream>>>(aob, N, 256, B2t + (size_t)i * 65536,
                                         bias2 + (size_t)i * 256, Pb, nullptr, nullptr);
    gemm_gate<1><<<cdiv(N, 128), 256, 0, stream>>>(nf, N, Wg1t + (size_t)i * 4096, Pb,
                                                   bg + (size_t)i * 64, nullptr, nf);
    gemm_gate<2><<<cdiv(E2, 128), 256, 0, stream>>>(efc, E2, Wg1t + (size_t)i * 4096, Pb,
                                                    bg + (size_t)i * 64, slist, efc);
  }

  // ---- classifier ----
  gemm_gate<0><<<cdiv(N, 128), 256, 0, stream>>>(nf, N, Wc1t, nullptr, nullptr, nullptr, ABt);
  gemm_gate<0><<<cdiv(N, 128), 256, 0, stream>>>(nf, N, Wc1t + 4096, nullptr, nullptr, nullptr, ABb);
  k_clf_pair<<<cdiv(E, 4), 256, 0, stream>>>(ABt, ABb, ei, bc1, Wc2, bc2, out, E);
  (void)out_size;
  (void)n_in;
}

// Round 13
// 697.871 us; speedup vs baseline: 1.5195x; 1.0242x over previous
//
#include <hip/hip_runtime.h>

// ============================================================================
// New_LinkNet GNN forward — MFMA bf16 GEMMs + fused gate updates.
// Round-13 changes vs round 12 (715us; attn online-max serial chain = VALU
// bound; P node-half round-trips HBM + separate gate<1> kernel):
//  - k_attn: running-max removed (exp(d) direct — mathematically identical,
//    logits bounded far below fp32 exp range). Accumulations now independent.
//  - B2 repacked [npj|vn|pe|ve]; gemm_p (y=0): P-node GEMM + Sn=nf@Wg1 +
//    fused node gate update (node P never hits HBM); (y=1): writes Pe[N,128].
//    gemm_gate<1> eliminated; gate<2> reads Pe stride 128.
// ============================================================================

#define LN_EPS 1e-5f
#define PBLK 512

typedef __attribute__((ext_vector_type(8))) short bf16x8;
typedef __attribute__((ext_vector_type(4))) float f32x4;

static __device__ __forceinline__ float wsum(float v) {
#pragma unroll
  for (int d = 32; d > 0; d >>= 1) v += __shfl_xor(v, d);
  return v;
}
static __device__ __forceinline__ float sigm(float x) { return 1.0f / (1.0f + __expf(-x)); }
static __device__ __forceinline__ unsigned short f2bf(float f) {
  unsigned int u = __float_as_uint(f);
  u += 0x7FFFu + ((u >> 16) & 1u);
  return (unsigned short)(u >> 16);
}
static __device__ __forceinline__ float bf2f(unsigned short b) {
  return __uint_as_float(((unsigned int)b) << 16);
}
static __device__ __forceinline__ float4 ld4v(const float* p) { return *(const float4*)p; }
static __device__ __forceinline__ float4 ld4v(const unsigned short* p) {
  union { uint2 u; unsigned short h[4]; } t;
  t.u = *(const uint2*)p;
  return make_float4(bf2f(t.h[0]), bf2f(t.h[1]), bf2f(t.h[2]), bf2f(t.h[3]));
}
static __device__ __forceinline__ void st4v(float* p, float4 v) { *(float4*)p = v; }
static __device__ __forceinline__ void st4v(unsigned short* p, float4 v) {
  union { uint2 u; unsigned short h[4]; } t;
  t.h[0] = f2bf(v.x); t.h[1] = f2bf(v.y); t.h[2] = f2bf(v.z); t.h[3] = f2bf(v.w);
  *(uint2*)p = t.u;
}

// ---------------- util ----------------
__global__ __launch_bounds__(256) void k_zero2(int* __restrict__ a, int* __restrict__ b, int n) {
  int i = blockIdx.x * 256 + threadIdx.x;
  if (i < n) { a[i] = 0; b[i] = 0; }
}

__global__ __launch_bounds__(256) void k_sentinel(float* __restrict__ out, int n) {
  int i = blockIdx.x * 256 + threadIdx.x;
  if (i < n) out[i] = 1.0e6f;
}

// ---------------- CSR build (by dst) ----------------
__global__ __launch_bounds__(256) void k_hist(const int* __restrict__ ei, int* __restrict__ cnt, int E) {
  int e = blockIdx.x * 256 + threadIdx.x;
  if (e >= 2 * E) return;
  int d = (e < E) ? ei[E + e] : ei[e - E];
  atomicAdd(&cnt[d], 1);
}

__global__ __launch_bounds__(256) void k_scan1(const int* __restrict__ cnt, int* __restrict__ off,
                                               int* __restrict__ bsum, int n) {
  const int t = threadIdx.x;
  const int lane = t & 63, w = t >> 6;
  const int i0 = blockIdx.x * 1024 + t * 4;
  int v0 = (i0 + 0 < n) ? cnt[i0 + 0] : 0;
  int v1 = (i0 + 1 < n) ? cnt[i0 + 1] : 0;
  int v2 = (i0 + 2 < n) ? cnt[i0 + 2] : 0;
  int v3 = (i0 + 3 < n) ? cnt[i0 + 3] : 0;
  int s = v0 + v1 + v2 + v3;
  int sc = s;
#pragma unroll
  for (int d = 1; d < 64; d <<= 1) {
    int tv = __shfl_up(sc, d);
    if (lane >= d) sc += tv;
  }
  __shared__ int wsums[4];
  if (lane == 63) wsums[w] = sc;
  __syncthreads();
  int wbase = 0;
#pragma unroll
  for (int k = 0; k < 4; ++k)
    if (k < w) wbase += wsums[k];
  int run = wbase + sc - s;
  if (i0 + 0 < n) off[i0 + 0] = run; run += v0;
  if (i0 + 1 < n) off[i0 + 1] = run; run += v1;
  if (i0 + 2 < n) off[i0 + 2] = run; run += v2;
  if (i0 + 3 < n) off[i0 + 3] = run;
  if (t == 255) bsum[blockIdx.x] = wbase + sc;
}

__global__ __launch_bounds__(64) void k_scan2(const int* __restrict__ bsum, int* __restrict__ boff,
                                              int* __restrict__ off, int n, int nblk) {
  const int lane = threadIdx.x;
  int carry = 0;
  for (int base = 0; base < nblk; base += 64) {
    int i = base + lane;
    int v = (i < nblk) ? bsum[i] : 0;
    int sc = v;
#pragma unroll
    for (int d = 1; d < 64; d <<= 1) {
      int tv = __shfl_up(sc, d);
      if (lane >= d) sc += tv;
    }
    if (i < nblk) boff[i] = carry + sc - v;
    carry += __shfl(sc, 63);
  }
  if (lane == 0) off[n] = carry;
}

__global__ __launch_bounds__(256) void k_scan3(int* __restrict__ off, const int* __restrict__ boff, int n) {
  int i = blockIdx.x * 256 + threadIdx.x;
  if (i < n) off[i] += boff[i >> 10];
}

__global__ __launch_bounds__(256) void k_scatter(const int* __restrict__ ei, const int* __restrict__ off,
                                                 int* __restrict__ cur, int* __restrict__ pinv,
                                                 int* __restrict__ slist, int E) {
  int e = blockIdx.x * 256 + threadIdx.x;
  if (e >= 2 * E) return;
  int d = (e < E) ? ei[E + e] : ei[e - E];
  int pos = atomicAdd(&cur[d], 1);
  int base = off[d] + pos;
  pinv[e] = base;
  slist[base] = ei[e];
}

// ---------------- pack all transposed bf16 weights ----------------
// B2 col order: [npj | vn | pe | ve] (node halves together for gemm_p)
__global__ __launch_bounds__(256) void k_packW(
    const float* __restrict__ Wq, const float* __restrict__ Wk, const float* __restrict__ Wv,
    const float* __restrict__ Ws, const float* __restrict__ bq, const float* __restrict__ bk,
    const float* __restrict__ bv, const float* __restrict__ bs,
    const float* __restrict__ Wpn, const float* __restrict__ Wpe,
    const float* __restrict__ bpn, const float* __restrict__ bpe,
    const float* __restrict__ Wg, const float* __restrict__ Wc1,
    unsigned short* __restrict__ W1t, float* __restrict__ bias1,
    unsigned short* __restrict__ B2t, float* __restrict__ bias2,
    unsigned short* __restrict__ Wg1t, unsigned short* __restrict__ Wc1t) {
  const int S1 = 3 * 1024 * 128, S2 = 3 * 1024, S3 = 3 * 256 * 256, S4 = 3 * 256;
  const int S5 = 3 * 64 * 64, S6 = 2 * 64 * 64;
  int idx = blockIdx.x * 256 + threadIdx.x;
  if (idx < S1) {
    int i = idx / 131072, r = idx % 131072;
    int col = r >> 7, k = r & 127;
    int m = col >> 8, cc = col & 255;
    const float* W = (m == 0) ? Wq : (m == 1) ? Wk : (m == 2) ? Wv : Ws;
    W1t[idx] = f2bf(W[i * 32768 + k * 256 + cc]);
  } else if (idx < S1 + S2) {
    int j = idx - S1;
    int i = j >> 10, col = j & 1023;
    int m = col >> 8, cc = col & 255;
    const float* bsrc = (m == 0) ? bq : (m == 1) ? bk : (m == 2) ? bv : bs;
    bias1[j] = bsrc[i * 256 + cc];
  } else if (idx < S1 + S2 + S3) {
    int j = idx - S1 - S2;
    int i = j / 65536, r = j % 65536;
    int col = r >> 8, k = r & 255;
    int half = col >> 6, cc = col & 63;
    float v;
    if (half == 0) v = Wpn[i * 16384 + k * 64 + cc];
    else if (half == 2) v = Wpe[i * 16384 + k * 64 + cc];
    else {
      const float* Wsrc = (half == 1) ? Wpn : Wpe;
      float acc = 0.f;
      for (int jj = 0; jj < 64; ++jj)
        acc = fmaf(Wsrc[i * 16384 + k * 64 + jj], Wg[i * 8192 + (64 + jj) * 64 + cc], acc);
      v = acc;
    }
    B2t[j] = f2bf(v);
  } else if (idx < S1 + S2 + S3 + S4) {
    int j = idx - S1 - S2 - S3;
    int i = j >> 8, col = j & 255;
    int half = col >> 6, cc = col & 63;
    float v;
    if (half == 0) v = bpn[i * 64 + cc];
    else if (half == 2) v = bpe[i * 64 + cc];
    else {
      const float* bsrc = (half == 1) ? bpn : bpe;
      float acc = 0.f;
      for (int jj = 0; jj < 64; ++jj)
        acc = fmaf(bsrc[i * 64 + jj], Wg[i * 8192 + (64 + jj) * 64 + cc], acc);
      v = acc;
    }
    bias2[j] = v;
  } else if (idx < S1 + S2 + S3 + S4 + S5) {
    int j = idx - S1 - S2 - S3 - S4;
    int i = j / 4096, r = j % 4096;
    int col = r >> 6, k = r & 63;
    Wg1t[j] = f2bf(Wg[i * 8192 + k * 64 + col]);
  } else if (idx < S1 + S2 + S3 + S4 + S5 + S6) {
    int j = idx - S1 - S2 - S3 - S4 - S5;
    int h = j / 4096, r = j % 4096;
    int col = r >> 6, k = r & 63;
    Wc1t[j] = f2bf(Wc1[(h * 64 + k) * 64 + col]);
  }
}

// ---------------- embeddings ----------------
__global__ __launch_bounds__(256) void k_node_embed(
    const float* __restrict__ x, const int* __restrict__ zk, const float* __restrict__ zt,
    const float* __restrict__ Wn, const float* __restrict__ bn, float* __restrict__ nf, int N) {
  int n = blockIdx.x * 4 + (threadIdx.x >> 6);
  int lane = threadIdx.x & 63;
  if (n >= N) return;
  const float* xr = x + (size_t)n * 6;
  float acc = bn[lane];
#pragma unroll
  for (int d = 0; d < 6; ++d) acc = fmaf(xr[d], Wn[d * 64 + lane], acc);
  int zi = __float2int_rn(xr[2]);
  int idx = 0;
#pragma unroll
  for (int t = 5; t >= 0; --t)
    if (zi == zk[t]) idx = t;
  nf[(size_t)n * 64 + lane] = fmaxf(acc, 0.0f) + zt[idx * 64 + lane];
}

__global__ __launch_bounds__(256) void k_edge_embed(
    const float* __restrict__ x, const float* __restrict__ ea, const int* __restrict__ ei,
    const float* __restrict__ We, const float* __restrict__ be,
    unsigned short* __restrict__ ef, int E) {
  int e = blockIdx.x * 4 + (threadIdx.x >> 6);
  int lane = threadIdx.x & 63;
  if (e >= 2 * E) return;
  int e0 = (e < E) ? e : e - E;
  int s = ei[e];
  int d = (e < E) ? ei[E + e] : ei[e - E];
  const float* ar = ea + (size_t)e0 * 4;
  const float* xs = x + (size_t)s * 6;
  const float* xd = x + (size_t)d * 6;
  float in[7];
  in[0] = ar[0]; in[1] = ar[1]; in[2] = ar[2]; in[3] = ar[3];
  in[4] = xs[0] - xd[0]; in[5] = xs[1] - xd[1]; in[6] = xs[2] - xd[2];
  float acc = be[lane];
#pragma unroll
  for (int dd = 0; dd < 7; ++dd) acc = fmaf(in[dd], We[dd * 64 + lane], acc);
  ef[(size_t)e * 64 + lane] = f2bf(fmaxf(acc, 0.0f));
}

// ---------------- CBAM (vectorized, fp32 or bf16 buffer) ----------------
template <typename T>
__global__ __launch_bounds__(256) void k_pool_partial(const T* __restrict__ buf, int n,
                                                      float* __restrict__ pm, float* __restrict__ ps) {
  const int w = threadIdx.x >> 6, l = threadIdx.x & 63;
  const int rsub = l >> 4, c4 = (l & 15) << 2;
  float4 mx = make_float4(-INFINITY, -INFINITY, -INFINITY, -INFINITY);
  float4 sm = make_float4(0.f, 0.f, 0.f, 0.f);
  for (int r = blockIdx.x * 16 + w * 4 + rsub; r < n; r += gridDim.x * 16) {
    float4 v = ld4v(buf + (size_t)r * 64 + c4);
    mx.x = fmaxf(mx.x, v.x); mx.y = fmaxf(mx.y, v.y);
    mx.z = fmaxf(mx.z, v.z); mx.w = fmaxf(mx.w, v.w);
    sm.x += v.x; sm.y += v.y; sm.z += v.z; sm.w += v.w;
  }
#pragma unroll
  for (int d = 16; d < 64; d <<= 1) {
    mx.x = fmaxf(mx.x, __shfl_xor(mx.x, d)); mx.y = fmaxf(mx.y, __shfl_xor(mx.y, d));
    mx.z = fmaxf(mx.z, __shfl_xor(mx.z, d)); mx.w = fmaxf(mx.w, __shfl_xor(mx.w, d));
    sm.x += __shfl_xor(sm.x, d); sm.y += __shfl_xor(sm.y, d);
    sm.z += __shfl_xor(sm.z, d); sm.w += __shfl_xor(sm.w, d);
  }
  __shared__ float smx[4][64], ssm[4][64];
  if (l < 16) {
    *(float4*)&smx[w][c4] = mx;
    *(float4*)&ssm[w][c4] = sm;
  }
  __syncthreads();
  if (threadIdx.x < 64) {
    int t = threadIdx.x;
    float m2 = fmaxf(fmaxf(smx[0][t], smx[1][t]), fmaxf(smx[2][t], smx[3][t]));
    float s2 = ssm[0][t] + ssm[1][t] + ssm[2][t] + ssm[3][t];
    pm[blockIdx.x * 64 + t] = m2;
    ps[blockIdx.x * 64 + t] = s2;
  }
}

__global__ __launch_bounds__(256) void k_pool_final(
    const float* __restrict__ pm, const float* __restrict__ ps, int n, int nblk,
    const float* __restrict__ w1, const float* __restrict__ b1,
    const float* __restrict__ w2, const float* __restrict__ b2, float* __restrict__ cw) {
  __shared__ float redm[4][64], reds[4][64];
  __shared__ float cat[128];
  __shared__ float hid[4];
  int t = threadIdx.x;
  int g = t >> 6, col = t & 63;
  float mx = -INFINITY, sm = 0.0f;
  for (int p = g; p < nblk; p += 4) {
    mx = fmaxf(mx, pm[p * 64 + col]);
    sm += ps[p * 64 + col];
  }
  redm[g][col] = mx;
  reds[g][col] = sm;
  __syncthreads();
  if (t < 64) {
    float m2 = fmaxf(fmaxf(redm[0][t], redm[1][t]), fmaxf(redm[2][t], redm[3][t]));
    float s2 = reds[0][t] + reds[1][t] + reds[2][t] + reds[3][t];
    cat[t] = m2;
    cat[64 + t] = s2 / (float)n;
  }
  __syncthreads();
  if (t < 4) {
    float a = b1[t];
    for (int k = 0; k < 128; ++k) a = fmaf(cat[k], w1[k * 4 + t], a);
    hid[t] = fmaxf(a, 0.0f);
  }
  __syncthreads();
  if (t < 64) {
    float a = b2[t];
#pragma unroll
    for (int h = 0; h < 4; ++h) a = fmaf(hid[h], w2[h * 64 + t], a);
    cw[t] = sigm(a);
  }
}

template <typename T>
__global__ __launch_bounds__(256) void k_chan_sp(T* __restrict__ buf, int n,
                                                 const float* __restrict__ cw,
                                                 float* __restrict__ spmax, float* __restrict__ spmean) {
  const int w = threadIdx.x >> 6, l = threadIdx.x & 63;
  const int rsub = l >> 4, c4 = (l & 15) << 2;
  int r = blockIdx.x * 16 + w * 4 + rsub;
  if (r >= n) return;
  float4 cwv = *(const float4*)(cw + c4);
  float4 v = ld4v(buf + (size_t)r * 64 + c4);
  v.x *= cwv.x; v.y *= cwv.y; v.z *= cwv.z; v.w *= cwv.w;
  st4v(buf + (size_t)r * 64 + c4, v);
  float mx = fmaxf(fmaxf(v.x, v.y), fmaxf(v.z, v.w));
  float sm = v.x + v.y + v.z + v.w;
#pragma unroll
  for (int d = 1; d < 16; d <<= 1) {
    mx = fmaxf(mx, __shfl_xor(mx, d));
    sm += __shfl_xor(sm, d);
  }
  if ((l & 15) == 0) {
    spmax[r] = mx;
    spmean[r] = sm * (1.0f / 64.0f);
  }
}

__global__ __launch_bounds__(256) void k_conv(const float* __restrict__ spmax, const float* __restrict__ spmean,
                                              int n, const float* __restrict__ w1, const float* __restrict__ b1,
                                              const float* __restrict__ w2, const float* __restrict__ b2,
                                              float* __restrict__ s) {
  __shared__ float tl[258];
  int base = blockIdx.x * 256;
  for (int q = threadIdx.x; q < 258; q += 256) {
    int p = base - 1 + q;
    float t = 0.0f;
    if (p >= 0 && p < n) {
      float a = b1[0];
#pragma unroll
      for (int h = 0; h < 5; ++h) {
        int pp = p + h - 2;
        if (pp >= 0 && pp < n) a += spmax[pp] * w1[h] + spmean[pp] * w1[5 + h];
      }
      t = fmaxf(a, 0.0f);
    }
    tl[q] = t;
  }
  __syncthreads();
  int o = base + threadIdx.x;
  if (o < n) {
    float a = b2[0] + tl[threadIdx.x] * w2[0] + tl[threadIdx.x + 1] * w2[1] + tl[threadIdx.x + 2] * w2[2];
    s[o] = sigm(a);
  }
}

__global__ __launch_bounds__(256) void k_row_scale(float* __restrict__ buf, int n, const float* __restrict__ s) {
  int i4 = blockIdx.x * 256 + threadIdx.x;
  if (i4 >= n * 16) return;
  int r = i4 >> 4;
  float sc = s[r];
  float4 v = ld4v(buf + (size_t)i4 * 4);
  v.x *= sc; v.y *= sc; v.z *= sc; v.w *= sc;
  st4v(buf + (size_t)i4 * 4, v);
}

__global__ __launch_bounds__(256) void k_row_scale_perm(const unsigned short* __restrict__ src, int n,
                                                        const float* __restrict__ s,
                                                        const int* __restrict__ pinv,
                                                        unsigned short* __restrict__ dst) {
  int i4 = blockIdx.x * 256 + threadIdx.x;
  if (i4 >= n * 16) return;
  int r = i4 >> 4, c4 = (i4 & 15) * 4;
  float sc = s[r];
  float4 v = ld4v(src + (size_t)r * 64 + c4);
  v.x *= sc; v.y *= sc; v.z *= sc; v.w *= sc;
  st4v(dst + (size_t)pinv[r] * 64 + c4, v);
}

// ---------------- agg + concat-LN (CSR-ordered bf16 ef, streaming) --------
__global__ __launch_bounds__(256) void k_aggcomb(const unsigned short* __restrict__ efc,
                                                 const float* __restrict__ nf,
                                                 const int* __restrict__ off,
                                                 unsigned short* __restrict__ comb, const float* __restrict__ g,
                                                 const float* __restrict__ b, int N) {
  int n = blockIdx.x * 4 + (threadIdx.x >> 6);
  int lane = threadIdx.x & 63;
  if (n >= N) return;
  float agg = 0.0f;
  int i0 = off[n], i1 = off[n + 1];
  for (int idx = i0; idx < i1; ++idx) agg += bf2f(efc[(size_t)idx * 64 + lane]);
  float y0 = nf[(size_t)n * 64 + lane];
  float y1 = agg - y0;
  float s1 = wsum(y0 + y1);
  float s2 = wsum(y0 * y0 + y1 * y1);
  float mu = s1 * (1.0f / 128.0f);
  float var = s2 * (1.0f / 128.0f) - mu * mu;
  float rs = rsqrtf(fmaxf(var, 0.0f) + LN_EPS);
  comb[(size_t)n * 128 + lane] = f2bf((y0 - mu) * rs * g[lane] + b[lane]);
  comb[(size_t)n * 128 + 64 + lane] = f2bf((y1 - mu) * rs * g[64 + lane] + b[64 + lane]);
}

// ---------------- MFMA GEMM: QKVS (MODE0-only, XCD-swizzled) --------------
__global__ __launch_bounds__(256) void gemm_mfma(
    const unsigned short* __restrict__ A, int M, int K,
    const unsigned short* __restrict__ Bt, const float* __restrict__ bias,
    unsigned short* __restrict__ outQ, unsigned short* __restrict__ outK,
    unsigned short* __restrict__ outS) {
  __shared__ unsigned short shmem[128 * 136];
  unsigned short* As = shmem;
  unsigned short* Bs = shmem + 128 * 64;
  const int tid = threadIdx.x;
  int cpx = gridDim.x >> 3;
  int wgid = (blockIdx.x & 7) * cpx + (blockIdx.x >> 3);
  int bm = (wgid >> 3) * 128;
  int bn = (wgid & 7) * 128;
  const int wid = tid >> 6, lane = tid & 63;
  const int wr = (wid >> 1) * 64, wc = (wid & 1) * 64;
  const int lrow = lane & 15, lkb = (lane >> 4) * 8;
  f32x4 acc[4][4];
#pragma unroll
  for (int m = 0; m < 4; ++m)
#pragma unroll
    for (int n = 0; n < 4; ++n) acc[m][n] = (f32x4){0.f, 0.f, 0.f, 0.f};

  for (int k0 = 0; k0 < K; k0 += 64) {
#pragma unroll
    for (int l = 0; l < 4; ++l) {
      int c = tid + l * 256;
      int row = c >> 3, kc = (c & 7) * 8;
      int sw = row * 64 + (kc ^ ((row & 7) << 3));
      int grow = bm + row;
      bf16x8 v = {0, 0, 0, 0, 0, 0, 0, 0};
      if (grow < M) v = *(const bf16x8*)(A + (size_t)grow * K + k0 + kc);
      *(bf16x8*)&As[sw] = v;
      int gcol = bn + row;
      *(bf16x8*)&Bs[sw] = *(const bf16x8*)(Bt + (size_t)gcol * K + k0 + kc);
    }
    __syncthreads();
#pragma unroll
    for (int ks = 0; ks < 2; ++ks) {
      const int ke = ks * 32 + lkb;
      bf16x8 af[4], bfr[4];
#pragma unroll
      for (int m = 0; m < 4; ++m) {
        int row = wr + m * 16 + lrow;
        af[m] = *(const bf16x8*)&As[row * 64 + (ke ^ ((row & 7) << 3))];
      }
#pragma unroll
      for (int n = 0; n < 4; ++n) {
        int col = wc + n * 16 + lrow;
        bfr[n] = *(const bf16x8*)&Bs[col * 64 + (ke ^ ((col & 7) << 3))];
      }
#pragma unroll
      for (int m = 0; m < 4; ++m)
#pragma unroll
        for (int n = 0; n < 4; ++n)
          acc[m][n] = __builtin_amdgcn_mfma_f32_16x16x32_bf16(af[m], bfr[n], acc[m][n], 0, 0, 0);
    }
    __syncthreads();
  }

  const int colw = lane & 15, rq = (lane >> 4) * 4;
  unsigned short* Cs = shmem;
#pragma unroll
  for (int m = 0; m < 4; ++m) {
#pragma unroll
    for (int n = 0; n < 4; ++n) {
      int col = wc + n * 16 + colw;
      float bv = bias[bn + col];
#pragma unroll
      for (int r = 0; r < 4; ++r) {
        int row = wr + m * 16 + rq + r;
        Cs[row * 136 + col] = f2bf(acc[m][n][r] + bv);
      }
    }
  }
  __syncthreads();
  const int rsub = tid >> 4, c8 = (tid & 15) * 8;
#pragma unroll
  for (int i = 0; i < 8; ++i) {
    int row = i * 16 + rsub;
    int grow = bm + row;
    if (grow >= M) continue;
    uint4 v = *(const uint4*)&Cs[row * 136 + c8];
    const int proj = bn >> 8;
    int cc = (bn & 255) + c8;
    if (proj == 0) *(uint4*)(outQ + (size_t)grow * 256 + cc) = v;
    else if (proj == 1) *(uint4*)(outK + (size_t)grow * 512 + cc) = v;
    else if (proj == 2) *(uint4*)(outK + (size_t)grow * 512 + 256 + cc) = v;
    else *(uint4*)(outS + (size_t)grow * 256 + cc) = v;
  }
}

// ---------- fused P GEMM: y=0 node path (P-node + Sn + gate update),
//            y=1 edge path (writes Pe[N,128]) --------------------------------
__global__ __launch_bounds__(256) void gemm_p(
    const unsigned short* __restrict__ aob, float* __restrict__ nf, int N,
    const unsigned short* __restrict__ B2t, const float* __restrict__ bias2,
    const unsigned short* __restrict__ Wg1t, const float* __restrict__ bgv,
    unsigned short* __restrict__ Pe) {
  __shared__ unsigned short shmem[128 * 136];
  unsigned short* As = shmem;
  unsigned short* Bs = shmem + 128 * 64;
  const int tid = threadIdx.x;
  const int bm = blockIdx.x * 128;
  const bool nodeblk = (blockIdx.y == 0);
  const int wid = tid >> 6, lane = tid & 63;
  const int lrow = lane & 15, lkb = (lane >> 4) * 8;

  f32x4 accS[2][4];
  if (nodeblk) {
    // Phase A: Sn = nf @ Wg1 (gate-style: wave wid owns rows wid*32..+32)
#pragma unroll
    for (int l = 0; l < 8; ++l) {
      int u = tid + l * 256;
      int row = u >> 4, k4 = (u & 15) << 2;
      int grow = bm + row;
      float4 v = make_float4(0.f, 0.f, 0.f, 0.f);
      if (grow < N) v = *(const float4*)(nf + (size_t)grow * 64 + k4);
      union { unsigned short h[4]; uint2 q; } pk;
      pk.h[0] = f2bf(v.x); pk.h[1] = f2bf(v.y); pk.h[2] = f2bf(v.z); pk.h[3] = f2bf(v.w);
      *(uint2*)&As[row * 64 + (k4 ^ ((row & 7) << 3))] = pk.q;
    }
#pragma unroll
    for (int l = 0; l < 2; ++l) {
      int u = tid + l * 256;
      int row = u >> 3, kc = (u & 7) * 8;
      *(bf16x8*)&Bs[row * 64 + (kc ^ ((row & 7) << 3))] = *(const bf16x8*)(Wg1t + row * 64 + kc);
    }
    __syncthreads();
    const int wrS = wid * 32;
#pragma unroll
    for (int m = 0; m < 2; ++m)
#pragma unroll
      for (int n = 0; n < 4; ++n) accS[m][n] = (f32x4){0.f, 0.f, 0.f, 0.f};
#pragma unroll
    for (int ks = 0; ks < 2; ++ks) {
      const int ke = ks * 32 + lkb;
      bf16x8 af[2], wf[4];
#pragma unroll
      for (int m = 0; m < 2; ++m) {
        int row = wrS + m * 16 + lrow;
        af[m] = *(const bf16x8*)&As[row * 64 + (ke ^ ((row & 7) << 3))];
      }
#pragma unroll
      for (int n = 0; n < 4; ++n) {
        int col = n * 16 + lrow;
        wf[n] = *(const bf16x8*)&Bs[col * 64 + (ke ^ ((col & 7) << 3))];
      }
#pragma unroll
      for (int m = 0; m < 2; ++m)
#pragma unroll
        for (int n = 0; n < 4; ++n)
          accS[m][n] = __builtin_amdgcn_mfma_f32_16x16x32_bf16(af[m], wf[n], accS[m][n], 0, 0, 0);
    }
    __syncthreads();
  }

  // Phase B: main GEMM over 128 cols (node: [npj|vn] rows 0-127 of B2t;
  // edge: [pe|ve] rows 128-255)
  const int cbase = nodeblk ? 0 : 128;
  const int wr = (wid >> 1) * 64, wc = (wid & 1) * 64;
  f32x4 acc[4][4];
#pragma unroll
  for (int m = 0; m < 4; ++m)
#pragma unroll
    for (int n = 0; n < 4; ++n) acc[m][n] = (f32x4){0.f, 0.f, 0.f, 0.f};
  for (int k0 = 0; k0 < 256; k0 += 64) {
#pragma unroll
    for (int l = 0; l < 4; ++l) {
      int c = tid + l * 256;
      int row = c >> 3, kc = (c & 7) * 8;
      int sw = row * 64 + (kc ^ ((row & 7) << 3));
      int grow = bm + row;
      bf16x8 v = {0, 0, 0, 0, 0, 0, 0, 0};
      if (grow < N) v = *(const bf16x8*)(aob + (size_t)grow * 256 + k0 + kc);
      *(bf16x8*)&As[sw] = v;
      *(bf16x8*)&Bs[sw] = *(const bf16x8*)(B2t + (size_t)(cbase + row) * 256 + k0 + kc);
    }
    __syncthreads();
#pragma unroll
    for (int ks = 0; ks < 2; ++ks) {
      const int ke = ks * 32 + lkb;
      bf16x8 af[4], bfr[4];
#pragma unroll
      for (int m = 0; m < 4; ++m) {
        int row = wr + m * 16 + lrow;
        af[m] = *(const bf16x8*)&As[row * 64 + (ke ^ ((row & 7) << 3))];
      }
#pragma unroll
      for (int n = 0; n < 4; ++n) {
        int col = wc + n * 16 + lrow;
        bfr[n] = *(const bf16x8*)&Bs[col * 64 + (ke ^ ((col & 7) << 3))];
      }
#pragma unroll
      for (int m = 0; m < 4; ++m)
#pragma unroll
        for (int n = 0; n < 4; ++n)
          acc[m][n] = __builtin_amdgcn_mfma_f32_16x16x32_bf16(af[m], bfr[n], acc[m][n], 0, 0, 0);
    }
    __syncthreads();
  }

  // Stage C tile (with bias) into LDS
  const int colw = lane & 15, rq = (lane >> 4) * 4;
  unsigned short* Cs = shmem;
#pragma unroll
  for (int m = 0; m < 4; ++m) {
#pragma unroll
    for (int n = 0; n < 4; ++n) {
      int col = wc + n * 16 + colw;
      float bv = bias2[cbase + col];
#pragma unroll
      for (int r = 0; r < 4; ++r) {
        int row = wr + m * 16 + rq + r;
        Cs[row * 136 + col] = f2bf(acc[m][n][r] + bv);
      }
    }
  }
  __syncthreads();

  if (nodeblk) {
    // node gate update: g = sigm(Sn + vn + bg); nf = nf*g + npj*(1-g)
    const int wrS = wid * 32;
#pragma unroll
    for (int m = 0; m < 2; ++m) {
#pragma unroll
      for (int r = 0; r < 4; ++r) {
        int row = wrS + m * 16 + rq + r;
        int grow = bm + row;
        if (grow >= N) continue;
#pragma unroll
        for (int n = 0; n < 4; ++n) {
          int c = n * 16 + colw;
          float g = sigm(accS[m][n][r] + bf2f(Cs[row * 136 + 64 + c]) + bgv[c]);
          size_t oi = (size_t)grow * 64 + c;
          float old = nf[oi];
          nf[oi] = old * g + bf2f(Cs[row * 136 + c]) * (1.0f - g);
        }
      }
    }
  } else {
    const int rsub = tid >> 4, c8 = (tid & 15) * 8;
#pragma unroll
    for (int i = 0; i < 8; ++i) {
      int row = i * 16 + rsub;
      int grow = bm + row;
      if (grow >= N) continue;
      *(uint4*)(Pe + (size_t)grow * 128 + c8) = *(const uint4*)&Cs[row * 136 + c8];
    }
  }
}

// ------ MFMA [M,64]@[64,64] with fused epilogue ------
// UPD 0: fp32 A, store fp32 C. UPD 2: bf16 A (efc), bf16 edge-gate update
// using Pe[N,128] (pe cols 0-63, ve cols 64-127); src from srcl.
template <int UPD>
__global__ __launch_bounds__(256) void gemm_gate(
    const void* __restrict__ Av, int M, const unsigned short* __restrict__ Wt,
    const unsigned short* __restrict__ P, const float* __restrict__ bgv,
    const int* __restrict__ srcl, void* __restrict__ updv) {
  __shared__ unsigned short As[128 * 64];
  __shared__ unsigned short Ws[64 * 64];
  const int tid = threadIdx.x;
  const int bm = blockIdx.x * 128;
  if (UPD == 2) {
    const unsigned short* Ab = (const unsigned short*)Av;
#pragma unroll
    for (int l = 0; l < 4; ++l) {
      int u = tid + l * 256;
      int row = u >> 3, kc = (u & 7) * 8;
      int grow = bm + row;
      bf16x8 v = {0, 0, 0, 0, 0, 0, 0, 0};
      if (grow < M) v = *(const bf16x8*)(Ab + (size_t)grow * 64 + kc);
      *(bf16x8*)&As[row * 64 + (kc ^ ((row & 7) << 3))] = v;
    }
  } else {
    const float* Af = (const float*)Av;
#pragma unroll
    for (int l = 0; l < 8; ++l) {
      int u = tid + l * 256;
      int row = u >> 4, k4 = (u & 15) << 2;
      int grow = bm + row;
      float4 v = make_float4(0.f, 0.f, 0.f, 0.f);
      if (grow < M) v = *(const float4*)(Af + (size_t)grow * 64 + k4);
      union { unsigned short h[4]; uint2 q; } pk;
      pk.h[0] = f2bf(v.x); pk.h[1] = f2bf(v.y); pk.h[2] = f2bf(v.z); pk.h[3] = f2bf(v.w);
      *(uint2*)&As[row * 64 + (k4 ^ ((row & 7) << 3))] = pk.q;
    }
  }
#pragma unroll
  for (int l = 0; l < 2; ++l) {
    int u = tid + l * 256;
    int row = u >> 3, kc = (u & 7) * 8;
    *(bf16x8*)&Ws[row * 64 + (kc ^ ((row & 7) << 3))] = *(const bf16x8*)(Wt + row * 64 + kc);
  }
  __syncthreads();
  const int wid = tid >> 6, lane = tid & 63;
  const int wr = wid * 32;
  const int lrow = lane & 15, lkb = (lane >> 4) * 8;
  f32x4 acc[2][4];
#pragma unroll
  for (int m = 0; m < 2; ++m)
#pragma unroll
    for (int n = 0; n < 4; ++n) acc[m][n] = (f32x4){0.f, 0.f, 0.f, 0.f};
#pragma unroll
  for (int ks = 0; ks < 2; ++ks) {
    const int ke = ks * 32 + lkb;
    bf16x8 af[2], wf[4];
#pragma unroll
    for (int m = 0; m < 2; ++m) {
      int row = wr + m * 16 + lrow;
      af[m] = *(const bf16x8*)&As[row * 64 + (ke ^ ((row & 7) << 3))];
    }
#pragma unroll
    for (int n = 0; n < 4; ++n) {
      int col = n * 16 + lrow;
      wf[n] = *(const bf16x8*)&Ws[col * 64 + (ke ^ ((col & 7) << 3))];
    }
#pragma unroll
    for (int m = 0; m < 2; ++m)
#pragma unroll
      for (int n = 0; n < 4; ++n)
        acc[m][n] = __builtin_amdgcn_mfma_f32_16x16x32_bf16(af[m], wf[n], acc[m][n], 0, 0, 0);
  }
  const int colw = lane & 15, rq = (lane >> 4) * 4;
#pragma unroll
  for (int m = 0; m < 2; ++m) {
#pragma unroll
    for (int r = 0; r < 4; ++r) {
      int e = bm + wr + m * 16 + rq + r;
      if (e >= M) continue;
      if (UPD == 0) {
        float* upd = (float*)updv;
#pragma unroll
        for (int n = 0; n < 4; ++n) upd[(size_t)e * 64 + n * 16 + colw] = acc[m][n][r];
      } else {
        unsigned short* upd = (unsigned short*)updv;
        int s = srcl[e];
        const unsigned short* Pr = P + (size_t)s * 128;
#pragma unroll
        for (int n = 0; n < 4; ++n) {
          int c = n * 16 + colw;
          float g = sigm(acc[m][n][r] + bf2f(Pr[64 + c]) + bgv[c]);
          size_t oi = (size_t)e * 64 + c;
          float vA = bf2f(upd[oi]);
          upd[oi] = f2bf(vA * g + bf2f(Pr[c]) * (1.0f - g));
        }
      }
    }
  }
}

// ---------------- attention: no-max softmax, 4-edge unrolled --------------
__global__ __launch_bounds__(256) void k_attn(const unsigned short* __restrict__ qo,
                                              const unsigned short* __restrict__ kv,
                                              const unsigned short* __restrict__ skipb, const int* __restrict__ off,
                                              const int* __restrict__ slist,
                                              unsigned short* __restrict__ aob,
                                              const float* __restrict__ g, const float* __restrict__ b, int N) {
  int n = blockIdx.x * 4 + (threadIdx.x >> 6);
  int lane = threadIdx.x & 63;
  if (n >= N) return;
  union { uint2 u; unsigned short h[4]; } qq;
  qq.u = *(const uint2*)(qo + (size_t)n * 256 + 4 * lane);
  float q0 = bf2f(qq.h[0]), q1 = bf2f(qq.h[1]), q2 = bf2f(qq.h[2]), q3 = bf2f(qq.h[3]);
  float lsum = 0.f;
  float a0 = 0.f, a1 = 0.f, a2 = 0.f, a3 = 0.f;
  int i0 = off[n], i1 = off[n + 1];
  int idx = i0;
  for (; idx + 4 <= i1; idx += 4) {
    int s0 = slist[idx], s1 = slist[idx + 1], s2 = slist[idx + 2], s3 = slist[idx + 3];
    const unsigned short* kb0 = kv + (size_t)s0 * 512;
    const unsigned short* kb1 = kv + (size_t)s1 * 512;
    const unsigned short* kb2 = kv + (size_t)s2 * 512;
    const unsigned short* kb3 = kv + (size_t)s3 * 512;
    union { uint2 u; unsigned short h[4]; } kk0, vv0, kk1, vv1, kk2, vv2, kk3, vv3;
    kk0.u = *(const uint2*)(kb0 + 4 * lane); vv0.u = *(const uint2*)(kb0 + 256 + 4 * lane);
    kk1.u = *(const uint2*)(kb1 + 4 * lane); vv1.u = *(const uint2*)(kb1 + 256 + 4 * lane);
    kk2.u = *(const uint2*)(kb2 + 4 * lane); vv2.u = *(const uint2*)(kb2 + 256 + 4 * lane);
    kk3.u = *(const uint2*)(kb3 + 4 * lane); vv3.u = *(const uint2*)(kb3 + 256 + 4 * lane);
    float d0 = q0 * bf2f(kk0.h[0]) + q1 * bf2f(kk0.h[1]) + q2 * bf2f(kk0.h[2]) + q3 * bf2f(kk0.h[3]);
    float d1 = q0 * bf2f(kk1.h[0]) + q1 * bf2f(kk1.h[1]) + q2 * bf2f(kk1.h[2]) + q3 * bf2f(kk1.h[3]);
    float d2 = q0 * bf2f(kk2.h[0]) + q1 * bf2f(kk2.h[1]) + q2 * bf2f(kk2.h[2]) + q3 * bf2f(kk2.h[3]);
    float d3 = q0 * bf2f(kk3.h[0]) + q1 * bf2f(kk3.h[1]) + q2 * bf2f(kk3.h[2]) + q3 * bf2f(kk3.h[3]);
#pragma unroll
    for (int dd = 1; dd < 16; dd <<= 1) {
      d0 += __shfl_xor(d0, dd);
      d1 += __shfl_xor(d1, dd);
      d2 += __shfl_xor(d2, dd);
      d3 += __shfl_xor(d3, dd);
    }
    float p0 = __expf(d0 * 0.125f);
    float p1 = __expf(d1 * 0.125f);
    float p2 = __expf(d2 * 0.125f);
    float p3 = __expf(d3 * 0.125f);
    lsum += p0 + p1 + p2 + p3;
    a0 = fmaf(p0, bf2f(vv0.h[0]), a0); a1 = fmaf(p0, bf2f(vv0.h[1]), a1);
    a2 = fmaf(p0, bf2f(vv0.h[2]), a2); a3 = fmaf(p0, bf2f(vv0.h[3]), a3);
    a0 = fmaf(p1, bf2f(vv1.h[0]), a0); a1 = fmaf(p1, bf2f(vv1.h[1]), a1);
    a2 = fmaf(p1, bf2f(vv1.h[2]), a2); a3 = fmaf(p1, bf2f(vv1.h[3]), a3);
    a0 = fmaf(p2, bf2f(vv2.h[0]), a0); a1 = fmaf(p2, bf2f(vv2.h[1]), a1);
    a2 = fmaf(p2, bf2f(vv2.h[2]), a2); a3 = fmaf(p2, bf2f(vv2.h[3]), a3);
    a0 = fmaf(p3, bf2f(vv3.h[0]), a0); a1 = fmaf(p3, bf2f(vv3.h[1]), a1);
    a2 = fmaf(p3, bf2f(vv3.h[2]), a2); a3 = fmaf(p3, bf2f(vv3.h[3]), a3);
  }
  for (; idx < i1; ++idx) {
    int s = slist[idx];
    const unsigned short* kb = kv + (size_t)s * 512;
    union { uint2 u; unsigned short h[4]; } kk, vv;
    kk.u = *(const uint2*)(kb + 4 * lane);
    vv.u = *(const uint2*)(kb + 256 + 4 * lane);
    float d = q0 * bf2f(kk.h[0]) + q1 * bf2f(kk.h[1]) + q2 * bf2f(kk.h[2]) + q3 * bf2f(kk.h[3]);
#pragma unroll
    for (int dd = 1; dd < 16; dd <<= 1) d += __shfl_xor(d, dd);
    float p = __expf(d * 0.125f);
    lsum += p;
    a0 = fmaf(p, bf2f(vv.h[0]), a0);
    a1 = fmaf(p, bf2f(vv.h[1]), a1);
    a2 = fmaf(p, bf2f(vv.h[2]), a2);
    a3 = fmaf(p, bf2f(vv.h[3]), a3);
  }
  union { uint2 u; unsigned short h[4]; } sb;
  sb.u = *(const uint2*)(skipb + (size_t)n * 256 + 4 * lane);
  float inv = (lsum > 0.f) ? 1.0f / lsum : 0.f;
  float v0 = bf2f(sb.h[0]) + a0 * inv;
  float v1 = bf2f(sb.h[1]) + a1 * inv;
  float v2 = bf2f(sb.h[2]) + a2 * inv;
  float v3 = bf2f(sb.h[3]) + a3 * inv;
  float s1 = wsum(v0 + v1 + v2 + v3);
  float s2 = wsum(v0 * v0 + v1 * v1 + v2 * v2 + v3 * v3);
  float mu = s1 * (1.0f / 256.0f);
  float var = s2 * (1.0f / 256.0f) - mu * mu;
  float rs = rsqrtf(fmaxf(var, 0.0f) + LN_EPS);
  float4 g4 = *(const float4*)(g + 4 * lane);
  float4 b4 = *(const float4*)(b + 4 * lane);
  union { uint2 u; unsigned short h[4]; } ob;
  ob.h[0] = f2bf((v0 - mu) * rs * g4.x + b4.x);
  ob.h[1] = f2bf((v1 - mu) * rs * g4.y + b4.y);
  ob.h[2] = f2bf((v2 - mu) * rs * g4.z + b4.z);
  ob.h[3] = f2bf((v3 - mu) * rs * g4.w + b4.w);
  *(uint2*)(aob + (size_t)n * 256 + 4 * lane) = ob.u;
}

// ---------------- classifier pair kernel ----------------
__global__ __launch_bounds__(256) void k_clf_pair(const float* __restrict__ ABt, const float* __restrict__ ABb,
                                                  const int* __restrict__ ei, const float* __restrict__ bc1,
                                                  const float* __restrict__ Wc2, const float* __restrict__ bc2,
                                                  float* __restrict__ out, int E) {
  int e = blockIdx.x * 4 + (threadIdx.x >> 6);
  int lane = threadIdx.x & 63;
  if (e >= E) return;
  int s = ei[e], t = ei[E + e];
  float h = fmaxf(ABt[(size_t)s * 64 + lane] + ABb[(size_t)t * 64 + lane] + bc1[lane], 0.0f);
  float r = wsum(h * Wc2[lane]);
  if (lane == 0) out[e] = r + bc2[0];
}

// ============================================================================
extern "C" void kernel_launch(void* const* d_in, const int* in_sizes, int n_in,
                              void* d_out, int out_size, void* d_ws, size_t ws_size,
                              hipStream_t stream) {
  const float* x = (const float*)d_in[0];
  const float* edge_attr = (const float*)d_in[1];
  const int* ei = (const int*)d_in[2];
  const int* zk = (const int*)d_in[3];
  const float* z_table = (const float*)d_in[4];
  const float* W_node = (const float*)d_in[5];
  const float* b_node = (const float*)d_in[6];
  const float* W_edge = (const float*)d_in[7];
  const float* b_edge = (const float*)d_in[8];
  const float* cn_w1 = (const float*)d_in[9];
  const float* cn_b1 = (const float*)d_in[10];
  const float* cn_w2 = (const float*)d_in[11];
  const float* cn_b2 = (const float*)d_in[12];
  const float* cn_cw1 = (const float*)d_in[13];
  const float* cn_cb1 = (const float*)d_in[14];
  const float* cn_cw2 = (const float*)d_in[15];
  const float* cn_cb2 = (const float*)d_in[16];
  const float* ce_w1 = (const float*)d_in[17];
  const float* ce_b1 = (const float*)d_in[18];
  const float* ce_w2 = (const float*)d_in[19];
  const float* ce_b2 = (const float*)d_in[20];
  const float* ce_cw1 = (const float*)d_in[21];
  const float* ce_cb1 = (const float*)d_in[22];
  const float* ce_cw2 = (const float*)d_in[23];
  const float* ce_cb2 = (const float*)d_in[24];
  const float* ln_comb_g = (const float*)d_in[25];
  const float* ln_comb_b = (const float*)d_in[26];
  const float* Wq = (const float*)d_in[27];
  const float* bq = (const float*)d_in[28];
  const float* Wk = (const float*)d_in[29];
  const float* bk = (const float*)d_in[30];
  const float* Wv = (const float*)d_in[31];
  const float* bv = (const float*)d_in[32];
  const float* Wskip = (const float*)d_in[33];
  const float* bskip = (const float*)d_in[34];
  const float* ln_tc_g = (const float*)d_in[35];
  const float* ln_tc_b = (const float*)d_in[36];
  const float* Wpn = (const float*)d_in[37];
  const float* bpn = (const float*)d_in[38];
  const float* Wpe = (const float*)d_in[39];
  const float* bpe = (const float*)d_in[40];
  const float* Wg = (const float*)d_in[41];
  const float* bg = (const float*)d_in[42];
  const float* Wc1 = (const float*)d_in[43];
  const float* bc1 = (const float*)d_in[44];
  const float* Wc2 = (const float*)d_in[45];
  const float* bc2 = (const float*)d_in[46];
  float* out = (float*)d_out;

  const int N = in_sizes[0] / 6;   // 50000
  const int E = in_sizes[2] / 2;   // 100000
  const int E2 = 2 * E;

  // ---- workspace carve (~216 MB peak) ----
  char* p = (char*)d_ws;
  auto carve = [&](size_t bytes) -> void* {
    void* r = (void*)p;
    p += (bytes + 255) & ~(size_t)255;
    return r;
  };
  unsigned short* qo = (unsigned short*)carve((size_t)N * 256 * 2);    // Q bf16
  unsigned short* skipb = (unsigned short*)carve((size_t)N * 256 * 2); // skip bf16 -> Pe bf16 [N,128] (alias)
  unsigned short* kvb = (unsigned short*)carve((size_t)N * 512 * 2);   // K|V bf16
  unsigned short* aob = (unsigned short*)carve((size_t)N * 256 * 2);   // attn out bf16 -> AB f32
  unsigned short* efb = (unsigned short*)carve((size_t)E2 * 64 * 2);   // edge feats bf16 (edge-id order)
  unsigned short* efc = (unsigned short*)carve((size_t)E2 * 64 * 2);   // edge feats bf16 (CSR order)
  float* nf = (float*)carve((size_t)N * 64 * 4);
  unsigned short* comb = (unsigned short*)carve((size_t)N * 128 * 2);
  unsigned short* W1t = (unsigned short*)carve((size_t)3 * 1024 * 128 * 2);
  float* bias1 = (float*)carve((size_t)3 * 1024 * 4);
  unsigned short* B2t = (unsigned short*)carve((size_t)3 * 256 * 256 * 2);
  float* bias2 = (float*)carve((size_t)3 * 256 * 4);
  unsigned short* Wg1t = (unsigned short*)carve((size_t)3 * 64 * 64 * 2);
  unsigned short* Wc1t = (unsigned short*)carve((size_t)2 * 64 * 64 * 2);
  int* cnt = (int*)carve((size_t)N * 4);
  int* cur = (int*)carve((size_t)N * 4);
  int* off = (int*)carve((size_t)(N + 1) * 4);
  int* pinv = (int*)carve((size_t)E2 * 4);
  int* slist = (int*)carve((size_t)E2 * 4);
  int* bsum = (int*)carve((size_t)256 * 4);
  int* boff = (int*)carve((size_t)256 * 4);
  float* pm = (float*)carve((size_t)PBLK * 64 * 4);
  float* ps = (float*)carve((size_t)PBLK * 64 * 4);
  float* cwv = (float*)carve(64 * 4);
  float* spmax = (float*)carve((size_t)E2 * 4);
  float* spmean = (float*)carve((size_t)E2 * 4);
  float* sconv = (float*)carve((size_t)E2 * 4);
  size_t need = (size_t)(p - (char*)d_ws);

  unsigned short* Pe = skipb;       // Pe [N,128] bf16 aliases skipb (dead after k_attn)
  float* ABt = (float*)aob;
  float* ABb = (float*)aob + (size_t)N * 64;

  auto cdiv = [](int a, int b) { return (a + b - 1) / b; };

  if (ws_size < need) {
    k_sentinel<<<cdiv(E, 256), 256, 0, stream>>>(out, E);
    return;
  }

  // ---- CSR by dst (multi-block scan) ----
  k_zero2<<<cdiv(N, 256), 256, 0, stream>>>(cnt, cur, N);
  k_hist<<<cdiv(E2, 256), 256, 0, stream>>>(ei, cnt, E);
  const int nblk = cdiv(N, 1024);
  k_scan1<<<nblk, 256, 0, stream>>>(cnt, off, bsum, N);
  k_scan2<<<1, 64, 0, stream>>>(bsum, boff, off, N, nblk);
  k_scan3<<<cdiv(N, 256), 256, 0, stream>>>(off, boff, N);
  k_scatter<<<cdiv(E2, 256), 256, 0, stream>>>(ei, off, cur, pinv, slist, E);

  // ---- pack weights (bf16 transposed) ----
  const int PACK = 3 * 1024 * 128 + 3 * 1024 + 3 * 256 * 256 + 3 * 256 + 3 * 64 * 64 + 2 * 64 * 64;
  k_packW<<<cdiv(PACK, 256), 256, 0, stream>>>(Wq, Wk, Wv, Wskip, bq, bk, bv, bskip,
                                               Wpn, Wpe, bpn, bpe, Wg, Wc1,
                                               W1t, bias1, B2t, bias2, Wg1t, Wc1t);

  // ---- embeddings ----
  k_node_embed<<<cdiv(N, 4), 256, 0, stream>>>(x, zk, z_table, W_node, b_node, nf, N);
  k_edge_embed<<<cdiv(E2, 4), 256, 0, stream>>>(x, edge_attr, ei, W_edge, b_edge, efb, E);

  // ---- CBAM: nodes (fp32, in place) then edges (bf16, scatter to CSR) ----
  k_pool_partial<float><<<PBLK, 256, 0, stream>>>(nf, N, pm, ps);
  k_pool_final<<<1, 256, 0, stream>>>(pm, ps, N, PBLK, cn_w1, cn_b1, cn_w2, cn_b2, cwv);
  k_chan_sp<float><<<cdiv(N, 16), 256, 0, stream>>>(nf, N, cwv, spmax, spmean);
  k_conv<<<cdiv(N, 256), 256, 0, stream>>>(spmax, spmean, N, cn_cw1, cn_cb1, cn_cw2, cn_cb2, sconv);
  k_row_scale<<<cdiv(N * 16, 256), 256, 0, stream>>>(nf, N, sconv);

  k_pool_partial<unsigned short><<<PBLK, 256, 0, stream>>>(efb, E2, pm, ps);
  k_pool_final<<<1, 256, 0, stream>>>(pm, ps, E2, PBLK, ce_w1, ce_b1, ce_w2, ce_b2, cwv);
  k_chan_sp<unsigned short><<<cdiv(E2, 16), 256, 0, stream>>>(efb, E2, cwv, spmax, spmean);
  k_conv<<<cdiv(E2, 256), 256, 0, stream>>>(spmax, spmean, E2, ce_cw1, ce_cb1, ce_cw2, ce_cb2, sconv);
  k_row_scale_perm<<<cdiv(E2 * 16, 256), 256, 0, stream>>>(efb, E2, sconv, pinv, efc);

  // ---- T = 3 message-passing iterations ----
  const int gqkvs = cdiv(N, 128) * 8;  // 1D, XCD-swizzled in-kernel
  dim3 gpf(cdiv(N, 128), 2);
  for (int i = 0; i < 3; ++i) {
    k_aggcomb<<<cdiv(N, 4), 256, 0, stream>>>(efc, nf, off, comb,
                                              ln_comb_g + (size_t)i * 128, ln_comb_b + (size_t)i * 128, N);
    gemm_mfma<<<gqkvs, 256, 0, stream>>>(comb, N, 128, W1t + (size_t)i * 131072,
                                         bias1 + (size_t)i * 1024, qo, kvb, skipb);
    k_attn<<<cdiv(N, 4), 256, 0, stream>>>(qo, kvb, skipb, off, slist, aob,
                                           ln_tc_g + (size_t)i * 256, ln_tc_b + (size_t)i * 256, N);
    gemm_p<<<gpf, 256, 0, stream>>>(aob, nf, N, B2t + (size_t)i * 65536,
                                    bias2 + (size_t)i * 256, Wg1t + (size_t)i * 4096,
                                    bg + (size_t)i * 64, Pe);
    gemm_gate<2><<<cdiv(E2, 128), 256, 0, stream>>>(efc, E2, Wg1t + (size_t)i * 4096, Pe,
                                                    bg + (size_t)i * 64, slist, efc);
  }

  // ---- classifier ----
  gemm_gate<0><<<cdiv(N, 128), 256, 0, stream>>>(nf, N, Wc1t, nullptr, nullptr, nullptr, ABt);
  gemm_gate<0><<<cdiv(N, 128), 256, 0, stream>>>(nf, N, Wc1t + 4096, nullptr, nullptr, nullptr, ABb);
  k_clf_pair<<<cdiv(E, 4), 256, 0, stream>>>(ABt, ABb, ei, bc1, Wc2, bc2, out, E);
  (void)out_size;
  (void)n_in;
}